// Round 11
// baseline (743.708 us; speedup 1.0000x reference)
//
#include <hip/hip_runtime.h>

#define N_NODES   40000
#define N_EDGES   640000
#define N_GRAPHS  64
#define DIM_IN    32
#define N_ETYPE   16
#define DH        128
#define DOUT      256
#define T_ITERS   4
#define SCAN_BLK  40          // ceil(40000/1024)

typedef unsigned int uint32;
typedef unsigned short ushort16;
typedef __attribute__((ext_vector_type(8))) short bf16x8;
typedef __attribute__((ext_vector_type(4))) float f32x4;

__device__ __forceinline__ uint32 f2bf1(float f) {
  uint32 u = __float_as_uint(f);
  return (u + 0x7fffu + ((u >> 16) & 1u)) >> 16;
}
__device__ __forceinline__ uint32 pack_bf2(float lo, float hi) {
  return (f2bf1(hi) << 16) | f2bf1(lo);
}

// ---------------- node embedding: h = x @ Wn + bn (fp32 + bf16 mirror) ----------------
__global__ __launch_bounds__(256) void k_embed(const float* __restrict__ x,
                                               const float* __restrict__ Wn,
                                               const float* __restrict__ bn,
                                               float* __restrict__ h,
                                               ushort16* __restrict__ hb) {
  int idx = blockIdx.x * 256 + threadIdx.x;     // n*128 + c, exact grid
  int n = idx >> 7, c = idx & 127;
  const float* xr = x + n * DIM_IN;
  float acc = bn[c];
#pragma unroll
  for (int k = 0; k < DIM_IN; ++k)
    acc = fmaf(xr[k], Wn[k * DH + c], acc);
  h[idx] = acc;
  hb[idx] = (ushort16)f2bf1(acc);
}

// ---------------- CSR build ----------------
__global__ __launch_bounds__(256) void k_hist(const int* __restrict__ dst,
                                              int* __restrict__ counts) {
  int i = blockIdx.x * 256 + threadIdx.x;
  atomicAdd(&counts[dst[i]], 1);
}

// ---- 3-pass parallel scan ----
__global__ __launch_bounds__(1024) void k_scan1(const int* __restrict__ counts,
                                                int* __restrict__ excl,      // = row_start
                                                int* __restrict__ blk_sums) {
  __shared__ int wsums[16];
  int tid = threadIdx.x, lane = tid & 63, w = tid >> 6;
  int i = blockIdx.x * 1024 + tid;
  int v = (i < N_NODES) ? counts[i] : 0;
  int s = v;
#pragma unroll
  for (int off = 1; off < 64; off <<= 1) {
    int t = __shfl_up(s, off);
    if (lane >= off) s += t;
  }
  if (lane == 63) wsums[w] = s;
  __syncthreads();
  if (tid < 16) {
    int ws_ = wsums[tid];
#pragma unroll
    for (int off = 1; off < 16; off <<= 1) {
      int t = __shfl_up(ws_, off);
      if (tid >= off) ws_ += t;
    }
    wsums[tid] = ws_;
  }
  __syncthreads();
  int e = s - v + (w ? wsums[w - 1] : 0);
  if (i < N_NODES) excl[i] = e;
  if (tid == 0) blk_sums[blockIdx.x] = wsums[15];
}

__global__ __launch_bounds__(64) void k_scan2(const int* __restrict__ blk_sums,
                                              int* __restrict__ blk_off,
                                              int* __restrict__ row_start) {
  int lane = threadIdx.x;
  int v = (lane < SCAN_BLK) ? blk_sums[lane] : 0;
  int s = v;
#pragma unroll
  for (int off = 1; off < 64; off <<= 1) {
    int t = __shfl_up(s, off);
    if (lane >= off) s += t;
  }
  if (lane < SCAN_BLK) blk_off[lane] = s - v;
  if (lane == 63) row_start[N_NODES] = s;
}

__global__ __launch_bounds__(1024) void k_scan3(int* __restrict__ row_start,
                                                const int* __restrict__ blk_off,
                                                int* __restrict__ cursor) {
  int i = blockIdx.x * 1024 + threadIdx.x;
  if (i < N_NODES) {
    int v = row_start[i] + blk_off[blockIdx.x];
    row_start[i] = v;
    cursor[i] = v;
  }
}

__global__ __launch_bounds__(256) void k_permute(const int* __restrict__ src,
                                                 const int* __restrict__ dst,
                                                 int* __restrict__ cursor,
                                                 int* __restrict__ src_perm,
                                                 int* __restrict__ eid_perm) {
  int i = blockIdx.x * 256 + threadIdx.x;
  int d = dst[i];
  int pos = atomicAdd(&cursor[d], 1);
  src_perm[pos] = src[i];
  eid_perm[pos] = i;
}

// permute WITH edge_attr materialization in CSR order (primary path)
__global__ __launch_bounds__(256) void k_permute_ea(const int* __restrict__ src,
                                                    const int* __restrict__ dst,
                                                    const float4* __restrict__ edge_attr,
                                                    int* __restrict__ cursor,
                                                    int* __restrict__ src_perm,
                                                    float4* __restrict__ ea_perm) {
  int i = blockIdx.x * 256 + threadIdx.x;
  int d = dst[i];
  int pos = atomicAdd(&cursor[d], 1);
  src_perm[pos] = src[i];
  const float4* s = edge_attr + ((size_t)i << 2);
  float4* o = ea_perm + ((size_t)pos << 2);
  float4 v0 = s[0], v1 = s[1], v2 = s[2], v3 = s[3];
  o[0] = v0; o[1] = v1; o[2] = v2; o[3] = v3;
}

#define MAC16(A0,A1,A2,A3)                                          \
  p0 = fmaf(A0.x, we0[0], p0);  p1 = fmaf(A0.x, we1[0], p1);        \
  p0 = fmaf(A0.y, we0[1], p0);  p1 = fmaf(A0.y, we1[1], p1);        \
  p0 = fmaf(A0.z, we0[2], p0);  p1 = fmaf(A0.z, we1[2], p1);        \
  p0 = fmaf(A0.w, we0[3], p0);  p1 = fmaf(A0.w, we1[3], p1);        \
  p0 = fmaf(A1.x, we0[4], p0);  p1 = fmaf(A1.x, we1[4], p1);        \
  p0 = fmaf(A1.y, we0[5], p0);  p1 = fmaf(A1.y, we1[5], p1);        \
  p0 = fmaf(A1.z, we0[6], p0);  p1 = fmaf(A1.z, we1[6], p1);        \
  p0 = fmaf(A1.w, we0[7], p0);  p1 = fmaf(A1.w, we1[7], p1);        \
  p0 = fmaf(A2.x, we0[8], p0);  p1 = fmaf(A2.x, we1[8], p1);        \
  p0 = fmaf(A2.y, we0[9], p0);  p1 = fmaf(A2.y, we1[9], p1);        \
  p0 = fmaf(A2.z, we0[10], p0); p1 = fmaf(A2.z, we1[10], p1);       \
  p0 = fmaf(A2.w, we0[11], p0); p1 = fmaf(A2.w, we1[11], p1);       \
  p0 = fmaf(A3.x, we0[12], p0); p1 = fmaf(A3.x, we1[12], p1);       \
  p0 = fmaf(A3.y, we0[13], p0); p1 = fmaf(A3.y, we1[13], p1);       \
  p0 = fmaf(A3.z, we0[14], p0); p1 = fmaf(A3.z, we1[14], p1);       \
  p0 = fmaf(A3.w, we0[15], p0); p1 = fmaf(A3.w, we1[15], p1);

#define RELU_ACC(G)                                                  \
  acc0 += fmaxf(__uint_as_float((G) << 16) + p0, 0.0f);              \
  acc1 += fmaxf(__uint_as_float((G) & 0xffff0000u) + p1, 0.0f);

// -------- aggregation, recompute path: zb[n] = bf16(hb[n] + sum relu(hb[src] + ea@We+be)) --------
// 10000 blocks, one wave per node; lane owns cols {2l, 2l+1}; We in registers.
__global__ __launch_bounds__(256) void k_agg_rc(const uint32* __restrict__ hb,
                                                const float4* __restrict__ ea_perm,
                                                const float* __restrict__ We,
                                                const float* __restrict__ be,
                                                const int* __restrict__ row_start,
                                                const int* __restrict__ src_perm,
                                                uint32* __restrict__ zb) {
  int lane = threadIdx.x & 63;
  int n = (blockIdx.x << 2) + (threadIdx.x >> 6);
  int c = lane << 1;
  float we0[N_ETYPE], we1[N_ETYPE];
#pragma unroll
  for (int k = 0; k < N_ETYPE; ++k) {
    we0[k] = We[k * DH + c];
    we1[k] = We[k * DH + c + 1];
  }
  float be0 = be[c], be1 = be[c + 1];
  uint32 hself = hb[(size_t)n * 64 + lane];
  float acc0 = __uint_as_float(hself << 16);
  float acc1 = __uint_as_float(hself & 0xffff0000u);
  int beg = row_start[n], end = row_start[n + 1];
  const float4* ea = ea_perm + ((size_t)beg << 2);
  int i = beg;
  for (; i + 4 <= end; i += 4, ea += 16) {
    int s0 = src_perm[i], s1 = src_perm[i + 1], s2 = src_perm[i + 2], s3 = src_perm[i + 3];
    uint32 g0 = hb[((size_t)s0 << 6) + lane];
    uint32 g1 = hb[((size_t)s1 << 6) + lane];
    uint32 g2 = hb[((size_t)s2 << 6) + lane];
    uint32 g3 = hb[((size_t)s3 << 6) + lane];
    float4 a0 = ea[0], a1 = ea[1], a2 = ea[2], a3 = ea[3];
    float4 b0 = ea[4], b1v = ea[5], b2v = ea[6], b3 = ea[7];
    float p0, p1;
    p0 = be0; p1 = be1; MAC16(a0, a1, a2, a3) RELU_ACC(g0)
    p0 = be0; p1 = be1; MAC16(b0, b1v, b2v, b3) RELU_ACC(g1)
    a0 = ea[8]; a1 = ea[9]; a2 = ea[10]; a3 = ea[11];
    b0 = ea[12]; b1v = ea[13]; b2v = ea[14]; b3 = ea[15];
    p0 = be0; p1 = be1; MAC16(a0, a1, a2, a3) RELU_ACC(g2)
    p0 = be0; p1 = be1; MAC16(b0, b1v, b2v, b3) RELU_ACC(g3)
  }
  for (; i < end; ++i, ea += 4) {
    int s0 = src_perm[i];
    uint32 g0 = hb[((size_t)s0 << 6) + lane];
    float4 a0 = ea[0], a1 = ea[1], a2 = ea[2], a3 = ea[3];
    float p0 = be0, p1 = be1;
    MAC16(a0, a1, a2, a3) RELU_ACC(g0)
  }
  zb[(size_t)n * 64 + lane] = pack_bf2(acc0, acc1);
}

// ---- one-time: W1,W2 -> bf16 fragment-major layout for MFMA B operands ----
// wc[(k0*8+n)*512 + l*8 + j] = bf16(W[k0*32 + (l>>4)*8 + j][n*16 + (l&15)])
__global__ __launch_bounds__(256) void k_prep_w(const float* __restrict__ W1,
                                                const float* __restrict__ W2,
                                                ushort16* __restrict__ w1c,
                                                ushort16* __restrict__ w2c) {
  int id = blockIdx.x * 256 + threadIdx.x;   // 0..32767
  int which = id >> 14;
  int rem = id & 16383;
  int j = rem & 7, lg = (rem >> 3) & 63, n = (rem >> 9) & 7, k0 = rem >> 12;
  int r = lg & 15, g = lg >> 4;
  const float* W = which ? W2 : W1;
  ushort16* wc = which ? w2c : w1c;
  wc[rem] = (ushort16)f2bf1(W[(k0 * 32 + g * 8 + j) * 128 + n * 16 + r]);
}

// ---------------- slim MFMA MLP: 1 wave / 16 nodes, 2500 blocks ----------------
// hb = bf16(relu(zb@W1+b1)@W2+b2); pooled += . All LDS traffic is wave-local.
__global__ __launch_bounds__(64) void k_mlp2(const uint32* __restrict__ zb,
                                             const ushort16* __restrict__ w1c,
                                             const ushort16* __restrict__ w2c,
                                             const float* __restrict__ b1,
                                             const float* __restrict__ b2,
                                             const int* __restrict__ graph_ids,
                                             uint32* __restrict__ hb_out,
                                             float* __restrict__ pooled,
                                             int t_slot) {
  __shared__ ushort16 sA[16 * 136];   // 4352 B
  int l = threadIdx.x;                // 0..63
  int rb = blockIdx.x * 16;

  // stage zb tile: 16 rows x 16 uint4
  for (int idx = l; idx < 256; idx += 64) {
    int row = idx >> 4, ch = idx & 15;
    *(uint4*)&sA[row * 136 + ch * 8] = *(const uint4*)&zb[(size_t)(rb + row) * 64 + ch * 4];
  }
  __syncthreads();   // 1-wave block: compiles to waitcnt only

  int r = l & 15, g = l >> 4;
  const ushort16* aBase = &sA[0] + r * 136 + g * 8;

  // ---- GEMM1 ----
  f32x4 acc[8];
#pragma unroll
  for (int n = 0; n < 8; ++n) {
    float bv = b1[n * 16 + r];
    acc[n] = (f32x4){bv, bv, bv, bv};
  }
#pragma unroll
  for (int k0 = 0; k0 < 4; ++k0) {
    bf16x8 a = *(const bf16x8*)(aBase + k0 * 32);
#pragma unroll
    for (int n = 0; n < 8; ++n) {
      bf16x8 b = *(const bf16x8*)(w1c + (k0 * 8 + n) * 512 + l * 8);
      acc[n] = __builtin_amdgcn_mfma_f32_16x16x32_bf16(a, b, acc[n], 0, 0, 0);
    }
  }

  // relu -> restage (within-wave LDS, barrier is waitcnt-only)
  __syncthreads();
#pragma unroll
  for (int n = 0; n < 8; ++n)
#pragma unroll
    for (int q = 0; q < 4; ++q)
      sA[(g * 4 + q) * 136 + n * 16 + r] = (ushort16)f2bf1(fmaxf(acc[n][q], 0.0f));
  __syncthreads();

  // ---- GEMM2 ----
#pragma unroll
  for (int n = 0; n < 8; ++n) {
    float bv = b2[n * 16 + r];
    acc[n] = (f32x4){bv, bv, bv, bv};
  }
#pragma unroll
  for (int k0 = 0; k0 < 4; ++k0) {
    bf16x8 a = *(const bf16x8*)(aBase + k0 * 32);
#pragma unroll
    for (int n = 0; n < 8; ++n) {
      bf16x8 b = *(const bf16x8*)(w2c + (k0 * 8 + n) * 512 + l * 8);
      acc[n] = __builtin_amdgcn_mfma_f32_16x16x32_bf16(a, b, acc[n], 0, 0, 0);
    }
  }

  // ---- pooled ----
  float* pbase = pooled + t_slot * DH;
  int gid0 = graph_ids[rb];
  if (gid0 == graph_ids[rb + 15]) {
#pragma unroll
    for (int n = 0; n < 8; ++n) {
      float s = acc[n][0] + acc[n][1] + acc[n][2] + acc[n][3];
      s += __shfl_xor(s, 16);
      s += __shfl_xor(s, 32);
      if (l < 16) atomicAdd(&pbase[gid0 * 512 + n * 16 + r], s);
    }
  } else {
#pragma unroll
    for (int q = 0; q < 4; ++q) {
      int node = rb + g * 4 + q;
      int gg = graph_ids[node];
#pragma unroll
      for (int n = 0; n < 8; ++n)
        atomicAdd(&pbase[gg * 512 + n * 16 + r], acc[n][q]);
    }
  }

  // ---- pack bf16 + coalesced store ----
  __syncthreads();
#pragma unroll
  for (int n = 0; n < 8; ++n)
#pragma unroll
    for (int q = 0; q < 4; ++q)
      sA[(g * 4 + q) * 136 + n * 16 + r] = (ushort16)f2bf1(acc[n][q]);
  __syncthreads();
  for (int idx = l; idx < 1024; idx += 64) {   // 16 rows x 64 dwords
    int row = idx >> 6, dw = idx & 63;
    uint32 v = *(const uint32*)&sA[row * 136 + dw * 2];
    hb_out[(size_t)(rb + row) * 64 + dw] = v;
  }
}

// -------- aggregation, fallback indirect path --------
__global__ __launch_bounds__(256, 8) void k_agg_ind(const float* __restrict__ h,
                                                    const uint32* __restrict__ hb,
                                                    const float* __restrict__ edge_attr,
                                                    const float* __restrict__ We,
                                                    const float* __restrict__ be,
                                                    const int* __restrict__ row_start,
                                                    const int* __restrict__ src_perm,
                                                    const int* __restrict__ eid_perm,
                                                    float* __restrict__ z) {
  int lane = threadIdx.x & 63;
  int n = (blockIdx.x << 2) + (threadIdx.x >> 6);
  int c = lane << 1;
  float we0[N_ETYPE], we1[N_ETYPE];
#pragma unroll
  for (int k = 0; k < N_ETYPE; ++k) {
    we0[k] = We[k * DH + c];
    we1[k] = We[k * DH + c + 1];
  }
  float be0 = be[c], be1 = be[c + 1];
  float2 hself = *(const float2*)&h[(size_t)n * DH + c];
  float acc0 = hself.x, acc1 = hself.y;
  int beg = row_start[n], end = row_start[n + 1];
  int i = beg;
  for (; i + 1 < end; i += 2) {
    int s0 = src_perm[i], s1 = src_perm[i + 1];
    int e0i = eid_perm[i], e1i = eid_perm[i + 1];
    uint32 g0 = hb[((size_t)s0 << 6) + lane];
    uint32 g1 = hb[((size_t)s1 << 6) + lane];
    const float4* eA = (const float4*)(edge_attr + (size_t)e0i * N_ETYPE);
    const float4* eB = (const float4*)(edge_attr + (size_t)e1i * N_ETYPE);
    float4 a0 = eA[0], a1 = eA[1], a2 = eA[2], a3 = eA[3];
    float p0, p1;
    p0 = be0; p1 = be1; MAC16(a0, a1, a2, a3) RELU_ACC(g0)
    float4 b0 = eB[0], b1v = eB[1], b2v = eB[2], b3 = eB[3];
    p0 = be0; p1 = be1; MAC16(b0, b1v, b2v, b3) RELU_ACC(g1)
  }
  if (i < end) {
    int s0 = src_perm[i];
    int e0i = eid_perm[i];
    uint32 g0 = hb[((size_t)s0 << 6) + lane];
    const float4* eA = (const float4*)(edge_attr + (size_t)e0i * N_ETYPE);
    float4 a0 = eA[0], a1 = eA[1], a2 = eA[2], a3 = eA[3];
    float p0 = be0, p1 = be1;
    MAC16(a0, a1, a2, a3) RELU_ACC(g0)
  }
  *(float2*)&z[(size_t)n * DH + c] = make_float2(acc0, acc1);
}

// ---------------- fallback fp32 MLP ----------------
#define MLPFMA(K, U0, U1)                                            \
  {                                                                  \
    _Pragma("unroll")                                                \
    for (int i_ = 0; i_ < 8; ++i_) {                                 \
      float2 a_ = *(const float2*)&sA[(r0 + i_) * 132 + (K)];        \
      acc[i_][0] = fmaf(a_.x, U0.x, acc[i_][0]);                     \
      acc[i_][1] = fmaf(a_.x, U0.y, acc[i_][1]);                     \
      acc[i_][2] = fmaf(a_.x, U0.z, acc[i_][2]);                     \
      acc[i_][3] = fmaf(a_.x, U0.w, acc[i_][3]);                     \
      acc[i_][0] = fmaf(a_.y, U1.x, acc[i_][0]);                     \
      acc[i_][1] = fmaf(a_.y, U1.y, acc[i_][1]);                     \
      acc[i_][2] = fmaf(a_.y, U1.z, acc[i_][2]);                     \
      acc[i_][3] = fmaf(a_.y, U1.w, acc[i_][3]);                     \
    }                                                                \
  }

__device__ __forceinline__ void gemm_tile_g(const float* sA, const float4* __restrict__ Wv,
                                            float acc[8][4], int r0, int cg) {
  float4 c0 = Wv[cg],       c1 = Wv[32 + cg];
  float4 n0 = Wv[64 + cg],  n1 = Wv[96 + cg];
#pragma unroll 4
  for (int k = 0; k < DH - 4; k += 2) {
    float4 u0 = c0, u1 = c1;
    c0 = n0; c1 = n1;
    n0 = Wv[(k + 4) * 32 + cg];
    n1 = Wv[(k + 5) * 32 + cg];
    MLPFMA(k, u0, u1)
  }
  MLPFMA(DH - 4, c0, c1)
  MLPFMA(DH - 2, n0, n1)
}

__global__ __launch_bounds__(256) void k_mlp(const float* __restrict__ z,
                                             const float* __restrict__ W1,
                                             const float* __restrict__ b1,
                                             const float* __restrict__ W2,
                                             const float* __restrict__ b2,
                                             const int* __restrict__ graph_ids,
                                             float* __restrict__ h_out,
                                             uint32* __restrict__ hb_out,
                                             float* __restrict__ pooled,
                                             int t_slot) {
  __shared__ float sA[64 * 132];
  int tid = threadIdx.x;
  int rb = blockIdx.x * 64;
  for (int idx = tid; idx < 64 * 32; idx += 256) {
    int r = idx >> 5, kq = (idx & 31) << 2;
    *(float4*)&sA[r * 132 + kq] = *(const float4*)&z[(size_t)(rb + r) * DH + kq];
  }
  __syncthreads();

  int cg = tid & 31, rg = tid >> 5;
  int c0 = cg << 2, r0 = rg << 3;
  float acc[8][4];
  {
    float4 bb = *(const float4*)&b1[c0];
#pragma unroll
    for (int i = 0; i < 8; ++i) { acc[i][0] = bb.x; acc[i][1] = bb.y; acc[i][2] = bb.z; acc[i][3] = bb.w; }
  }
  gemm_tile_g(sA, (const float4*)W1, acc, r0, cg);
  __syncthreads();
#pragma unroll
  for (int i = 0; i < 8; ++i) {
    float4 v;
    v.x = fmaxf(acc[i][0], 0.0f); v.y = fmaxf(acc[i][1], 0.0f);
    v.z = fmaxf(acc[i][2], 0.0f); v.w = fmaxf(acc[i][3], 0.0f);
    *(float4*)&sA[(r0 + i) * 132 + c0] = v;
  }
  __syncthreads();
  {
    float4 bb = *(const float4*)&b2[c0];
#pragma unroll
    for (int i = 0; i < 8; ++i) { acc[i][0] = bb.x; acc[i][1] = bb.y; acc[i][2] = bb.z; acc[i][3] = bb.w; }
  }
  gemm_tile_g(sA, (const float4*)W2, acc, r0, cg);

  int node0 = rb + r0;
#pragma unroll
  for (int i = 0; i < 8; ++i) {
    float4 v = make_float4(acc[i][0], acc[i][1], acc[i][2], acc[i][3]);
    *(float4*)&h_out[(size_t)(node0 + i) * DH + c0] = v;
    uint2 hv;
    hv.x = pack_bf2(acc[i][0], acc[i][1]);
    hv.y = pack_bf2(acc[i][2], acc[i][3]);
    *(uint2*)&hb_out[(size_t)(node0 + i) * 64 + (c0 >> 1)] = hv;
  }
  float* pbase = pooled + t_slot * DH;
  int g_first = graph_ids[node0];
  int g_last = graph_ids[node0 + 7];
  if (g_first == g_last) {
    float s0 = 0.f, s1 = 0.f, s2 = 0.f, s3 = 0.f;
#pragma unroll
    for (int i = 0; i < 8; ++i) { s0 += acc[i][0]; s1 += acc[i][1]; s2 += acc[i][2]; s3 += acc[i][3]; }
    atomicAdd(&pbase[g_first * 512 + c0 + 0], s0);
    atomicAdd(&pbase[g_first * 512 + c0 + 1], s1);
    atomicAdd(&pbase[g_first * 512 + c0 + 2], s2);
    atomicAdd(&pbase[g_first * 512 + c0 + 3], s3);
  } else {
#pragma unroll
    for (int i = 0; i < 8; ++i) {
      int g = graph_ids[node0 + i];
      atomicAdd(&pbase[g * 512 + c0 + 0], acc[i][0]);
      atomicAdd(&pbase[g * 512 + c0 + 1], acc[i][1]);
      atomicAdd(&pbase[g * 512 + c0 + 2], acc[i][2]);
      atomicAdd(&pbase[g * 512 + c0 + 3], acc[i][3]);
    }
  }
}

// ---------------- final: out = pooled @ Wl + bl ----------------
__global__ __launch_bounds__(256) void k_final(const float* __restrict__ pooled,
                                               const float* __restrict__ Wl,
                                               const float* __restrict__ bl,
                                               float* __restrict__ out) {
  int g = blockIdx.x, o = threadIdx.x;
  __shared__ float sp[DH * T_ITERS];
  for (int idx = o; idx < DH * T_ITERS; idx += 256) sp[idx] = pooled[g * (DH * T_ITERS) + idx];
  __syncthreads();
  float acc = bl[o];
#pragma unroll 8
  for (int j = 0; j < DH * T_ITERS; ++j)
    acc = fmaf(sp[j], Wl[j * DOUT + o], acc);
  out[g * DOUT + o] = acc;
}

extern "C" void kernel_launch(void* const* d_in, const int* in_sizes, int n_in,
                              void* d_out, int out_size, void* d_ws, size_t ws_size,
                              hipStream_t stream) {
  const float* x         = (const float*)d_in[0];
  const int*   edge_index= (const int*)d_in[1];
  const float* edge_attr = (const float*)d_in[2];
  const int*   graph_ids = (const int*)d_in[3];
  const float* Wn = (const float*)d_in[4];
  const float* bn = (const float*)d_in[5];
  const float* We = (const float*)d_in[6];
  const float* be = (const float*)d_in[7];
  const float* W1 = (const float*)d_in[8];
  const float* b1 = (const float*)d_in[9];
  const float* W2 = (const float*)d_in[10];
  const float* b2 = (const float*)d_in[11];
  const float* Wl = (const float*)d_in[12];
  const float* bl = (const float*)d_in[13];
  float* out = (float*)d_out;

  char* p = (char*)d_ws;
  auto alloc = [&](size_t bytes) { char* r = p; p += (bytes + 255) & ~(size_t)255; return r; };
  float*  h        = (float*)alloc((size_t)N_NODES * DH * 4);   // fallback path only
  float*  z        = (float*)alloc((size_t)N_NODES * DH * 4);   // primary: zb overlay
  uint32* hb       = (uint32*)alloc((size_t)N_NODES * DH * 2);
  float*  pooled   = (float*)alloc((size_t)N_GRAPHS * DH * T_ITERS * 4);
  int*    counts   = (int*)alloc((size_t)N_NODES * 4);          // reused as w1c/w2c after scan
  int*    row_start= (int*)alloc((size_t)(N_NODES + 1) * 4);
  int*    cursor   = (int*)alloc((size_t)N_NODES * 4);
  int*    src_perm = (int*)alloc((size_t)N_EDGES * 4);
  int*    blk_sums = (int*)alloc(256);
  int*    blk_off  = (int*)alloc(256);

  const int* src = edge_index;
  const int* dst = edge_index + N_EDGES;

  size_t used = (size_t)(p - (char*)d_ws);
  size_t need_ea = used + (size_t)N_EDGES * N_ETYPE * 4 + 4096;   // ea_perm 41 MB

  hipMemsetAsync(counts, 0, (size_t)N_NODES * 4, stream);
  hipMemsetAsync(pooled, 0, (size_t)N_GRAPHS * DH * T_ITERS * 4, stream);

  k_embed<<<N_NODES * DH / 256, 256, 0, stream>>>(x, Wn, bn, h, (ushort16*)hb);
  k_hist<<<N_EDGES / 256, 256, 0, stream>>>(dst, counts);
  k_scan1<<<SCAN_BLK, 1024, 0, stream>>>(counts, row_start, blk_sums);
  k_scan2<<<1, 64, 0, stream>>>(blk_sums, blk_off, row_start);
  k_scan3<<<SCAN_BLK, 1024, 0, stream>>>(row_start, blk_off, cursor);

  if (ws_size >= need_ea) {
    float4* ea_perm = (float4*)alloc((size_t)N_EDGES * N_ETYPE * 4);
    uint32* zb = (uint32*)z;                              // overlay
    ushort16* w1c = (ushort16*)counts;                    // counts dead after scan
    ushort16* w2c = w1c + 16384;
    k_prep_w<<<128, 256, 0, stream>>>(W1, W2, w1c, w2c);
    k_permute_ea<<<N_EDGES / 256, 256, 0, stream>>>(src, dst, (const float4*)edge_attr,
                                                    cursor, src_perm, ea_perm);
    for (int t = 0; t < T_ITERS; ++t) {
      k_agg_rc<<<N_NODES / 4, 256, 0, stream>>>(hb, ea_perm, We, be, row_start, src_perm, zb);
      k_mlp2<<<N_NODES / 16, 64, 0, stream>>>(zb, w1c, w2c, b1, b2, graph_ids,
                                              hb, pooled, t);
    }
  } else {
    int* eid_perm = (int*)alloc((size_t)N_EDGES * 4);
    k_permute<<<N_EDGES / 256, 256, 0, stream>>>(src, dst, cursor, src_perm, eid_perm);
    for (int t = 0; t < T_ITERS; ++t) {
      k_agg_ind<<<N_NODES / 4, 256, 0, stream>>>(h, hb, edge_attr, We, be, row_start, src_perm, eid_perm, z);
      k_mlp<<<N_NODES / 64, 256, 0, stream>>>(z, W1, b1, W2, b2, graph_ids, h, hb, pooled, t);
    }
  }
  k_final<<<N_GRAPHS, 256, 0, stream>>>(pooled, Wl, bl, out);
}

// Round 12
// 479.994 us; speedup vs baseline: 1.5494x; 1.5494x over previous
//
#include <hip/hip_runtime.h>

#define N_NODES   40000
#define N_EDGES   640000
#define N_GRAPHS  64
#define DIM_IN    32
#define N_ETYPE   16
#define DH        128
#define DOUT      256
#define T_ITERS   4
#define SCAN_BLK  40          // ceil(40000/1024)

typedef unsigned int uint32;
typedef unsigned short ushort16;
typedef __attribute__((ext_vector_type(8))) short bf16x8;
typedef __attribute__((ext_vector_type(4))) float f32x4;

__device__ __forceinline__ uint32 f2bf1(float f) {
  uint32 u = __float_as_uint(f);
  return (u + 0x7fffu + ((u >> 16) & 1u)) >> 16;
}
__device__ __forceinline__ uint32 pack_bf2(float lo, float hi) {
  return (f2bf1(hi) << 16) | f2bf1(lo);
}
#define UPLO(u) __uint_as_float((u) << 16)
#define UPHI(u) __uint_as_float((u) & 0xffff0000u)

// ---------------- node embedding: h = x @ Wn + bn (fp32 + bf16 mirror) ----------------
__global__ __launch_bounds__(256) void k_embed(const float* __restrict__ x,
                                               const float* __restrict__ Wn,
                                               const float* __restrict__ bn,
                                               float* __restrict__ h,
                                               ushort16* __restrict__ hb) {
  int idx = blockIdx.x * 256 + threadIdx.x;     // n*128 + c, exact grid
  int n = idx >> 7, c = idx & 127;
  const float* xr = x + n * DIM_IN;
  float acc = bn[c];
#pragma unroll
  for (int k = 0; k < DIM_IN; ++k)
    acc = fmaf(xr[k], Wn[k * DH + c], acc);
  h[idx] = acc;
  hb[idx] = (ushort16)f2bf1(acc);
}

// ---------------- CSR build ----------------
__global__ __launch_bounds__(256) void k_hist(const int* __restrict__ dst,
                                              int* __restrict__ counts) {
  int i = blockIdx.x * 256 + threadIdx.x;
  atomicAdd(&counts[dst[i]], 1);
}

// ---- 3-pass parallel scan ----
__global__ __launch_bounds__(1024) void k_scan1(const int* __restrict__ counts,
                                                int* __restrict__ excl,      // = row_start
                                                int* __restrict__ blk_sums) {
  __shared__ int wsums[16];
  int tid = threadIdx.x, lane = tid & 63, w = tid >> 6;
  int i = blockIdx.x * 1024 + tid;
  int v = (i < N_NODES) ? counts[i] : 0;
  int s = v;
#pragma unroll
  for (int off = 1; off < 64; off <<= 1) {
    int t = __shfl_up(s, off);
    if (lane >= off) s += t;
  }
  if (lane == 63) wsums[w] = s;
  __syncthreads();
  if (tid < 16) {
    int ws_ = wsums[tid];
#pragma unroll
    for (int off = 1; off < 16; off <<= 1) {
      int t = __shfl_up(ws_, off);
      if (tid >= off) ws_ += t;
    }
    wsums[tid] = ws_;
  }
  __syncthreads();
  int e = s - v + (w ? wsums[w - 1] : 0);
  if (i < N_NODES) excl[i] = e;
  if (tid == 0) blk_sums[blockIdx.x] = wsums[15];
}

__global__ __launch_bounds__(64) void k_scan2(const int* __restrict__ blk_sums,
                                              int* __restrict__ blk_off,
                                              int* __restrict__ row_start) {
  int lane = threadIdx.x;
  int v = (lane < SCAN_BLK) ? blk_sums[lane] : 0;
  int s = v;
#pragma unroll
  for (int off = 1; off < 64; off <<= 1) {
    int t = __shfl_up(s, off);
    if (lane >= off) s += t;
  }
  if (lane < SCAN_BLK) blk_off[lane] = s - v;
  if (lane == 63) row_start[N_NODES] = s;
}

__global__ __launch_bounds__(1024) void k_scan3(int* __restrict__ row_start,
                                                const int* __restrict__ blk_off,
                                                int* __restrict__ cursor) {
  int i = blockIdx.x * 1024 + threadIdx.x;
  if (i < N_NODES) {
    int v = row_start[i] + blk_off[blockIdx.x];
    row_start[i] = v;
    cursor[i] = v;
  }
}

__global__ __launch_bounds__(256) void k_permute(const int* __restrict__ src,
                                                 const int* __restrict__ dst,
                                                 int* __restrict__ cursor,
                                                 int* __restrict__ src_perm,
                                                 int* __restrict__ eid_perm) {
  int i = blockIdx.x * 256 + threadIdx.x;
  int d = dst[i];
  int pos = atomicAdd(&cursor[d], 1);
  src_perm[pos] = src[i];
  eid_perm[pos] = i;
}

#define MAC16(A0,A1,A2,A3)                                          \
  p0 = fmaf(A0.x, we0[0], p0);  p1 = fmaf(A0.x, we1[0], p1);        \
  p0 = fmaf(A0.y, we0[1], p0);  p1 = fmaf(A0.y, we1[1], p1);        \
  p0 = fmaf(A0.z, we0[2], p0);  p1 = fmaf(A0.z, we1[2], p1);        \
  p0 = fmaf(A0.w, we0[3], p0);  p1 = fmaf(A0.w, we1[3], p1);        \
  p0 = fmaf(A1.x, we0[4], p0);  p1 = fmaf(A1.x, we1[4], p1);        \
  p0 = fmaf(A1.y, we0[5], p0);  p1 = fmaf(A1.y, we1[5], p1);        \
  p0 = fmaf(A1.z, we0[6], p0);  p1 = fmaf(A1.z, we1[6], p1);        \
  p0 = fmaf(A1.w, we0[7], p0);  p1 = fmaf(A1.w, we1[7], p1);        \
  p0 = fmaf(A2.x, we0[8], p0);  p1 = fmaf(A2.x, we1[8], p1);        \
  p0 = fmaf(A2.y, we0[9], p0);  p1 = fmaf(A2.y, we1[9], p1);        \
  p0 = fmaf(A2.z, we0[10], p0); p1 = fmaf(A2.z, we1[10], p1);       \
  p0 = fmaf(A2.w, we0[11], p0); p1 = fmaf(A2.w, we1[11], p1);       \
  p0 = fmaf(A3.x, we0[12], p0); p1 = fmaf(A3.x, we1[12], p1);       \
  p0 = fmaf(A3.y, we0[13], p0); p1 = fmaf(A3.y, we1[13], p1);       \
  p0 = fmaf(A3.z, we0[14], p0); p1 = fmaf(A3.z, we1[14], p1);       \
  p0 = fmaf(A3.w, we0[15], p0); p1 = fmaf(A3.w, we1[15], p1);

#define RELU_ACC(G)                                                  \
  acc0 += fmaxf(UPLO(G) + p0, 0.0f);                                 \
  acc1 += fmaxf(UPHI(G) + p1, 0.0f);

// ---- one-time merged pass: CSR permute + e_perm[pos] = bf16(edge_attr[i]@We + be) ----
__global__ __launch_bounds__(256) void k_perm_e(const int* __restrict__ src,
                                                const int* __restrict__ dst,
                                                const float4* __restrict__ edge_attr,
                                                const float* __restrict__ We,
                                                const float* __restrict__ be,
                                                int* __restrict__ cursor,
                                                int* __restrict__ src_perm,
                                                uint32* __restrict__ e_perm) {
  __shared__ float4 sAttr[1024];     // 256 edges x 16 floats = 16 KB
  __shared__ int spos[256];
  int tid = threadIdx.x;
  int i = blockIdx.x * 256 + tid;
  int d = dst[i];
  int pos = atomicAdd(&cursor[d], 1);
  src_perm[pos] = src[i];
  spos[tid] = pos;
  size_t blockBase = (size_t)blockIdx.x * 1024;   // float4 units
  for (int idx = tid; idx < 1024; idx += 256)
    sAttr[idx] = edge_attr[blockBase + idx];
  __syncthreads();
  int lane = tid & 63, wv = tid >> 6;
  int c = lane << 1;
  float we0[N_ETYPE], we1[N_ETYPE];
#pragma unroll
  for (int k = 0; k < N_ETYPE; ++k) {
    we0[k] = We[k * DH + c];
    we1[k] = We[k * DH + c + 1];
  }
  float be0 = be[c], be1 = be[c + 1];
  const float4* a = &sAttr[wv << 8];   // 64 edges x 4 float4
  const int* wp = &spos[wv << 6];
#pragma unroll 2
  for (int j = 0; j < 64; ++j) {
    int pos_j = wp[j];
    float4 a0 = a[j * 4 + 0], a1 = a[j * 4 + 1], a2 = a[j * 4 + 2], a3 = a[j * 4 + 3];
    float p0 = be0, p1 = be1;
    MAC16(a0, a1, a2, a3)
    e_perm[((size_t)pos_j << 6) + lane] = pack_bf2(p0, p1);
  }
}

// -------- aggregation, pair path: 2 edges / load instruction --------
// lane l (ll=l&31, half=l>>5) owns cols 4ll..4ll+3 of edge i+half (uint2 loads).
// Even/odd partial sums combined via shfl_xor(32); lanes 0-31 write the zb row.
#define ACCP(G, E)                                                   \
  acc0 += fmaxf(UPLO((G).x) + UPLO((E).x), 0.0f);                    \
  acc1 += fmaxf(UPHI((G).x) + UPHI((E).x), 0.0f);                    \
  acc2 += fmaxf(UPLO((G).y) + UPLO((E).y), 0.0f);                    \
  acc3 += fmaxf(UPHI((G).y) + UPHI((E).y), 0.0f);

__global__ __launch_bounds__(256) void k_agg_lite2(const uint32* __restrict__ hb,
                                                   const uint32* __restrict__ e_perm,
                                                   const int* __restrict__ row_start,
                                                   const int* __restrict__ src_perm,
                                                   uint32* __restrict__ zb) {
  int l = threadIdx.x & 63;
  int n = (blockIdx.x << 2) + (threadIdx.x >> 6);
  int ll = l & 31, half = l >> 5;
  uint2 hself = *(const uint2*)&hb[((size_t)n << 6) + 2 * ll];
  float acc0, acc1, acc2, acc3;
  if (half == 0) {
    acc0 = UPLO(hself.x); acc1 = UPHI(hself.x);
    acc2 = UPLO(hself.y); acc3 = UPHI(hself.y);
  } else {
    acc0 = acc1 = acc2 = acc3 = 0.0f;
  }
  int beg = row_start[n], end = row_start[n + 1];
  const uint32* ep = e_perm + ((size_t)beg << 6) + 2 * ll;
  const int* sp = src_perm + beg;
  int m = end - beg;
  int i = 0;
  for (; i + 16 <= m; i += 16, ep += 1024, sp += 16) {
    int ss[8]; uint2 gg[8], ee[8];
#pragma unroll
    for (int p = 0; p < 8; ++p) ss[p] = sp[2 * p + half];
#pragma unroll
    for (int p = 0; p < 8; ++p) gg[p] = *(const uint2*)&hb[((size_t)ss[p] << 6) + 2 * ll];
#pragma unroll
    for (int p = 0; p < 8; ++p) ee[p] = *(const uint2*)&ep[(size_t)(2 * p + half) << 6];
#pragma unroll
    for (int p = 0; p < 8; ++p) { ACCP(gg[p], ee[p]) }
  }
  for (; i + 2 <= m; i += 2, ep += 128, sp += 2) {
    int s = sp[half];
    uint2 g = *(const uint2*)&hb[((size_t)s << 6) + 2 * ll];
    uint2 e = *(const uint2*)&ep[(size_t)half << 6];
    ACCP(g, e)
  }
  if (i < m) {     // odd tail: half 0 only
    int s = sp[0];
    uint2 g = *(const uint2*)&hb[((size_t)s << 6) + 2 * ll];
    uint2 e = *(const uint2*)&ep[0];
    if (half == 0) { ACCP(g, e) }
  }
  // combine even/odd halves
  acc0 += __shfl_xor(acc0, 32);
  acc1 += __shfl_xor(acc1, 32);
  acc2 += __shfl_xor(acc2, 32);
  acc3 += __shfl_xor(acc3, 32);
  if (half == 0) {
    uint2 o;
    o.x = pack_bf2(acc0, acc1);
    o.y = pack_bf2(acc2, acc3);
    *(uint2*)&zb[((size_t)n << 6) + 2 * ll] = o;
  }
}

// ---- one-time: W1,W2 -> bf16 fragment-major layout for MFMA B operands ----
// wc[(k0*8+n)*512 + l*8 + j] = bf16(W[k0*32 + (l>>4)*8 + j][n*16 + (l&15)])
__global__ __launch_bounds__(256) void k_prep_w(const float* __restrict__ W1,
                                                const float* __restrict__ W2,
                                                ushort16* __restrict__ w1c,
                                                ushort16* __restrict__ w2c) {
  int id = blockIdx.x * 256 + threadIdx.x;   // 0..32767
  int which = id >> 14;
  int rem = id & 16383;
  int j = rem & 7, lg = (rem >> 3) & 63, n = (rem >> 9) & 7, k0 = rem >> 12;
  int r = lg & 15, g = lg >> 4;
  const float* W = which ? W2 : W1;
  ushort16* wc = which ? w2c : w1c;
  wc[rem] = (ushort16)f2bf1(W[(k0 * 32 + g * 8 + j) * 128 + n * 16 + r]);
}

// ---------------- slim MFMA MLP: 1 wave / 16 nodes, 2500 blocks ----------------
__global__ __launch_bounds__(64) void k_mlp2(const uint32* __restrict__ zb,
                                             const ushort16* __restrict__ w1c,
                                             const ushort16* __restrict__ w2c,
                                             const float* __restrict__ b1,
                                             const float* __restrict__ b2,
                                             const int* __restrict__ graph_ids,
                                             uint32* __restrict__ hb_out,
                                             float* __restrict__ pooled,
                                             int t_slot) {
  __shared__ ushort16 sA[16 * 136];   // 4352 B
  int l = threadIdx.x;                // 0..63
  int rb = blockIdx.x * 16;

  for (int idx = l; idx < 256; idx += 64) {
    int row = idx >> 4, ch = idx & 15;
    *(uint4*)&sA[row * 136 + ch * 8] = *(const uint4*)&zb[(size_t)(rb + row) * 64 + ch * 4];
  }
  __syncthreads();

  int r = l & 15, g = l >> 4;
  const ushort16* aBase = &sA[0] + r * 136 + g * 8;

  f32x4 acc[8];
#pragma unroll
  for (int n = 0; n < 8; ++n) {
    float bv = b1[n * 16 + r];
    acc[n] = (f32x4){bv, bv, bv, bv};
  }
#pragma unroll
  for (int k0 = 0; k0 < 4; ++k0) {
    bf16x8 a = *(const bf16x8*)(aBase + k0 * 32);
#pragma unroll
    for (int n = 0; n < 8; ++n) {
      bf16x8 b = *(const bf16x8*)(w1c + (k0 * 8 + n) * 512 + l * 8);
      acc[n] = __builtin_amdgcn_mfma_f32_16x16x32_bf16(a, b, acc[n], 0, 0, 0);
    }
  }

  __syncthreads();
#pragma unroll
  for (int n = 0; n < 8; ++n)
#pragma unroll
    for (int q = 0; q < 4; ++q)
      sA[(g * 4 + q) * 136 + n * 16 + r] = (ushort16)f2bf1(fmaxf(acc[n][q], 0.0f));
  __syncthreads();

#pragma unroll
  for (int n = 0; n < 8; ++n) {
    float bv = b2[n * 16 + r];
    acc[n] = (f32x4){bv, bv, bv, bv};
  }
#pragma unroll
  for (int k0 = 0; k0 < 4; ++k0) {
    bf16x8 a = *(const bf16x8*)(aBase + k0 * 32);
#pragma unroll
    for (int n = 0; n < 8; ++n) {
      bf16x8 b = *(const bf16x8*)(w2c + (k0 * 8 + n) * 512 + l * 8);
      acc[n] = __builtin_amdgcn_mfma_f32_16x16x32_bf16(a, b, acc[n], 0, 0, 0);
    }
  }

  float* pbase = pooled + t_slot * DH;
  int gid0 = graph_ids[rb];
  if (gid0 == graph_ids[rb + 15]) {
#pragma unroll
    for (int n = 0; n < 8; ++n) {
      float s = acc[n][0] + acc[n][1] + acc[n][2] + acc[n][3];
      s += __shfl_xor(s, 16);
      s += __shfl_xor(s, 32);
      if (l < 16) atomicAdd(&pbase[gid0 * 512 + n * 16 + r], s);
    }
  } else {
#pragma unroll
    for (int q = 0; q < 4; ++q) {
      int node = rb + g * 4 + q;
      int gg = graph_ids[node];
#pragma unroll
      for (int n = 0; n < 8; ++n)
        atomicAdd(&pbase[gg * 512 + n * 16 + r], acc[n][q]);
    }
  }

  __syncthreads();
#pragma unroll
  for (int n = 0; n < 8; ++n)
#pragma unroll
    for (int q = 0; q < 4; ++q)
      sA[(g * 4 + q) * 136 + n * 16 + r] = (ushort16)f2bf1(acc[n][q]);
  __syncthreads();
  for (int idx = l; idx < 1024; idx += 64) {   // 16 rows x 64 dwords
    int row = idx >> 6, dw = idx & 63;
    uint32 v = *(const uint32*)&sA[row * 136 + dw * 2];
    hb_out[(size_t)(rb + row) * 64 + dw] = v;
  }
}

// -------- aggregation, fallback indirect path --------
__global__ __launch_bounds__(256, 8) void k_agg_ind(const float* __restrict__ h,
                                                    const uint32* __restrict__ hb,
                                                    const float* __restrict__ edge_attr,
                                                    const float* __restrict__ We,
                                                    const float* __restrict__ be,
                                                    const int* __restrict__ row_start,
                                                    const int* __restrict__ src_perm,
                                                    const int* __restrict__ eid_perm,
                                                    float* __restrict__ z) {
  int lane = threadIdx.x & 63;
  int n = (blockIdx.x << 2) + (threadIdx.x >> 6);
  int c = lane << 1;
  float we0[N_ETYPE], we1[N_ETYPE];
#pragma unroll
  for (int k = 0; k < N_ETYPE; ++k) {
    we0[k] = We[k * DH + c];
    we1[k] = We[k * DH + c + 1];
  }
  float be0 = be[c], be1 = be[c + 1];
  float2 hself = *(const float2*)&h[(size_t)n * DH + c];
  float acc0 = hself.x, acc1 = hself.y;
  int beg = row_start[n], end = row_start[n + 1];
  int i = beg;
  for (; i + 1 < end; i += 2) {
    int s0 = src_perm[i], s1 = src_perm[i + 1];
    int e0i = eid_perm[i], e1i = eid_perm[i + 1];
    uint32 g0 = hb[((size_t)s0 << 6) + lane];
    uint32 g1 = hb[((size_t)s1 << 6) + lane];
    const float4* eA = (const float4*)(edge_attr + (size_t)e0i * N_ETYPE);
    const float4* eB = (const float4*)(edge_attr + (size_t)e1i * N_ETYPE);
    float4 a0 = eA[0], a1 = eA[1], a2 = eA[2], a3 = eA[3];
    float p0, p1;
    p0 = be0; p1 = be1; MAC16(a0, a1, a2, a3) RELU_ACC(g0)
    float4 b0 = eB[0], b1v = eB[1], b2v = eB[2], b3 = eB[3];
    p0 = be0; p1 = be1; MAC16(b0, b1v, b2v, b3) RELU_ACC(g1)
  }
  if (i < end) {
    int s0 = src_perm[i];
    int e0i = eid_perm[i];
    uint32 g0 = hb[((size_t)s0 << 6) + lane];
    const float4* eA = (const float4*)(edge_attr + (size_t)e0i * N_ETYPE);
    float4 a0 = eA[0], a1 = eA[1], a2 = eA[2], a3 = eA[3];
    float p0 = be0, p1 = be1;
    MAC16(a0, a1, a2, a3) RELU_ACC(g0)
  }
  *(float2*)&z[(size_t)n * DH + c] = make_float2(acc0, acc1);
}

// ---------------- fallback fp32 MLP ----------------
#define MLPFMA(K, U0, U1)                                            \
  {                                                                  \
    _Pragma("unroll")                                                \
    for (int i_ = 0; i_ < 8; ++i_) {                                 \
      float2 a_ = *(const float2*)&sA[(r0 + i_) * 132 + (K)];        \
      acc[i_][0] = fmaf(a_.x, U0.x, acc[i_][0]);                     \
      acc[i_][1] = fmaf(a_.x, U0.y, acc[i_][1]);                     \
      acc[i_][2] = fmaf(a_.x, U0.z, acc[i_][2]);                     \
      acc[i_][3] = fmaf(a_.x, U0.w, acc[i_][3]);                     \
      acc[i_][0] = fmaf(a_.y, U1.x, acc[i_][0]);                     \
      acc[i_][1] = fmaf(a_.y, U1.y, acc[i_][1]);                     \
      acc[i_][2] = fmaf(a_.y, U1.z, acc[i_][2]);                     \
      acc[i_][3] = fmaf(a_.y, U1.w, acc[i_][3]);                     \
    }                                                                \
  }

__device__ __forceinline__ void gemm_tile_g(const float* sA, const float4* __restrict__ Wv,
                                            float acc[8][4], int r0, int cg) {
  float4 c0 = Wv[cg],       c1 = Wv[32 + cg];
  float4 n0 = Wv[64 + cg],  n1 = Wv[96 + cg];
#pragma unroll 4
  for (int k = 0; k < DH - 4; k += 2) {
    float4 u0 = c0, u1 = c1;
    c0 = n0; c1 = n1;
    n0 = Wv[(k + 4) * 32 + cg];
    n1 = Wv[(k + 5) * 32 + cg];
    MLPFMA(k, u0, u1)
  }
  MLPFMA(DH - 4, c0, c1)
  MLPFMA(DH - 2, n0, n1)
}

__global__ __launch_bounds__(256) void k_mlp(const float* __restrict__ z,
                                             const float* __restrict__ W1,
                                             const float* __restrict__ b1,
                                             const float* __restrict__ W2,
                                             const float* __restrict__ b2,
                                             const int* __restrict__ graph_ids,
                                             float* __restrict__ h_out,
                                             uint32* __restrict__ hb_out,
                                             float* __restrict__ pooled,
                                             int t_slot) {
  __shared__ float sA[64 * 132];
  int tid = threadIdx.x;
  int rb = blockIdx.x * 64;
  for (int idx = tid; idx < 64 * 32; idx += 256) {
    int r = idx >> 5, kq = (idx & 31) << 2;
    *(float4*)&sA[r * 132 + kq] = *(const float4*)&z[(size_t)(rb + r) * DH + kq];
  }
  __syncthreads();

  int cg = tid & 31, rg = tid >> 5;
  int c0 = cg << 2, r0 = rg << 3;
  float acc[8][4];
  {
    float4 bb = *(const float4*)&b1[c0];
#pragma unroll
    for (int i = 0; i < 8; ++i) { acc[i][0] = bb.x; acc[i][1] = bb.y; acc[i][2] = bb.z; acc[i][3] = bb.w; }
  }
  gemm_tile_g(sA, (const float4*)W1, acc, r0, cg);
  __syncthreads();
#pragma unroll
  for (int i = 0; i < 8; ++i) {
    float4 v;
    v.x = fmaxf(acc[i][0], 0.0f); v.y = fmaxf(acc[i][1], 0.0f);
    v.z = fmaxf(acc[i][2], 0.0f); v.w = fmaxf(acc[i][3], 0.0f);
    *(float4*)&sA[(r0 + i) * 132 + c0] = v;
  }
  __syncthreads();
  {
    float4 bb = *(const float4*)&b2[c0];
#pragma unroll
    for (int i = 0; i < 8; ++i) { acc[i][0] = bb.x; acc[i][1] = bb.y; acc[i][2] = bb.z; acc[i][3] = bb.w; }
  }
  gemm_tile_g(sA, (const float4*)W2, acc, r0, cg);

  int node0 = rb + r0;
#pragma unroll
  for (int i = 0; i < 8; ++i) {
    float4 v = make_float4(acc[i][0], acc[i][1], acc[i][2], acc[i][3]);
    *(float4*)&h_out[(size_t)(node0 + i) * DH + c0] = v;
    uint2 hv;
    hv.x = pack_bf2(acc[i][0], acc[i][1]);
    hv.y = pack_bf2(acc[i][2], acc[i][3]);
    *(uint2*)&hb_out[(size_t)(node0 + i) * 64 + (c0 >> 1)] = hv;
  }
  float* pbase = pooled + t_slot * DH;
  int g_first = graph_ids[node0];
  int g_last = graph_ids[node0 + 7];
  if (g_first == g_last) {
    float s0 = 0.f, s1 = 0.f, s2 = 0.f, s3 = 0.f;
#pragma unroll
    for (int i = 0; i < 8; ++i) { s0 += acc[i][0]; s1 += acc[i][1]; s2 += acc[i][2]; s3 += acc[i][3]; }
    atomicAdd(&pbase[g_first * 512 + c0 + 0], s0);
    atomicAdd(&pbase[g_first * 512 + c0 + 1], s1);
    atomicAdd(&pbase[g_first * 512 + c0 + 2], s2);
    atomicAdd(&pbase[g_first * 512 + c0 + 3], s3);
  } else {
#pragma unroll
    for (int i = 0; i < 8; ++i) {
      int g = graph_ids[node0 + i];
      atomicAdd(&pbase[g * 512 + c0 + 0], acc[i][0]);
      atomicAdd(&pbase[g * 512 + c0 + 1], acc[i][1]);
      atomicAdd(&pbase[g * 512 + c0 + 2], acc[i][2]);
      atomicAdd(&pbase[g * 512 + c0 + 3], acc[i][3]);
    }
  }
}

// ---------------- final: out = pooled @ Wl + bl ----------------
__global__ __launch_bounds__(256) void k_final(const float* __restrict__ pooled,
                                               const float* __restrict__ Wl,
                                               const float* __restrict__ bl,
                                               float* __restrict__ out) {
  int g = blockIdx.x, o = threadIdx.x;
  __shared__ float sp[DH * T_ITERS];
  for (int idx = o; idx < DH * T_ITERS; idx += 256) sp[idx] = pooled[g * (DH * T_ITERS) + idx];
  __syncthreads();
  float acc = bl[o];
#pragma unroll 8
  for (int j = 0; j < DH * T_ITERS; ++j)
    acc = fmaf(sp[j], Wl[j * DOUT + o], acc);
  out[g * DOUT + o] = acc;
}

extern "C" void kernel_launch(void* const* d_in, const int* in_sizes, int n_in,
                              void* d_out, int out_size, void* d_ws, size_t ws_size,
                              hipStream_t stream) {
  const float* x         = (const float*)d_in[0];
  const int*   edge_index= (const int*)d_in[1];
  const float* edge_attr = (const float*)d_in[2];
  const int*   graph_ids = (const int*)d_in[3];
  const float* Wn = (const float*)d_in[4];
  const float* bn = (const float*)d_in[5];
  const float* We = (const float*)d_in[6];
  const float* be = (const float*)d_in[7];
  const float* W1 = (const float*)d_in[8];
  const float* b1 = (const float*)d_in[9];
  const float* W2 = (const float*)d_in[10];
  const float* b2 = (const float*)d_in[11];
  const float* Wl = (const float*)d_in[12];
  const float* bl = (const float*)d_in[13];
  float* out = (float*)d_out;

  char* p = (char*)d_ws;
  auto alloc = [&](size_t bytes) { char* r = p; p += (bytes + 255) & ~(size_t)255; return r; };
  float*  h        = (float*)alloc((size_t)N_NODES * DH * 4);   // fallback path only
  float*  z        = (float*)alloc((size_t)N_NODES * DH * 4);   // primary: zb overlay
  uint32* hb       = (uint32*)alloc((size_t)N_NODES * DH * 2);
  float*  pooled   = (float*)alloc((size_t)N_GRAPHS * DH * T_ITERS * 4);
  int*    counts   = (int*)alloc((size_t)N_NODES * 4);          // reused as w1c/w2c after scan
  int*    row_start= (int*)alloc((size_t)(N_NODES + 1) * 4);
  int*    cursor   = (int*)alloc((size_t)N_NODES * 4);
  int*    src_perm = (int*)alloc((size_t)N_EDGES * 4);
  int*    blk_sums = (int*)alloc(256);
  int*    blk_off  = (int*)alloc(256);

  const int* src = edge_index;
  const int* dst = edge_index + N_EDGES;

  size_t used = (size_t)(p - (char*)d_ws);
  size_t need_e = used + (size_t)N_EDGES * DH * 2 + 4096;   // e_perm 160 MB

  hipMemsetAsync(counts, 0, (size_t)N_NODES * 4, stream);
  hipMemsetAsync(pooled, 0, (size_t)N_GRAPHS * DH * T_ITERS * 4, stream);

  k_embed<<<N_NODES * DH / 256, 256, 0, stream>>>(x, Wn, bn, h, (ushort16*)hb);
  k_hist<<<N_EDGES / 256, 256, 0, stream>>>(dst, counts);
  k_scan1<<<SCAN_BLK, 1024, 0, stream>>>(counts, row_start, blk_sums);
  k_scan2<<<1, 64, 0, stream>>>(blk_sums, blk_off, row_start);
  k_scan3<<<SCAN_BLK, 1024, 0, stream>>>(row_start, blk_off, cursor);

  if (ws_size >= need_e) {
    uint32* e_perm = (uint32*)alloc((size_t)N_EDGES * DH * 2);
    uint32* zb = (uint32*)z;                              // overlay
    ushort16* w1c = (ushort16*)counts;                    // counts dead after scan
    ushort16* w2c = w1c + 16384;
    k_prep_w<<<128, 256, 0, stream>>>(W1, W2, w1c, w2c);
    k_perm_e<<<N_EDGES / 256, 256, 0, stream>>>(src, dst, (const float4*)edge_attr,
                                                We, be, cursor, src_perm, e_perm);
    for (int t = 0; t < T_ITERS; ++t) {
      k_agg_lite2<<<N_NODES / 4, 256, 0, stream>>>(hb, e_perm, row_start, src_perm, zb);
      k_mlp2<<<N_NODES / 16, 64, 0, stream>>>(zb, w1c, w2c, b1, b2, graph_ids,
                                              hb, pooled, t);
    }
  } else {
    int* eid_perm = (int*)alloc((size_t)N_EDGES * 4);
    k_permute<<<N_EDGES / 256, 256, 0, stream>>>(src, dst, cursor, src_perm, eid_perm);
    for (int t = 0; t < T_ITERS; ++t) {
      k_agg_ind<<<N_NODES / 4, 256, 0, stream>>>(h, hb, edge_attr, We, be, row_start, src_perm, eid_perm, z);
      k_mlp<<<N_NODES / 64, 256, 0, stream>>>(z, W1, b1, W2, b2, graph_ids, h, (uint32*)hb, pooled, t);
    }
  }
  k_final<<<N_GRAPHS, 256, 0, stream>>>(pooled, Wl, bl, out);
}

// Round 13
// 463.753 us; speedup vs baseline: 1.6037x; 1.0350x over previous
//
#include <hip/hip_runtime.h>

#define N_NODES   40000
#define N_EDGES   640000
#define N_GRAPHS  64
#define DIM_IN    32
#define N_ETYPE   16
#define DH        128
#define DOUT      256
#define T_ITERS   4
#define SCAN_BLK  40          // ceil(40000/1024)

typedef unsigned int uint32;
typedef unsigned short ushort16;
typedef __attribute__((ext_vector_type(8))) short bf16x8;
typedef __attribute__((ext_vector_type(4))) float f32x4;

__device__ __forceinline__ uint32 f2bf1(float f) {
  uint32 u = __float_as_uint(f);
  return (u + 0x7fffu + ((u >> 16) & 1u)) >> 16;
}
__device__ __forceinline__ uint32 pack_bf2(float lo, float hi) {
  return (f2bf1(hi) << 16) | f2bf1(lo);
}

// ---------------- node embedding: h = x @ Wn + bn (fp32 + bf16 mirror) ----------------
__global__ __launch_bounds__(256) void k_embed(const float* __restrict__ x,
                                               const float* __restrict__ Wn,
                                               const float* __restrict__ bn,
                                               float* __restrict__ h,
                                               ushort16* __restrict__ hb) {
  int idx = blockIdx.x * 256 + threadIdx.x;     // n*128 + c, exact grid
  int n = idx >> 7, c = idx & 127;
  const float* xr = x + n * DIM_IN;
  float acc = bn[c];
#pragma unroll
  for (int k = 0; k < DIM_IN; ++k)
    acc = fmaf(xr[k], Wn[k * DH + c], acc);
  h[idx] = acc;
  hb[idx] = (ushort16)f2bf1(acc);
}

// ---------------- CSR build ----------------
__global__ __launch_bounds__(256) void k_hist(const int* __restrict__ dst,
                                              int* __restrict__ counts) {
  int i = blockIdx.x * 256 + threadIdx.x;
  atomicAdd(&counts[dst[i]], 1);
}

// ---- 3-pass parallel scan ----
__global__ __launch_bounds__(1024) void k_scan1(const int* __restrict__ counts,
                                                int* __restrict__ excl,      // = row_start
                                                int* __restrict__ blk_sums) {
  __shared__ int wsums[16];
  int tid = threadIdx.x, lane = tid & 63, w = tid >> 6;
  int i = blockIdx.x * 1024 + tid;
  int v = (i < N_NODES) ? counts[i] : 0;
  int s = v;
#pragma unroll
  for (int off = 1; off < 64; off <<= 1) {
    int t = __shfl_up(s, off);
    if (lane >= off) s += t;
  }
  if (lane == 63) wsums[w] = s;
  __syncthreads();
  if (tid < 16) {
    int ws_ = wsums[tid];
#pragma unroll
    for (int off = 1; off < 16; off <<= 1) {
      int t = __shfl_up(ws_, off);
      if (tid >= off) ws_ += t;
    }
    wsums[tid] = ws_;
  }
  __syncthreads();
  int e = s - v + (w ? wsums[w - 1] : 0);
  if (i < N_NODES) excl[i] = e;
  if (tid == 0) blk_sums[blockIdx.x] = wsums[15];
}

__global__ __launch_bounds__(64) void k_scan2(const int* __restrict__ blk_sums,
                                              int* __restrict__ blk_off,
                                              int* __restrict__ row_start) {
  int lane = threadIdx.x;
  int v = (lane < SCAN_BLK) ? blk_sums[lane] : 0;
  int s = v;
#pragma unroll
  for (int off = 1; off < 64; off <<= 1) {
    int t = __shfl_up(s, off);
    if (lane >= off) s += t;
  }
  if (lane < SCAN_BLK) blk_off[lane] = s - v;
  if (lane == 63) row_start[N_NODES] = s;
}

__global__ __launch_bounds__(1024) void k_scan3(int* __restrict__ row_start,
                                                const int* __restrict__ blk_off,
                                                int* __restrict__ cursor) {
  int i = blockIdx.x * 1024 + threadIdx.x;
  if (i < N_NODES) {
    int v = row_start[i] + blk_off[blockIdx.x];
    row_start[i] = v;
    cursor[i] = v;
  }
}

__global__ __launch_bounds__(256) void k_permute(const int* __restrict__ src,
                                                 const int* __restrict__ dst,
                                                 int* __restrict__ cursor,
                                                 int* __restrict__ src_perm,
                                                 int* __restrict__ eid_perm) {
  int i = blockIdx.x * 256 + threadIdx.x;
  int d = dst[i];
  int pos = atomicAdd(&cursor[d], 1);
  src_perm[pos] = src[i];
  eid_perm[pos] = i;
}

#define MAC16(A0,A1,A2,A3)                                          \
  p0 = fmaf(A0.x, we0[0], p0);  p1 = fmaf(A0.x, we1[0], p1);        \
  p0 = fmaf(A0.y, we0[1], p0);  p1 = fmaf(A0.y, we1[1], p1);        \
  p0 = fmaf(A0.z, we0[2], p0);  p1 = fmaf(A0.z, we1[2], p1);        \
  p0 = fmaf(A0.w, we0[3], p0);  p1 = fmaf(A0.w, we1[3], p1);        \
  p0 = fmaf(A1.x, we0[4], p0);  p1 = fmaf(A1.x, we1[4], p1);        \
  p0 = fmaf(A1.y, we0[5], p0);  p1 = fmaf(A1.y, we1[5], p1);        \
  p0 = fmaf(A1.z, we0[6], p0);  p1 = fmaf(A1.z, we1[6], p1);        \
  p0 = fmaf(A1.w, we0[7], p0);  p1 = fmaf(A1.w, we1[7], p1);        \
  p0 = fmaf(A2.x, we0[8], p0);  p1 = fmaf(A2.x, we1[8], p1);        \
  p0 = fmaf(A2.y, we0[9], p0);  p1 = fmaf(A2.y, we1[9], p1);        \
  p0 = fmaf(A2.z, we0[10], p0); p1 = fmaf(A2.z, we1[10], p1);       \
  p0 = fmaf(A2.w, we0[11], p0); p1 = fmaf(A2.w, we1[11], p1);       \
  p0 = fmaf(A3.x, we0[12], p0); p1 = fmaf(A3.x, we1[12], p1);       \
  p0 = fmaf(A3.y, we0[13], p0); p1 = fmaf(A3.y, we1[13], p1);       \
  p0 = fmaf(A3.z, we0[14], p0); p1 = fmaf(A3.z, we1[14], p1);       \
  p0 = fmaf(A3.w, we0[15], p0); p1 = fmaf(A3.w, we1[15], p1);

#define RELU_ACC(G)                                                  \
  acc0 += fmaxf(__uint_as_float((G) << 16) + p0, 0.0f);              \
  acc1 += fmaxf(__uint_as_float((G) & 0xffff0000u) + p1, 0.0f);

#define ACC2(G,E)                                                                 \
  acc0 += fmaxf(__uint_as_float((G) << 16) + __uint_as_float((E) << 16), 0.0f);   \
  acc1 += fmaxf(__uint_as_float((G) & 0xffff0000u) +                              \
                __uint_as_float((E) & 0xffff0000u), 0.0f);

// ---- one-time merged pass: CSR permute + e_perm[pos] = bf16(edge_attr[i]@We + be) ----
__global__ __launch_bounds__(256) void k_perm_e(const int* __restrict__ src,
                                                const int* __restrict__ dst,
                                                const float4* __restrict__ edge_attr,
                                                const float* __restrict__ We,
                                                const float* __restrict__ be,
                                                int* __restrict__ cursor,
                                                int* __restrict__ src_perm,
                                                uint32* __restrict__ e_perm) {
  __shared__ float4 sAttr[1024];     // 256 edges x 16 floats = 16 KB
  __shared__ int spos[256];
  int tid = threadIdx.x;
  int i = blockIdx.x * 256 + tid;
  int d = dst[i];
  int pos = atomicAdd(&cursor[d], 1);
  src_perm[pos] = src[i];
  spos[tid] = pos;
  size_t blockBase = (size_t)blockIdx.x * 1024;   // float4 units
  for (int idx = tid; idx < 1024; idx += 256)
    sAttr[idx] = edge_attr[blockBase + idx];
  __syncthreads();
  int lane = tid & 63, wv = tid >> 6;
  int c = lane << 1;
  float we0[N_ETYPE], we1[N_ETYPE];
#pragma unroll
  for (int k = 0; k < N_ETYPE; ++k) {
    we0[k] = We[k * DH + c];
    we1[k] = We[k * DH + c + 1];
  }
  float be0 = be[c], be1 = be[c + 1];
  const float4* a = &sAttr[wv << 8];   // 64 edges x 4 float4
  const int* wp = &spos[wv << 6];
#pragma unroll 2
  for (int j = 0; j < 64; ++j) {
    int pos_j = wp[j];
    float4 a0 = a[j * 4 + 0], a1 = a[j * 4 + 1], a2 = a[j * 4 + 2], a3 = a[j * 4 + 3];
    float p0 = be0, p1 = be1;
    MAC16(a0, a1, a2, a3)
    e_perm[((size_t)pos_j << 6) + lane] = pack_bf2(p0, p1);
  }
}

// -------- aggregation, lite path: zb[n] = bf16(h[n] + sum relu(hb[src] + e_perm)) --------
__global__ __launch_bounds__(256) void k_agg_lite(const float* __restrict__ h,
                                                  const uint32* __restrict__ hb,
                                                  const uint32* __restrict__ e_perm,
                                                  const int* __restrict__ row_start,
                                                  const int* __restrict__ src_perm,
                                                  uint32* __restrict__ zb) {
  int lane = threadIdx.x & 63;
  int n = (blockIdx.x << 2) + (threadIdx.x >> 6);
  int c = lane << 1;
  float2 hself = *(const float2*)&h[(size_t)n * DH + c];
  float acc0 = hself.x, acc1 = hself.y;
  int beg = row_start[n], end = row_start[n + 1];
  const uint32* ep = e_perm + ((size_t)beg << 6) + lane;
  const int* sp = src_perm + beg;
  int m = end - beg;
  int i = 0;
  for (; i + 16 <= m; i += 16, ep += 1024, sp += 16) {
    int ss[16];
    uint32 gg[16], ee[16];
#pragma unroll
    for (int k = 0; k < 16; ++k) ss[k] = sp[k];
#pragma unroll
    for (int k = 0; k < 16; ++k) gg[k] = hb[((size_t)ss[k] << 6) + lane];
#pragma unroll
    for (int k = 0; k < 16; ++k) ee[k] = ep[k * 64];
#pragma unroll
    for (int k = 0; k < 16; ++k) { ACC2(gg[k], ee[k]) }
  }
  for (; i + 4 <= m; i += 4, ep += 256, sp += 4) {
    int ss[4];
    uint32 gg[4], ee[4];
#pragma unroll
    for (int k = 0; k < 4; ++k) ss[k] = sp[k];
#pragma unroll
    for (int k = 0; k < 4; ++k) gg[k] = hb[((size_t)ss[k] << 6) + lane];
#pragma unroll
    for (int k = 0; k < 4; ++k) ee[k] = ep[k * 64];
#pragma unroll
    for (int k = 0; k < 4; ++k) { ACC2(gg[k], ee[k]) }
  }
  for (; i < m; ++i, ep += 64, ++sp) {
    int s0 = sp[0];
    uint32 g0 = hb[((size_t)s0 << 6) + lane];
    uint32 e0 = ep[0];
    ACC2(g0, e0)
  }
  zb[(size_t)n * 64 + lane] = pack_bf2(acc0, acc1);
}

// ---- one-time: transpose W1,W2 -> bf16 [out_col][in_k] for MFMA B operands ----
__global__ __launch_bounds__(256) void k_prep_w(const float* __restrict__ W1,
                                                const float* __restrict__ W2,
                                                ushort16* __restrict__ w1t,
                                                ushort16* __restrict__ w2t) {
  int id = blockIdx.x * 256 + threadIdx.x;   // 0..32767
  int which = id >> 14;
  int rem = id & 16383;
  int k = rem >> 7, n = rem & 127;
  const float* W = which ? W2 : W1;
  ushort16* wt = which ? w2t : w1t;
  wt[n * 128 + k] = (ushort16)f2bf1(W[k * 128 + n]);
}

// ---------------- MFMA MLP (R7-verified): LDS-staged W, 52 KB, 3 blocks/CU ----------------
__global__ __launch_bounds__(256) void k_mlp_mfma(const uint32* __restrict__ zb,
                                                  const ushort16* __restrict__ w1t,
                                                  const ushort16* __restrict__ w2t,
                                                  const float* __restrict__ b1,
                                                  const float* __restrict__ b2,
                                                  const int* __restrict__ graph_ids,
                                                  float* __restrict__ h_out,
                                                  ushort16* __restrict__ hb_out,
                                                  float* __restrict__ pooled,
                                                  int t_slot) {
  __shared__ ushort16 sW[128 * 136];   // 34816 B
  __shared__ ushort16 sA[64 * 136];    // 17408 B
  int tid = threadIdx.x;
  int rb = blockIdx.x * 64;

  for (int idx = tid; idx < 1024; idx += 256) {
    int row = idx >> 4, ch = idx & 15;
    *(uint4*)&sA[row * 136 + ch * 8] = *(const uint4*)&zb[(size_t)(rb + row) * 64 + ch * 4];
  }
  for (int idx = tid; idx < 2048; idx += 256) {
    int row = idx >> 4, ch = idx & 15;
    *(uint4*)&sW[row * 136 + ch * 8] = *(const uint4*)&w1t[row * 128 + ch * 8];
  }
  __syncthreads();

  int l = tid & 63, w = tid >> 6;
  int r = l & 15, g = l >> 4;

  f32x4 acc[8];
#pragma unroll
  for (int n = 0; n < 8; ++n) {
    float bv = b1[n * 16 + r];
    acc[n] = (f32x4){bv, bv, bv, bv};
  }
#pragma unroll
  for (int k0 = 0; k0 < 4; ++k0) {
    bf16x8 a = *(const bf16x8*)&sA[(w * 16 + r) * 136 + k0 * 32 + g * 8];
#pragma unroll
    for (int n = 0; n < 8; ++n) {
      bf16x8 b = *(const bf16x8*)&sW[(n * 16 + r) * 136 + k0 * 32 + g * 8];
      acc[n] = __builtin_amdgcn_mfma_f32_16x16x32_bf16(a, b, acc[n], 0, 0, 0);
    }
  }
#pragma unroll
  for (int n = 0; n < 8; ++n) {
#pragma unroll
    for (int q = 0; q < 4; ++q) {
      float v = fmaxf(acc[n][q], 0.0f);
      sA[(w * 16 + g * 4 + q) * 136 + n * 16 + r] = (ushort16)f2bf1(v);
    }
  }
  __syncthreads();
  for (int idx = tid; idx < 2048; idx += 256) {
    int row = idx >> 4, ch = idx & 15;
    *(uint4*)&sW[row * 136 + ch * 8] = *(const uint4*)&w2t[row * 128 + ch * 8];
  }
  __syncthreads();

#pragma unroll
  for (int n = 0; n < 8; ++n) {
    float bv = b2[n * 16 + r];
    acc[n] = (f32x4){bv, bv, bv, bv};
  }
#pragma unroll
  for (int k0 = 0; k0 < 4; ++k0) {
    bf16x8 a = *(const bf16x8*)&sA[(w * 16 + r) * 136 + k0 * 32 + g * 8];
#pragma unroll
    for (int n = 0; n < 8; ++n) {
      bf16x8 b = *(const bf16x8*)&sW[(n * 16 + r) * 136 + k0 * 32 + g * 8];
      acc[n] = __builtin_amdgcn_mfma_f32_16x16x32_bf16(a, b, acc[n], 0, 0, 0);
    }
  }

  int node0 = rb + w * 16;
#pragma unroll
  for (int n = 0; n < 8; ++n) {
#pragma unroll
    for (int q = 0; q < 4; ++q) {
      int node = node0 + g * 4 + q;
      float v = acc[n][q];
      h_out[(size_t)node * DH + n * 16 + r] = v;
      hb_out[(size_t)node * DH + n * 16 + r] = (ushort16)f2bf1(v);
    }
  }
  float* pbase = pooled + t_slot * DH;
  int gid0 = graph_ids[node0];
  if (gid0 == graph_ids[node0 + 15]) {
#pragma unroll
    for (int n = 0; n < 8; ++n) {
      float s = acc[n][0] + acc[n][1] + acc[n][2] + acc[n][3];
      s += __shfl_xor(s, 16);
      s += __shfl_xor(s, 32);
      if (l < 16) atomicAdd(&pbase[gid0 * 512 + n * 16 + r], s);
    }
  } else {
#pragma unroll
    for (int q = 0; q < 4; ++q) {
      int node = node0 + g * 4 + q;
      int gg = graph_ids[node];
#pragma unroll
      for (int n = 0; n < 8; ++n)
        atomicAdd(&pbase[gg * 512 + n * 16 + r], acc[n][q]);
    }
  }
}

// -------- aggregation, fallback indirect path --------
__global__ __launch_bounds__(256, 8) void k_agg_ind(const float* __restrict__ h,
                                                    const uint32* __restrict__ hb,
                                                    const float* __restrict__ edge_attr,
                                                    const float* __restrict__ We,
                                                    const float* __restrict__ be,
                                                    const int* __restrict__ row_start,
                                                    const int* __restrict__ src_perm,
                                                    const int* __restrict__ eid_perm,
                                                    float* __restrict__ z) {
  int lane = threadIdx.x & 63;
  int n = (blockIdx.x << 2) + (threadIdx.x >> 6);
  int c = lane << 1;
  float we0[N_ETYPE], we1[N_ETYPE];
#pragma unroll
  for (int k = 0; k < N_ETYPE; ++k) {
    we0[k] = We[k * DH + c];
    we1[k] = We[k * DH + c + 1];
  }
  float be0 = be[c], be1 = be[c + 1];
  float2 hself = *(const float2*)&h[(size_t)n * DH + c];
  float acc0 = hself.x, acc1 = hself.y;
  int beg = row_start[n], end = row_start[n + 1];
  int i = beg;
  for (; i + 1 < end; i += 2) {
    int s0 = src_perm[i], s1 = src_perm[i + 1];
    int e0i = eid_perm[i], e1i = eid_perm[i + 1];
    uint32 g0 = hb[((size_t)s0 << 6) + lane];
    uint32 g1 = hb[((size_t)s1 << 6) + lane];
    const float4* eA = (const float4*)(edge_attr + (size_t)e0i * N_ETYPE);
    const float4* eB = (const float4*)(edge_attr + (size_t)e1i * N_ETYPE);
    float4 a0 = eA[0], a1 = eA[1], a2 = eA[2], a3 = eA[3];
    float p0, p1;
    p0 = be0; p1 = be1; MAC16(a0, a1, a2, a3) RELU_ACC(g0)
    float4 b0 = eB[0], b1v = eB[1], b2v = eB[2], b3 = eB[3];
    p0 = be0; p1 = be1; MAC16(b0, b1v, b2v, b3) RELU_ACC(g1)
  }
  if (i < end) {
    int s0 = src_perm[i];
    int e0i = eid_perm[i];
    uint32 g0 = hb[((size_t)s0 << 6) + lane];
    const float4* eA = (const float4*)(edge_attr + (size_t)e0i * N_ETYPE);
    float4 a0 = eA[0], a1 = eA[1], a2 = eA[2], a3 = eA[3];
    float p0 = be0, p1 = be1;
    MAC16(a0, a1, a2, a3) RELU_ACC(g0)
  }
  *(float2*)&z[(size_t)n * DH + c] = make_float2(acc0, acc1);
}

// ---------------- fallback fp32 MLP ----------------
#define MLPFMA(K, U0, U1)                                            \
  {                                                                  \
    _Pragma("unroll")                                                \
    for (int i_ = 0; i_ < 8; ++i_) {                                 \
      float2 a_ = *(const float2*)&sA[(r0 + i_) * 132 + (K)];        \
      acc[i_][0] = fmaf(a_.x, U0.x, acc[i_][0]);                     \
      acc[i_][1] = fmaf(a_.x, U0.y, acc[i_][1]);                     \
      acc[i_][2] = fmaf(a_.x, U0.z, acc[i_][2]);                     \
      acc[i_][3] = fmaf(a_.x, U0.w, acc[i_][3]);                     \
      acc[i_][0] = fmaf(a_.y, U1.x, acc[i_][0]);                     \
      acc[i_][1] = fmaf(a_.y, U1.y, acc[i_][1]);                     \
      acc[i_][2] = fmaf(a_.y, U1.z, acc[i_][2]);                     \
      acc[i_][3] = fmaf(a_.y, U1.w, acc[i_][3]);                     \
    }                                                                \
  }

__device__ __forceinline__ void gemm_tile_g(const float* sA, const float4* __restrict__ Wv,
                                            float acc[8][4], int r0, int cg) {
  float4 c0 = Wv[cg],       c1 = Wv[32 + cg];
  float4 n0 = Wv[64 + cg],  n1 = Wv[96 + cg];
#pragma unroll 4
  for (int k = 0; k < DH - 4; k += 2) {
    float4 u0 = c0, u1 = c1;
    c0 = n0; c1 = n1;
    n0 = Wv[(k + 4) * 32 + cg];
    n1 = Wv[(k + 5) * 32 + cg];
    MLPFMA(k, u0, u1)
  }
  MLPFMA(DH - 4, c0, c1)
  MLPFMA(DH - 2, n0, n1)
}

__global__ __launch_bounds__(256) void k_mlp(const float* __restrict__ z,
                                             const float* __restrict__ W1,
                                             const float* __restrict__ b1,
                                             const float* __restrict__ W2,
                                             const float* __restrict__ b2,
                                             const int* __restrict__ graph_ids,
                                             float* __restrict__ h_out,
                                             uint32* __restrict__ hb_out,
                                             float* __restrict__ pooled,
                                             int t_slot) {
  __shared__ float sA[64 * 132];
  int tid = threadIdx.x;
  int rb = blockIdx.x * 64;
  for (int idx = tid; idx < 64 * 32; idx += 256) {
    int r = idx >> 5, kq = (idx & 31) << 2;
    *(float4*)&sA[r * 132 + kq] = *(const float4*)&z[(size_t)(rb + r) * DH + kq];
  }
  __syncthreads();

  int cg = tid & 31, rg = tid >> 5;
  int c0 = cg << 2, r0 = rg << 3;
  float acc[8][4];
  {
    float4 bb = *(const float4*)&b1[c0];
#pragma unroll
    for (int i = 0; i < 8; ++i) { acc[i][0] = bb.x; acc[i][1] = bb.y; acc[i][2] = bb.z; acc[i][3] = bb.w; }
  }
  gemm_tile_g(sA, (const float4*)W1, acc, r0, cg);
  __syncthreads();
#pragma unroll
  for (int i = 0; i < 8; ++i) {
    float4 v;
    v.x = fmaxf(acc[i][0], 0.0f); v.y = fmaxf(acc[i][1], 0.0f);
    v.z = fmaxf(acc[i][2], 0.0f); v.w = fmaxf(acc[i][3], 0.0f);
    *(float4*)&sA[(r0 + i) * 132 + c0] = v;
  }
  __syncthreads();
  {
    float4 bb = *(const float4*)&b2[c0];
#pragma unroll
    for (int i = 0; i < 8; ++i) { acc[i][0] = bb.x; acc[i][1] = bb.y; acc[i][2] = bb.z; acc[i][3] = bb.w; }
  }
  gemm_tile_g(sA, (const float4*)W2, acc, r0, cg);

  int node0 = rb + r0;
#pragma unroll
  for (int i = 0; i < 8; ++i) {
    float4 v = make_float4(acc[i][0], acc[i][1], acc[i][2], acc[i][3]);
    *(float4*)&h_out[(size_t)(node0 + i) * DH + c0] = v;
    uint2 hv;
    hv.x = pack_bf2(acc[i][0], acc[i][1]);
    hv.y = pack_bf2(acc[i][2], acc[i][3]);
    *(uint2*)&hb_out[(size_t)(node0 + i) * 64 + (c0 >> 1)] = hv;
  }
  float* pbase = pooled + t_slot * DH;
  int g_first = graph_ids[node0];
  int g_last = graph_ids[node0 + 7];
  if (g_first == g_last) {
    float s0 = 0.f, s1 = 0.f, s2 = 0.f, s3 = 0.f;
#pragma unroll
    for (int i = 0; i < 8; ++i) { s0 += acc[i][0]; s1 += acc[i][1]; s2 += acc[i][2]; s3 += acc[i][3]; }
    atomicAdd(&pbase[g_first * 512 + c0 + 0], s0);
    atomicAdd(&pbase[g_first * 512 + c0 + 1], s1);
    atomicAdd(&pbase[g_first * 512 + c0 + 2], s2);
    atomicAdd(&pbase[g_first * 512 + c0 + 3], s3);
  } else {
#pragma unroll
    for (int i = 0; i < 8; ++i) {
      int g = graph_ids[node0 + i];
      atomicAdd(&pbase[g * 512 + c0 + 0], acc[i][0]);
      atomicAdd(&pbase[g * 512 + c0 + 1], acc[i][1]);
      atomicAdd(&pbase[g * 512 + c0 + 2], acc[i][2]);
      atomicAdd(&pbase[g * 512 + c0 + 3], acc[i][3]);
    }
  }
}

// ---------------- final: out = pooled @ Wl + bl ----------------
__global__ __launch_bounds__(256) void k_final(const float* __restrict__ pooled,
                                               const float* __restrict__ Wl,
                                               const float* __restrict__ bl,
                                               float* __restrict__ out) {
  int g = blockIdx.x, o = threadIdx.x;
  __shared__ float sp[DH * T_ITERS];
  for (int idx = o; idx < DH * T_ITERS; idx += 256) sp[idx] = pooled[g * (DH * T_ITERS) + idx];
  __syncthreads();
  float acc = bl[o];
#pragma unroll 8
  for (int j = 0; j < DH * T_ITERS; ++j)
    acc = fmaf(sp[j], Wl[j * DOUT + o], acc);
  out[g * DOUT + o] = acc;
}

extern "C" void kernel_launch(void* const* d_in, const int* in_sizes, int n_in,
                              void* d_out, int out_size, void* d_ws, size_t ws_size,
                              hipStream_t stream) {
  const float* x         = (const float*)d_in[0];
  const int*   edge_index= (const int*)d_in[1];
  const float* edge_attr = (const float*)d_in[2];
  const int*   graph_ids = (const int*)d_in[3];
  const float* Wn = (const float*)d_in[4];
  const float* bn = (const float*)d_in[5];
  const float* We = (const float*)d_in[6];
  const float* be = (const float*)d_in[7];
  const float* W1 = (const float*)d_in[8];
  const float* b1 = (const float*)d_in[9];
  const float* W2 = (const float*)d_in[10];
  const float* b2 = (const float*)d_in[11];
  const float* Wl = (const float*)d_in[12];
  const float* bl = (const float*)d_in[13];
  float* out = (float*)d_out;

  char* p = (char*)d_ws;
  auto alloc = [&](size_t bytes) { char* r = p; p += (bytes + 255) & ~(size_t)255; return r; };
  float*  h        = (float*)alloc((size_t)N_NODES * DH * 4);
  float*  z        = (float*)alloc((size_t)N_NODES * DH * 4);   // primary path reuses as zb
  uint32* hb       = (uint32*)alloc((size_t)N_NODES * DH * 2);
  float*  pooled   = (float*)alloc((size_t)N_GRAPHS * DH * T_ITERS * 4);
  int*    counts   = (int*)alloc((size_t)N_NODES * 4);          // reused as w1t/w2t after scan
  int*    row_start= (int*)alloc((size_t)(N_NODES + 1) * 4);
  int*    cursor   = (int*)alloc((size_t)N_NODES * 4);
  int*    src_perm = (int*)alloc((size_t)N_EDGES * 4);
  int*    blk_sums = (int*)alloc(256);
  int*    blk_off  = (int*)alloc(256);

  const int* src = edge_index;
  const int* dst = edge_index + N_EDGES;

  size_t used = (size_t)(p - (char*)d_ws);
  size_t need_e = used + (size_t)N_EDGES * DH * 2 + 4096;   // e_perm 160 MB

  hipMemsetAsync(counts, 0, (size_t)N_NODES * 4, stream);
  hipMemsetAsync(pooled, 0, (size_t)N_GRAPHS * DH * T_ITERS * 4, stream);

  k_embed<<<N_NODES * DH / 256, 256, 0, stream>>>(x, Wn, bn, h, (ushort16*)hb);
  k_hist<<<N_EDGES / 256, 256, 0, stream>>>(dst, counts);
  k_scan1<<<SCAN_BLK, 1024, 0, stream>>>(counts, row_start, blk_sums);
  k_scan2<<<1, 64, 0, stream>>>(blk_sums, blk_off, row_start);
  k_scan3<<<SCAN_BLK, 1024, 0, stream>>>(row_start, blk_off, cursor);

  if (ws_size >= need_e) {
    uint32* e_perm = (uint32*)alloc((size_t)N_EDGES * DH * 2);
    uint32* zb = (uint32*)z;                              // overlay (z fp32 unused here)
    ushort16* w1t = (ushort16*)counts;                    // counts dead after scan
    ushort16* w2t = w1t + 128 * 128;
    k_prep_w<<<128, 256, 0, stream>>>(W1, W2, w1t, w2t);
    k_perm_e<<<N_EDGES / 256, 256, 0, stream>>>(src, dst, (const float4*)edge_attr,
                                                We, be, cursor, src_perm, e_perm);
    for (int t = 0; t < T_ITERS; ++t) {
      k_agg_lite<<<N_NODES / 4, 256, 0, stream>>>(h, hb, e_perm, row_start, src_perm, zb);
      k_mlp_mfma<<<N_NODES / 64, 256, 0, stream>>>(zb, w1t, w2t, b1, b2, graph_ids,
                                                   h, (ushort16*)hb, pooled, t);
    }
  } else {
    int* eid_perm = (int*)alloc((size_t)N_EDGES * 4);
    k_permute<<<N_EDGES / 256, 256, 0, stream>>>(src, dst, cursor, src_perm, eid_perm);
    for (int t = 0; t < T_ITERS; ++t) {
      k_agg_ind<<<N_NODES / 4, 256, 0, stream>>>(h, hb, edge_attr, We, be, row_start, src_perm, eid_perm, z);
      k_mlp<<<N_NODES / 64, 256, 0, stream>>>(z, W1, b1, W2, b2, graph_ids, h, hb, pooled, t);
    }
  }
  k_final<<<N_GRAPHS, 256, 0, stream>>>(pooled, Wl, bl, out);
}

// Round 14
// 440.316 us; speedup vs baseline: 1.6890x; 1.0532x over previous
//
#include <hip/hip_runtime.h>

#define N_NODES   40000
#define N_EDGES   640000
#define N_GRAPHS  64
#define DIM_IN    32
#define N_ETYPE   16
#define DH        128
#define DOUT      256
#define T_ITERS   4
#define SCAN_BLK  40          // ceil(40000/1024)

typedef unsigned int uint32;
typedef unsigned short ushort16;
typedef __attribute__((ext_vector_type(8))) short bf16x8;
typedef __attribute__((ext_vector_type(4))) float f32x4;

__device__ __forceinline__ uint32 f2bf1(float f) {
  uint32 u = __float_as_uint(f);
  return (u + 0x7fffu + ((u >> 16) & 1u)) >> 16;
}
__device__ __forceinline__ uint32 pack_bf2(float lo, float hi) {
  return (f2bf1(hi) << 16) | f2bf1(lo);
}

// ---------------- node embedding: h = x @ Wn + bn (fp32 + bf16 mirror) ----------------
__global__ __launch_bounds__(256) void k_embed(const float* __restrict__ x,
                                               const float* __restrict__ Wn,
                                               const float* __restrict__ bn,
                                               float* __restrict__ h,
                                               ushort16* __restrict__ hb) {
  int idx = blockIdx.x * 256 + threadIdx.x;     // n*128 + c, exact grid
  int n = idx >> 7, c = idx & 127;
  const float* xr = x + n * DIM_IN;
  float acc = bn[c];
#pragma unroll
  for (int k = 0; k < DIM_IN; ++k)
    acc = fmaf(xr[k], Wn[k * DH + c], acc);
  h[idx] = acc;
  hb[idx] = (ushort16)f2bf1(acc);
}

// ---------------- CSR build ----------------
__global__ __launch_bounds__(256) void k_hist(const int* __restrict__ dst,
                                              int* __restrict__ counts) {
  int i = blockIdx.x * 256 + threadIdx.x;
  atomicAdd(&counts[dst[i]], 1);
}

// ---- 3-pass parallel scan ----
__global__ __launch_bounds__(1024) void k_scan1(const int* __restrict__ counts,
                                                int* __restrict__ excl,      // = row_start
                                                int* __restrict__ blk_sums) {
  __shared__ int wsums[16];
  int tid = threadIdx.x, lane = tid & 63, w = tid >> 6;
  int i = blockIdx.x * 1024 + tid;
  int v = (i < N_NODES) ? counts[i] : 0;
  int s = v;
#pragma unroll
  for (int off = 1; off < 64; off <<= 1) {
    int t = __shfl_up(s, off);
    if (lane >= off) s += t;
  }
  if (lane == 63) wsums[w] = s;
  __syncthreads();
  if (tid < 16) {
    int ws_ = wsums[tid];
#pragma unroll
    for (int off = 1; off < 16; off <<= 1) {
      int t = __shfl_up(ws_, off);
      if (tid >= off) ws_ += t;
    }
    wsums[tid] = ws_;
  }
  __syncthreads();
  int e = s - v + (w ? wsums[w - 1] : 0);
  if (i < N_NODES) excl[i] = e;
  if (tid == 0) blk_sums[blockIdx.x] = wsums[15];
}

__global__ __launch_bounds__(64) void k_scan2(const int* __restrict__ blk_sums,
                                              int* __restrict__ blk_off,
                                              int* __restrict__ row_start) {
  int lane = threadIdx.x;
  int v = (lane < SCAN_BLK) ? blk_sums[lane] : 0;
  int s = v;
#pragma unroll
  for (int off = 1; off < 64; off <<= 1) {
    int t = __shfl_up(s, off);
    if (lane >= off) s += t;
  }
  if (lane < SCAN_BLK) blk_off[lane] = s - v;
  if (lane == 63) row_start[N_NODES] = s;
}

__global__ __launch_bounds__(1024) void k_scan3(int* __restrict__ row_start,
                                                const int* __restrict__ blk_off,
                                                int* __restrict__ cursor) {
  int i = blockIdx.x * 1024 + threadIdx.x;
  if (i < N_NODES) {
    int v = row_start[i] + blk_off[blockIdx.x];
    row_start[i] = v;
    cursor[i] = v;
  }
}

__global__ __launch_bounds__(256) void k_permute(const int* __restrict__ src,
                                                 const int* __restrict__ dst,
                                                 int* __restrict__ cursor,
                                                 int* __restrict__ src_perm,
                                                 int* __restrict__ eid_perm) {
  int i = blockIdx.x * 256 + threadIdx.x;
  int d = dst[i];
  int pos = atomicAdd(&cursor[d], 1);
  src_perm[pos] = src[i];
  eid_perm[pos] = i;
}

#define MAC16(A0,A1,A2,A3)                                          \
  p0 = fmaf(A0.x, we0[0], p0);  p1 = fmaf(A0.x, we1[0], p1);        \
  p0 = fmaf(A0.y, we0[1], p0);  p1 = fmaf(A0.y, we1[1], p1);        \
  p0 = fmaf(A0.z, we0[2], p0);  p1 = fmaf(A0.z, we1[2], p1);        \
  p0 = fmaf(A0.w, we0[3], p0);  p1 = fmaf(A0.w, we1[3], p1);        \
  p0 = fmaf(A1.x, we0[4], p0);  p1 = fmaf(A1.x, we1[4], p1);        \
  p0 = fmaf(A1.y, we0[5], p0);  p1 = fmaf(A1.y, we1[5], p1);        \
  p0 = fmaf(A1.z, we0[6], p0);  p1 = fmaf(A1.z, we1[6], p1);        \
  p0 = fmaf(A1.w, we0[7], p0);  p1 = fmaf(A1.w, we1[7], p1);        \
  p0 = fmaf(A2.x, we0[8], p0);  p1 = fmaf(A2.x, we1[8], p1);        \
  p0 = fmaf(A2.y, we0[9], p0);  p1 = fmaf(A2.y, we1[9], p1);        \
  p0 = fmaf(A2.z, we0[10], p0); p1 = fmaf(A2.z, we1[10], p1);       \
  p0 = fmaf(A2.w, we0[11], p0); p1 = fmaf(A2.w, we1[11], p1);       \
  p0 = fmaf(A3.x, we0[12], p0); p1 = fmaf(A3.x, we1[12], p1);       \
  p0 = fmaf(A3.y, we0[13], p0); p1 = fmaf(A3.y, we1[13], p1);       \
  p0 = fmaf(A3.z, we0[14], p0); p1 = fmaf(A3.z, we1[14], p1);       \
  p0 = fmaf(A3.w, we0[15], p0); p1 = fmaf(A3.w, we1[15], p1);

#define RELU_ACC(G)                                                  \
  acc0 += fmaxf(__uint_as_float((G) << 16) + p0, 0.0f);              \
  acc1 += fmaxf(__uint_as_float((G) & 0xffff0000u) + p1, 0.0f);

#define ACC2(G,E)                                                                 \
  acc0 += fmaxf(__uint_as_float((G) << 16) + __uint_as_float((E) << 16), 0.0f);   \
  acc1 += fmaxf(__uint_as_float((G) & 0xffff0000u) +                              \
                __uint_as_float((E) & 0xffff0000u), 0.0f);

// ---- one-time merged pass: CSR permute + e_perm[pos] = bf16(edge_attr[i]@We + be) ----
__global__ __launch_bounds__(256) void k_perm_e(const int* __restrict__ src,
                                                const int* __restrict__ dst,
                                                const float4* __restrict__ edge_attr,
                                                const float* __restrict__ We,
                                                const float* __restrict__ be,
                                                int* __restrict__ cursor,
                                                int* __restrict__ src_perm,
                                                uint32* __restrict__ e_perm) {
  __shared__ float4 sAttr[1024];     // 256 edges x 16 floats = 16 KB
  __shared__ int spos[256];
  int tid = threadIdx.x;
  int i = blockIdx.x * 256 + tid;
  int d = dst[i];
  int pos = atomicAdd(&cursor[d], 1);
  src_perm[pos] = src[i];
  spos[tid] = pos;
  size_t blockBase = (size_t)blockIdx.x * 1024;   // float4 units
  for (int idx = tid; idx < 1024; idx += 256)
    sAttr[idx] = edge_attr[blockBase + idx];
  __syncthreads();
  int lane = tid & 63, wv = tid >> 6;
  int c = lane << 1;
  float we0[N_ETYPE], we1[N_ETYPE];
#pragma unroll
  for (int k = 0; k < N_ETYPE; ++k) {
    we0[k] = We[k * DH + c];
    we1[k] = We[k * DH + c + 1];
  }
  float be0 = be[c], be1 = be[c + 1];
  const float4* a = &sAttr[wv << 8];   // 64 edges x 4 float4
  const int* wp = &spos[wv << 6];
#pragma unroll 2
  for (int j = 0; j < 64; ++j) {
    int pos_j = wp[j];
    float4 a0 = a[j * 4 + 0], a1 = a[j * 4 + 1], a2 = a[j * 4 + 2], a3 = a[j * 4 + 3];
    float p0 = be0, p1 = be1;
    MAC16(a0, a1, a2, a3)
    e_perm[((size_t)pos_j << 6) + lane] = pack_bf2(p0, p1);
  }
}

// -------- aggregation: zb[n] = bf16(hb[n] + sum relu(hb[src] + e_perm)) --------
// (R9-verified: bf16 self-term, 16-deep unroll)
__global__ __launch_bounds__(256) void k_agg_lite(const uint32* __restrict__ hb,
                                                  const uint32* __restrict__ e_perm,
                                                  const int* __restrict__ row_start,
                                                  const int* __restrict__ src_perm,
                                                  uint32* __restrict__ zb) {
  int lane = threadIdx.x & 63;
  int n = (blockIdx.x << 2) + (threadIdx.x >> 6);
  uint32 hself = hb[(size_t)n * 64 + lane];
  float acc0 = __uint_as_float(hself << 16);
  float acc1 = __uint_as_float(hself & 0xffff0000u);
  int beg = row_start[n], end = row_start[n + 1];
  const uint32* ep = e_perm + ((size_t)beg << 6) + lane;
  const int* sp = src_perm + beg;
  int m = end - beg;
  int i = 0;
  for (; i + 16 <= m; i += 16, ep += 1024, sp += 16) {
    int ss[16];
    uint32 gg[16], ee[16];
#pragma unroll
    for (int k = 0; k < 16; ++k) ss[k] = sp[k];
#pragma unroll
    for (int k = 0; k < 16; ++k) gg[k] = hb[((size_t)ss[k] << 6) + lane];
#pragma unroll
    for (int k = 0; k < 16; ++k) ee[k] = ep[k * 64];
#pragma unroll
    for (int k = 0; k < 16; ++k) { ACC2(gg[k], ee[k]) }
  }
  for (; i + 4 <= m; i += 4, ep += 256, sp += 4) {
    int ss[4];
    uint32 gg[4], ee[4];
#pragma unroll
    for (int k = 0; k < 4; ++k) ss[k] = sp[k];
#pragma unroll
    for (int k = 0; k < 4; ++k) gg[k] = hb[((size_t)ss[k] << 6) + lane];
#pragma unroll
    for (int k = 0; k < 4; ++k) ee[k] = ep[k * 64];
#pragma unroll
    for (int k = 0; k < 4; ++k) { ACC2(gg[k], ee[k]) }
  }
  for (; i < m; ++i, ep += 64, ++sp) {
    int s0 = sp[0];
    uint32 g0 = hb[((size_t)s0 << 6) + lane];
    uint32 e0 = ep[0];
    ACC2(g0, e0)
  }
  zb[(size_t)n * 64 + lane] = pack_bf2(acc0, acc1);
}

// ---- one-time: transpose W1,W2 -> bf16 [out_col][in_k] for MFMA B operands ----
__global__ __launch_bounds__(256) void k_prep_w(const float* __restrict__ W1,
                                                const float* __restrict__ W2,
                                                ushort16* __restrict__ w1t,
                                                ushort16* __restrict__ w2t) {
  int id = blockIdx.x * 256 + threadIdx.x;   // 0..32767
  int which = id >> 14;
  int rem = id & 16383;
  int k = rem >> 7, n = rem & 127;
  const float* W = which ? W2 : W1;
  ushort16* wt = which ? w2t : w1t;
  wt[n * 128 + k] = (ushort16)f2bf1(W[k * 128 + n]);
}

// ------- MFMA MLP: LDS-staged W (R7 core) + bf16-only coalesced epilogue (R9) -------
// hb_out = bf16(relu(zb@W1+b1)@W2+b2); no fp32 h write.
__global__ __launch_bounds__(256) void k_mlp_mfma(const uint32* __restrict__ zb,
                                                  const ushort16* __restrict__ w1t,
                                                  const ushort16* __restrict__ w2t,
                                                  const float* __restrict__ b1,
                                                  const float* __restrict__ b2,
                                                  const int* __restrict__ graph_ids,
                                                  uint32* __restrict__ hb_out,
                                                  float* __restrict__ pooled,
                                                  int t_slot) {
  __shared__ ushort16 sW[128 * 136];   // 34816 B
  __shared__ ushort16 sA[64 * 136];    // 17408 B
  int tid = threadIdx.x;
  int rb = blockIdx.x * 64;

  for (int idx = tid; idx < 1024; idx += 256) {
    int row = idx >> 4, ch = idx & 15;
    *(uint4*)&sA[row * 136 + ch * 8] = *(const uint4*)&zb[(size_t)(rb + row) * 64 + ch * 4];
  }
  for (int idx = tid; idx < 2048; idx += 256) {
    int row = idx >> 4, ch = idx & 15;
    *(uint4*)&sW[row * 136 + ch * 8] = *(const uint4*)&w1t[row * 128 + ch * 8];
  }
  __syncthreads();

  int l = tid & 63, w = tid >> 6;
  int r = l & 15, g = l >> 4;

  f32x4 acc[8];
#pragma unroll
  for (int n = 0; n < 8; ++n) {
    float bv = b1[n * 16 + r];
    acc[n] = (f32x4){bv, bv, bv, bv};
  }
#pragma unroll
  for (int k0 = 0; k0 < 4; ++k0) {
    bf16x8 a = *(const bf16x8*)&sA[(w * 16 + r) * 136 + k0 * 32 + g * 8];
#pragma unroll
    for (int n = 0; n < 8; ++n) {
      bf16x8 b = *(const bf16x8*)&sW[(n * 16 + r) * 136 + k0 * 32 + g * 8];
      acc[n] = __builtin_amdgcn_mfma_f32_16x16x32_bf16(a, b, acc[n], 0, 0, 0);
    }
  }
#pragma unroll
  for (int n = 0; n < 8; ++n) {
#pragma unroll
    for (int q = 0; q < 4; ++q) {
      float v = fmaxf(acc[n][q], 0.0f);
      sA[(w * 16 + g * 4 + q) * 136 + n * 16 + r] = (ushort16)f2bf1(v);
    }
  }
  __syncthreads();
  for (int idx = tid; idx < 2048; idx += 256) {
    int row = idx >> 4, ch = idx & 15;
    *(uint4*)&sW[row * 136 + ch * 8] = *(const uint4*)&w2t[row * 128 + ch * 8];
  }
  __syncthreads();

#pragma unroll
  for (int n = 0; n < 8; ++n) {
    float bv = b2[n * 16 + r];
    acc[n] = (f32x4){bv, bv, bv, bv};
  }
#pragma unroll
  for (int k0 = 0; k0 < 4; ++k0) {
    bf16x8 a = *(const bf16x8*)&sA[(w * 16 + r) * 136 + k0 * 32 + g * 8];
#pragma unroll
    for (int n = 0; n < 8; ++n) {
      bf16x8 b = *(const bf16x8*)&sW[(n * 16 + r) * 136 + k0 * 32 + g * 8];
      acc[n] = __builtin_amdgcn_mfma_f32_16x16x32_bf16(a, b, acc[n], 0, 0, 0);
    }
  }

  // ---- pooled (fp32, from registers) ----
  float* pbase = pooled + t_slot * DH;
  int node0 = rb + w * 16;
  int gid0 = graph_ids[node0];
  if (gid0 == graph_ids[node0 + 15]) {
#pragma unroll
    for (int n = 0; n < 8; ++n) {
      float s = acc[n][0] + acc[n][1] + acc[n][2] + acc[n][3];
      s += __shfl_xor(s, 16);
      s += __shfl_xor(s, 32);
      if (l < 16) atomicAdd(&pbase[gid0 * 512 + n * 16 + r], s);
    }
  } else {
#pragma unroll
    for (int q = 0; q < 4; ++q) {
      int node = node0 + g * 4 + q;
      int gg = graph_ids[node];
#pragma unroll
      for (int n = 0; n < 8; ++n)
        atomicAdd(&pbase[gg * 512 + n * 16 + r], acc[n][q]);
    }
  }

  // ---- epilogue (R9-verified): pack bf16 into own sA rows, coalesced hb store ----
#pragma unroll
  for (int n = 0; n < 8; ++n)
#pragma unroll
    for (int q = 0; q < 4; ++q)
      sA[(w * 16 + g * 4 + q) * 136 + n * 16 + r] = (ushort16)f2bf1(acc[n][q]);
  __syncthreads();
  for (int idx = tid; idx < 4096; idx += 256) {   // 64 rows x 64 dwords
    int row = idx >> 6, dw = idx & 63;
    uint32 v = *(const uint32*)&sA[row * 136 + dw * 2];
    hb_out[(size_t)(rb + row) * 64 + dw] = v;
  }
}

// -------- aggregation, fallback indirect path --------
__global__ __launch_bounds__(256, 8) void k_agg_ind(const float* __restrict__ h,
                                                    const uint32* __restrict__ hb,
                                                    const float* __restrict__ edge_attr,
                                                    const float* __restrict__ We,
                                                    const float* __restrict__ be,
                                                    const int* __restrict__ row_start,
                                                    const int* __restrict__ src_perm,
                                                    const int* __restrict__ eid_perm,
                                                    float* __restrict__ z) {
  int lane = threadIdx.x & 63;
  int n = (blockIdx.x << 2) + (threadIdx.x >> 6);
  int c = lane << 1;
  float we0[N_ETYPE], we1[N_ETYPE];
#pragma unroll
  for (int k = 0; k < N_ETYPE; ++k) {
    we0[k] = We[k * DH + c];
    we1[k] = We[k * DH + c + 1];
  }
  float be0 = be[c], be1 = be[c + 1];
  float2 hself = *(const float2*)&h[(size_t)n * DH + c];
  float acc0 = hself.x, acc1 = hself.y;
  int beg = row_start[n], end = row_start[n + 1];
  int i = beg;
  for (; i + 1 < end; i += 2) {
    int s0 = src_perm[i], s1 = src_perm[i + 1];
    int e0i = eid_perm[i], e1i = eid_perm[i + 1];
    uint32 g0 = hb[((size_t)s0 << 6) + lane];
    uint32 g1 = hb[((size_t)s1 << 6) + lane];
    const float4* eA = (const float4*)(edge_attr + (size_t)e0i * N_ETYPE);
    const float4* eB = (const float4*)(edge_attr + (size_t)e1i * N_ETYPE);
    float4 a0 = eA[0], a1 = eA[1], a2 = eA[2], a3 = eA[3];
    float p0, p1;
    p0 = be0; p1 = be1; MAC16(a0, a1, a2, a3) RELU_ACC(g0)
    float4 b0 = eB[0], b1v = eB[1], b2v = eB[2], b3 = eB[3];
    p0 = be0; p1 = be1; MAC16(b0, b1v, b2v, b3) RELU_ACC(g1)
  }
  if (i < end) {
    int s0 = src_perm[i];
    int e0i = eid_perm[i];
    uint32 g0 = hb[((size_t)s0 << 6) + lane];
    const float4* eA = (const float4*)(edge_attr + (size_t)e0i * N_ETYPE);
    float4 a0 = eA[0], a1 = eA[1], a2 = eA[2], a3 = eA[3];
    float p0 = be0, p1 = be1;
    MAC16(a0, a1, a2, a3) RELU_ACC(g0)
  }
  *(float2*)&z[(size_t)n * DH + c] = make_float2(acc0, acc1);
}

// ---------------- fallback fp32 MLP ----------------
#define MLPFMA(K, U0, U1)                                            \
  {                                                                  \
    _Pragma("unroll")                                                \
    for (int i_ = 0; i_ < 8; ++i_) {                                 \
      float2 a_ = *(const float2*)&sA[(r0 + i_) * 132 + (K)];        \
      acc[i_][0] = fmaf(a_.x, U0.x, acc[i_][0]);                     \
      acc[i_][1] = fmaf(a_.x, U0.y, acc[i_][1]);                     \
      acc[i_][2] = fmaf(a_.x, U0.z, acc[i_][2]);                     \
      acc[i_][3] = fmaf(a_.x, U0.w, acc[i_][3]);                     \
      acc[i_][0] = fmaf(a_.y, U1.x, acc[i_][0]);                     \
      acc[i_][1] = fmaf(a_.y, U1.y, acc[i_][1]);                     \
      acc[i_][2] = fmaf(a_.y, U1.z, acc[i_][2]);                     \
      acc[i_][3] = fmaf(a_.y, U1.w, acc[i_][3]);                     \
    }                                                                \
  }

__device__ __forceinline__ void gemm_tile_g(const float* sA, const float4* __restrict__ Wv,
                                            float acc[8][4], int r0, int cg) {
  float4 c0 = Wv[cg],       c1 = Wv[32 + cg];
  float4 n0 = Wv[64 + cg],  n1 = Wv[96 + cg];
#pragma unroll 4
  for (int k = 0; k < DH - 4; k += 2) {
    float4 u0 = c0, u1 = c1;
    c0 = n0; c1 = n1;
    n0 = Wv[(k + 4) * 32 + cg];
    n1 = Wv[(k + 5) * 32 + cg];
    MLPFMA(k, u0, u1)
  }
  MLPFMA(DH - 4, c0, c1)
  MLPFMA(DH - 2, n0, n1)
}

__global__ __launch_bounds__(256) void k_mlp(const float* __restrict__ z,
                                             const float* __restrict__ W1,
                                             const float* __restrict__ b1,
                                             const float* __restrict__ W2,
                                             const float* __restrict__ b2,
                                             const int* __restrict__ graph_ids,
                                             float* __restrict__ h_out,
                                             uint32* __restrict__ hb_out,
                                             float* __restrict__ pooled,
                                             int t_slot) {
  __shared__ float sA[64 * 132];
  int tid = threadIdx.x;
  int rb = blockIdx.x * 64;
  for (int idx = tid; idx < 64 * 32; idx += 256) {
    int r = idx >> 5, kq = (idx & 31) << 2;
    *(float4*)&sA[r * 132 + kq] = *(const float4*)&z[(size_t)(rb + r) * DH + kq];
  }
  __syncthreads();

  int cg = tid & 31, rg = tid >> 5;
  int c0 = cg << 2, r0 = rg << 3;
  float acc[8][4];
  {
    float4 bb = *(const float4*)&b1[c0];
#pragma unroll
    for (int i = 0; i < 8; ++i) { acc[i][0] = bb.x; acc[i][1] = bb.y; acc[i][2] = bb.z; acc[i][3] = bb.w; }
  }
  gemm_tile_g(sA, (const float4*)W1, acc, r0, cg);
  __syncthreads();
#pragma unroll
  for (int i = 0; i < 8; ++i) {
    float4 v;
    v.x = fmaxf(acc[i][0], 0.0f); v.y = fmaxf(acc[i][1], 0.0f);
    v.z = fmaxf(acc[i][2], 0.0f); v.w = fmaxf(acc[i][3], 0.0f);
    *(float4*)&sA[(r0 + i) * 132 + c0] = v;
  }
  __syncthreads();
  {
    float4 bb = *(const float4*)&b2[c0];
#pragma unroll
    for (int i = 0; i < 8; ++i) { acc[i][0] = bb.x; acc[i][1] = bb.y; acc[i][2] = bb.z; acc[i][3] = bb.w; }
  }
  gemm_tile_g(sA, (const float4*)W2, acc, r0, cg);

  int node0 = rb + r0;
#pragma unroll
  for (int i = 0; i < 8; ++i) {
    float4 v = make_float4(acc[i][0], acc[i][1], acc[i][2], acc[i][3]);
    *(float4*)&h_out[(size_t)(node0 + i) * DH + c0] = v;
    uint2 hv;
    hv.x = pack_bf2(acc[i][0], acc[i][1]);
    hv.y = pack_bf2(acc[i][2], acc[i][3]);
    *(uint2*)&hb_out[(size_t)(node0 + i) * 64 + (c0 >> 1)] = hv;
  }
  float* pbase = pooled + t_slot * DH;
  int g_first = graph_ids[node0];
  int g_last = graph_ids[node0 + 7];
  if (g_first == g_last) {
    float s0 = 0.f, s1 = 0.f, s2 = 0.f, s3 = 0.f;
#pragma unroll
    for (int i = 0; i < 8; ++i) { s0 += acc[i][0]; s1 += acc[i][1]; s2 += acc[i][2]; s3 += acc[i][3]; }
    atomicAdd(&pbase[g_first * 512 + c0 + 0], s0);
    atomicAdd(&pbase[g_first * 512 + c0 + 1], s1);
    atomicAdd(&pbase[g_first * 512 + c0 + 2], s2);
    atomicAdd(&pbase[g_first * 512 + c0 + 3], s3);
  } else {
#pragma unroll
    for (int i = 0; i < 8; ++i) {
      int g = graph_ids[node0 + i];
      atomicAdd(&pbase[g * 512 + c0 + 0], acc[i][0]);
      atomicAdd(&pbase[g * 512 + c0 + 1], acc[i][1]);
      atomicAdd(&pbase[g * 512 + c0 + 2], acc[i][2]);
      atomicAdd(&pbase[g * 512 + c0 + 3], acc[i][3]);
    }
  }
}

// ---------------- final: out = pooled @ Wl + bl ----------------
__global__ __launch_bounds__(256) void k_final(const float* __restrict__ pooled,
                                               const float* __restrict__ Wl,
                                               const float* __restrict__ bl,
                                               float* __restrict__ out) {
  int g = blockIdx.x, o = threadIdx.x;
  __shared__ float sp[DH * T_ITERS];
  for (int idx = o; idx < DH * T_ITERS; idx += 256) sp[idx] = pooled[g * (DH * T_ITERS) + idx];
  __syncthreads();
  float acc = bl[o];
#pragma unroll 8
  for (int j = 0; j < DH * T_ITERS; ++j)
    acc = fmaf(sp[j], Wl[j * DOUT + o], acc);
  out[g * DOUT + o] = acc;
}

extern "C" void kernel_launch(void* const* d_in, const int* in_sizes, int n_in,
                              void* d_out, int out_size, void* d_ws, size_t ws_size,
                              hipStream_t stream) {
  const float* x         = (const float*)d_in[0];
  const int*   edge_index= (const int*)d_in[1];
  const float* edge_attr = (const float*)d_in[2];
  const int*   graph_ids = (const int*)d_in[3];
  const float* Wn = (const float*)d_in[4];
  const float* bn = (const float*)d_in[5];
  const float* We = (const float*)d_in[6];
  const float* be = (const float*)d_in[7];
  const float* W1 = (const float*)d_in[8];
  const float* b1 = (const float*)d_in[9];
  const float* W2 = (const float*)d_in[10];
  const float* b2 = (const float*)d_in[11];
  const float* Wl = (const float*)d_in[12];
  const float* bl = (const float*)d_in[13];
  float* out = (float*)d_out;

  char* p = (char*)d_ws;
  auto alloc = [&](size_t bytes) { char* r = p; p += (bytes + 255) & ~(size_t)255; return r; };
  float*  h        = (float*)alloc((size_t)N_NODES * DH * 4);   // fallback path only
  float*  z        = (float*)alloc((size_t)N_NODES * DH * 4);   // primary path reuses as zb
  uint32* hb       = (uint32*)alloc((size_t)N_NODES * DH * 2);
  float*  pooled   = (float*)alloc((size_t)N_GRAPHS * DH * T_ITERS * 4);
  int*    counts   = (int*)alloc((size_t)N_NODES * 4);          // reused as w1t/w2t after scan
  int*    row_start= (int*)alloc((size_t)(N_NODES + 1) * 4);
  int*    cursor   = (int*)alloc((size_t)N_NODES * 4);
  int*    src_perm = (int*)alloc((size_t)N_EDGES * 4);
  int*    blk_sums = (int*)alloc(256);
  int*    blk_off  = (int*)alloc(256);

  const int* src = edge_index;
  const int* dst = edge_index + N_EDGES;

  size_t used = (size_t)(p - (char*)d_ws);
  size_t need_e = used + (size_t)N_EDGES * DH * 2 + 4096;   // e_perm 160 MB

  hipMemsetAsync(counts, 0, (size_t)N_NODES * 4, stream);
  hipMemsetAsync(pooled, 0, (size_t)N_GRAPHS * DH * T_ITERS * 4, stream);

  k_embed<<<N_NODES * DH / 256, 256, 0, stream>>>(x, Wn, bn, h, (ushort16*)hb);
  k_hist<<<N_EDGES / 256, 256, 0, stream>>>(dst, counts);
  k_scan1<<<SCAN_BLK, 1024, 0, stream>>>(counts, row_start, blk_sums);
  k_scan2<<<1, 64, 0, stream>>>(blk_sums, blk_off, row_start);
  k_scan3<<<SCAN_BLK, 1024, 0, stream>>>(row_start, blk_off, cursor);

  if (ws_size >= need_e) {
    uint32* e_perm = (uint32*)alloc((size_t)N_EDGES * DH * 2);
    uint32* zb = (uint32*)z;                              // overlay (z fp32 unused here)
    ushort16* w1t = (ushort16*)counts;                    // counts dead after scan
    ushort16* w2t = w1t + 128 * 128;
    k_prep_w<<<128, 256, 0, stream>>>(W1, W2, w1t, w2t);
    k_perm_e<<<N_EDGES / 256, 256, 0, stream>>>(src, dst, (const float4*)edge_attr,
                                                We, be, cursor, src_perm, e_perm);
    for (int t = 0; t < T_ITERS; ++t) {
      k_agg_lite<<<N_NODES / 4, 256, 0, stream>>>(hb, e_perm, row_start, src_perm, zb);
      k_mlp_mfma<<<N_NODES / 64, 256, 0, stream>>>(zb, w1t, w2t, b1, b2, graph_ids,
                                                   hb, pooled, t);
    }
  } else {
    int* eid_perm = (int*)alloc((size_t)N_EDGES * 4);
    k_permute<<<N_EDGES / 256, 256, 0, stream>>>(src, dst, cursor, src_perm, eid_perm);
    for (int t = 0; t < T_ITERS; ++t) {
      k_agg_ind<<<N_NODES / 4, 256, 0, stream>>>(h, hb, edge_attr, We, be, row_start, src_perm, eid_perm, z);
      k_mlp<<<N_NODES / 64, 256, 0, stream>>>(z, W1, b1, W2, b2, graph_ids, h, (uint32*)hb, pooled, t);
    }
  }
  k_final<<<N_GRAPHS, 256, 0, stream>>>(pooled, Wl, bl, out);
}

// Round 15
// 394.056 us; speedup vs baseline: 1.8873x; 1.1174x over previous
//
#include <hip/hip_runtime.h>

#define N_NODES   40000
#define N_EDGES   640000
#define N_GRAPHS  64
#define DIM_IN    32
#define N_ETYPE   16
#define DH        128
#define DOUT      256
#define T_ITERS   4
#define SCAN_BLK  40          // ceil(40000/1024)

typedef unsigned int uint32;
typedef unsigned short ushort16;
typedef __attribute__((ext_vector_type(8))) short bf16x8;
typedef __attribute__((ext_vector_type(4))) float f32x4;

__device__ __forceinline__ uint32 f2bf1(float f) {
  uint32 u = __float_as_uint(f);
  return (u + 0x7fffu + ((u >> 16) & 1u)) >> 16;
}
__device__ __forceinline__ uint32 pack_bf2(float lo, float hi) {
  return (f2bf1(hi) << 16) | f2bf1(lo);
}
#define UPLO(u) __uint_as_float((u) << 16)
#define UPHI(u) __uint_as_float((u) & 0xffff0000u)

// int8 e quantization: scale 64 (dequant 1/64), clamp +-127
#define EQ_SCALE   64.0f
#define EQ_INV     0.015625f
#define E2F0(E) ((float)((signed char)((E) & 0xff)) * EQ_INV)
#define E2F1(E) ((float)((signed char)((E) >> 8)) * EQ_INV)

// ---------------- node embedding: h = x @ Wn + bn (fp32 + bf16 mirror) ----------------
__global__ __launch_bounds__(256) void k_embed(const float* __restrict__ x,
                                               const float* __restrict__ Wn,
                                               const float* __restrict__ bn,
                                               float* __restrict__ h,
                                               ushort16* __restrict__ hb) {
  int idx = blockIdx.x * 256 + threadIdx.x;     // n*128 + c, exact grid
  int n = idx >> 7, c = idx & 127;
  const float* xr = x + n * DIM_IN;
  float acc = bn[c];
#pragma unroll
  for (int k = 0; k < DIM_IN; ++k)
    acc = fmaf(xr[k], Wn[k * DH + c], acc);
  h[idx] = acc;
  hb[idx] = (ushort16)f2bf1(acc);
}

// ---------------- CSR build ----------------
__global__ __launch_bounds__(256) void k_hist(const int* __restrict__ dst,
                                              int* __restrict__ counts) {
  int i = blockIdx.x * 256 + threadIdx.x;
  atomicAdd(&counts[dst[i]], 1);
}

// ---- 3-pass parallel scan ----
__global__ __launch_bounds__(1024) void k_scan1(const int* __restrict__ counts,
                                                int* __restrict__ excl,      // = row_start
                                                int* __restrict__ blk_sums) {
  __shared__ int wsums[16];
  int tid = threadIdx.x, lane = tid & 63, w = tid >> 6;
  int i = blockIdx.x * 1024 + tid;
  int v = (i < N_NODES) ? counts[i] : 0;
  int s = v;
#pragma unroll
  for (int off = 1; off < 64; off <<= 1) {
    int t = __shfl_up(s, off);
    if (lane >= off) s += t;
  }
  if (lane == 63) wsums[w] = s;
  __syncthreads();
  if (tid < 16) {
    int ws_ = wsums[tid];
#pragma unroll
    for (int off = 1; off < 16; off <<= 1) {
      int t = __shfl_up(ws_, off);
      if (tid >= off) ws_ += t;
    }
    wsums[tid] = ws_;
  }
  __syncthreads();
  int e = s - v + (w ? wsums[w - 1] : 0);
  if (i < N_NODES) excl[i] = e;
  if (tid == 0) blk_sums[blockIdx.x] = wsums[15];
}

__global__ __launch_bounds__(64) void k_scan2(const int* __restrict__ blk_sums,
                                              int* __restrict__ blk_off,
                                              int* __restrict__ row_start) {
  int lane = threadIdx.x;
  int v = (lane < SCAN_BLK) ? blk_sums[lane] : 0;
  int s = v;
#pragma unroll
  for (int off = 1; off < 64; off <<= 1) {
    int t = __shfl_up(s, off);
    if (lane >= off) s += t;
  }
  if (lane < SCAN_BLK) blk_off[lane] = s - v;
  if (lane == 63) row_start[N_NODES] = s;
}

__global__ __launch_bounds__(1024) void k_scan3(int* __restrict__ row_start,
                                                const int* __restrict__ blk_off,
                                                int* __restrict__ cursor) {
  int i = blockIdx.x * 1024 + threadIdx.x;
  if (i < N_NODES) {
    int v = row_start[i] + blk_off[blockIdx.x];
    row_start[i] = v;
    cursor[i] = v;
  }
}

__global__ __launch_bounds__(256) void k_permute(const int* __restrict__ src,
                                                 const int* __restrict__ dst,
                                                 int* __restrict__ cursor,
                                                 int* __restrict__ src_perm,
                                                 int* __restrict__ eid_perm) {
  int i = blockIdx.x * 256 + threadIdx.x;
  int d = dst[i];
  int pos = atomicAdd(&cursor[d], 1);
  src_perm[pos] = src[i];
  eid_perm[pos] = i;
}

#define MAC16(A0,A1,A2,A3)                                          \
  p0 = fmaf(A0.x, we0[0], p0);  p1 = fmaf(A0.x, we1[0], p1);        \
  p0 = fmaf(A0.y, we0[1], p0);  p1 = fmaf(A0.y, we1[1], p1);        \
  p0 = fmaf(A0.z, we0[2], p0);  p1 = fmaf(A0.z, we1[2], p1);        \
  p0 = fmaf(A0.w, we0[3], p0);  p1 = fmaf(A0.w, we1[3], p1);        \
  p0 = fmaf(A1.x, we0[4], p0);  p1 = fmaf(A1.x, we1[4], p1);        \
  p0 = fmaf(A1.y, we0[5], p0);  p1 = fmaf(A1.y, we1[5], p1);        \
  p0 = fmaf(A1.z, we0[6], p0);  p1 = fmaf(A1.z, we1[6], p1);        \
  p0 = fmaf(A1.w, we0[7], p0);  p1 = fmaf(A1.w, we1[7], p1);        \
  p0 = fmaf(A2.x, we0[8], p0);  p1 = fmaf(A2.x, we1[8], p1);        \
  p0 = fmaf(A2.y, we0[9], p0);  p1 = fmaf(A2.y, we1[9], p1);        \
  p0 = fmaf(A2.z, we0[10], p0); p1 = fmaf(A2.z, we1[10], p1);       \
  p0 = fmaf(A2.w, we0[11], p0); p1 = fmaf(A2.w, we1[11], p1);       \
  p0 = fmaf(A3.x, we0[12], p0); p1 = fmaf(A3.x, we1[12], p1);       \
  p0 = fmaf(A3.y, we0[13], p0); p1 = fmaf(A3.y, we1[13], p1);       \
  p0 = fmaf(A3.z, we0[14], p0); p1 = fmaf(A3.z, we1[14], p1);       \
  p0 = fmaf(A3.w, we0[15], p0); p1 = fmaf(A3.w, we1[15], p1);

#define RELU_ACC(G)                                                  \
  acc0 += fmaxf(UPLO(G) + p0, 0.0f);                                 \
  acc1 += fmaxf(UPHI(G) + p1, 0.0f);

// int8-e message accumulate
#define ACC2Q(G,E)                                                   \
  acc0 += fmaxf(UPLO(G) + E2F0(E), 0.0f);                            \
  acc1 += fmaxf(UPHI(G) + E2F1(E), 0.0f);

// ---- one-time merged pass: CSR permute + e8_perm[pos] = int8(edge_attr[i]@We + be) ----
__global__ __launch_bounds__(256) void k_perm_e(const int* __restrict__ src,
                                                const int* __restrict__ dst,
                                                const float4* __restrict__ edge_attr,
                                                const float* __restrict__ We,
                                                const float* __restrict__ be,
                                                int* __restrict__ cursor,
                                                int* __restrict__ src_perm,
                                                unsigned short* __restrict__ e8_perm) {
  __shared__ float4 sAttr[1024];     // 256 edges x 16 floats = 16 KB
  __shared__ int spos[256];
  int tid = threadIdx.x;
  int i = blockIdx.x * 256 + tid;
  int d = dst[i];
  int pos = atomicAdd(&cursor[d], 1);
  src_perm[pos] = src[i];
  spos[tid] = pos;
  size_t blockBase = (size_t)blockIdx.x * 1024;   // float4 units
  for (int idx = tid; idx < 1024; idx += 256)
    sAttr[idx] = edge_attr[blockBase + idx];
  __syncthreads();
  int lane = tid & 63, wv = tid >> 6;
  int c = lane << 1;
  float we0[N_ETYPE], we1[N_ETYPE];
#pragma unroll
  for (int k = 0; k < N_ETYPE; ++k) {
    we0[k] = We[k * DH + c];
    we1[k] = We[k * DH + c + 1];
  }
  float be0 = be[c], be1 = be[c + 1];
  const float4* a = &sAttr[wv << 8];   // 64 edges x 4 float4
  const int* wp = &spos[wv << 6];
#pragma unroll 2
  for (int j = 0; j < 64; ++j) {
    int pos_j = wp[j];
    float4 a0 = a[j * 4 + 0], a1 = a[j * 4 + 1], a2 = a[j * 4 + 2], a3 = a[j * 4 + 3];
    float p0 = be0, p1 = be1;
    MAC16(a0, a1, a2, a3)
    int q0 = (int)rintf(p0 * EQ_SCALE);
    int q1 = (int)rintf(p1 * EQ_SCALE);
    q0 = q0 > 127 ? 127 : (q0 < -127 ? -127 : q0);
    q1 = q1 > 127 ? 127 : (q1 < -127 ? -127 : q1);
    e8_perm[((size_t)pos_j << 6) + lane] =
        (unsigned short)((q0 & 0xff) | ((q1 & 0xff) << 8));
  }
}

// -------- aggregation: zb[n] = bf16(hb[n] + sum relu(hb[src] + dequant(e8))) --------
__global__ __launch_bounds__(256) void k_agg_lite(const uint32* __restrict__ hb,
                                                  const unsigned short* __restrict__ e8_perm,
                                                  const int* __restrict__ row_start,
                                                  const int* __restrict__ src_perm,
                                                  uint32* __restrict__ zb) {
  int lane = threadIdx.x & 63;
  int n = (blockIdx.x << 2) + (threadIdx.x >> 6);
  uint32 hself = hb[(size_t)n * 64 + lane];
  float acc0 = UPLO(hself);
  float acc1 = UPHI(hself);
  int beg = row_start[n], end = row_start[n + 1];
  const unsigned short* ep = e8_perm + ((size_t)beg << 6) + lane;
  const int* sp = src_perm + beg;
  int m = end - beg;
  int i = 0;
  for (; i + 16 <= m; i += 16, ep += 1024, sp += 16) {
    int ss[16];
    uint32 gg[16];
    unsigned short ee[16];
#pragma unroll
    for (int k = 0; k < 16; ++k) ss[k] = sp[k];
#pragma unroll
    for (int k = 0; k < 16; ++k) gg[k] = hb[((size_t)ss[k] << 6) + lane];
#pragma unroll
    for (int k = 0; k < 16; ++k) ee[k] = ep[k * 64];
#pragma unroll
    for (int k = 0; k < 16; ++k) { ACC2Q(gg[k], ee[k]) }
  }
  for (; i + 4 <= m; i += 4, ep += 256, sp += 4) {
    int ss[4];
    uint32 gg[4];
    unsigned short ee[4];
#pragma unroll
    for (int k = 0; k < 4; ++k) ss[k] = sp[k];
#pragma unroll
    for (int k = 0; k < 4; ++k) gg[k] = hb[((size_t)ss[k] << 6) + lane];
#pragma unroll
    for (int k = 0; k < 4; ++k) ee[k] = ep[k * 64];
#pragma unroll
    for (int k = 0; k < 4; ++k) { ACC2Q(gg[k], ee[k]) }
  }
  for (; i < m; ++i, ep += 64, ++sp) {
    int s0 = sp[0];
    uint32 g0 = hb[((size_t)s0 << 6) + lane];
    unsigned short e0 = ep[0];
    ACC2Q(g0, e0)
  }
  zb[(size_t)n * 64 + lane] = pack_bf2(acc0, acc1);
}

// ---- one-time: transpose W1,W2 -> bf16 [out_col][in_k] for MFMA B operands ----
__global__ __launch_bounds__(256) void k_prep_w(const float* __restrict__ W1,
                                                const float* __restrict__ W2,
                                                ushort16* __restrict__ w1t,
                                                ushort16* __restrict__ w2t) {
  int id = blockIdx.x * 256 + threadIdx.x;   // 0..32767
  int which = id >> 14;
  int rem = id & 16383;
  int k = rem >> 7, n = rem & 127;
  const float* W = which ? W2 : W1;
  ushort16* wt = which ? w2t : w1t;
  wt[n * 128 + k] = (ushort16)f2bf1(W[k * 128 + n]);
}

// ------- MFMA MLP (R14-verified): LDS-staged W, bf16-only coalesced epilogue -------
__global__ __launch_bounds__(256) void k_mlp_mfma(const uint32* __restrict__ zb,
                                                  const ushort16* __restrict__ w1t,
                                                  const ushort16* __restrict__ w2t,
                                                  const float* __restrict__ b1,
                                                  const float* __restrict__ b2,
                                                  const int* __restrict__ graph_ids,
                                                  uint32* __restrict__ hb_out,
                                                  float* __restrict__ pooled,
                                                  int t_slot) {
  __shared__ ushort16 sW[128 * 136];   // 34816 B
  __shared__ ushort16 sA[64 * 136];    // 17408 B
  int tid = threadIdx.x;
  int rb = blockIdx.x * 64;

  for (int idx = tid; idx < 1024; idx += 256) {
    int row = idx >> 4, ch = idx & 15;
    *(uint4*)&sA[row * 136 + ch * 8] = *(const uint4*)&zb[(size_t)(rb + row) * 64 + ch * 4];
  }
  for (int idx = tid; idx < 2048; idx += 256) {
    int row = idx >> 4, ch = idx & 15;
    *(uint4*)&sW[row * 136 + ch * 8] = *(const uint4*)&w1t[row * 128 + ch * 8];
  }
  __syncthreads();

  int l = tid & 63, w = tid >> 6;
  int r = l & 15, g = l >> 4;

  f32x4 acc[8];
#pragma unroll
  for (int n = 0; n < 8; ++n) {
    float bv = b1[n * 16 + r];
    acc[n] = (f32x4){bv, bv, bv, bv};
  }
#pragma unroll
  for (int k0 = 0; k0 < 4; ++k0) {
    bf16x8 a = *(const bf16x8*)&sA[(w * 16 + r) * 136 + k0 * 32 + g * 8];
#pragma unroll
    for (int n = 0; n < 8; ++n) {
      bf16x8 b = *(const bf16x8*)&sW[(n * 16 + r) * 136 + k0 * 32 + g * 8];
      acc[n] = __builtin_amdgcn_mfma_f32_16x16x32_bf16(a, b, acc[n], 0, 0, 0);
    }
  }
#pragma unroll
  for (int n = 0; n < 8; ++n) {
#pragma unroll
    for (int q = 0; q < 4; ++q) {
      float v = fmaxf(acc[n][q], 0.0f);
      sA[(w * 16 + g * 4 + q) * 136 + n * 16 + r] = (ushort16)f2bf1(v);
    }
  }
  __syncthreads();
  for (int idx = tid; idx < 2048; idx += 256) {
    int row = idx >> 4, ch = idx & 15;
    *(uint4*)&sW[row * 136 + ch * 8] = *(const uint4*)&w2t[row * 128 + ch * 8];
  }
  __syncthreads();

#pragma unroll
  for (int n = 0; n < 8; ++n) {
    float bv = b2[n * 16 + r];
    acc[n] = (f32x4){bv, bv, bv, bv};
  }
#pragma unroll
  for (int k0 = 0; k0 < 4; ++k0) {
    bf16x8 a = *(const bf16x8*)&sA[(w * 16 + r) * 136 + k0 * 32 + g * 8];
#pragma unroll
    for (int n = 0; n < 8; ++n) {
      bf16x8 b = *(const bf16x8*)&sW[(n * 16 + r) * 136 + k0 * 32 + g * 8];
      acc[n] = __builtin_amdgcn_mfma_f32_16x16x32_bf16(a, b, acc[n], 0, 0, 0);
    }
  }

  // ---- pooled (fp32, from registers) ----
  float* pbase = pooled + t_slot * DH;
  int node0 = rb + w * 16;
  int gid0 = graph_ids[node0];
  if (gid0 == graph_ids[node0 + 15]) {
#pragma unroll
    for (int n = 0; n < 8; ++n) {
      float s = acc[n][0] + acc[n][1] + acc[n][2] + acc[n][3];
      s += __shfl_xor(s, 16);
      s += __shfl_xor(s, 32);
      if (l < 16) atomicAdd(&pbase[gid0 * 512 + n * 16 + r], s);
    }
  } else {
#pragma unroll
    for (int q = 0; q < 4; ++q) {
      int node = node0 + g * 4 + q;
      int gg = graph_ids[node];
#pragma unroll
      for (int n = 0; n < 8; ++n)
        atomicAdd(&pbase[gg * 512 + n * 16 + r], acc[n][q]);
    }
  }

  // ---- epilogue: pack bf16 into own sA rows, coalesced hb store ----
#pragma unroll
  for (int n = 0; n < 8; ++n)
#pragma unroll
    for (int q = 0; q < 4; ++q)
      sA[(w * 16 + g * 4 + q) * 136 + n * 16 + r] = (ushort16)f2bf1(acc[n][q]);
  __syncthreads();
  for (int idx = tid; idx < 4096; idx += 256) {   // 64 rows x 64 dwords
    int row = idx >> 6, dw = idx & 63;
    uint32 v = *(const uint32*)&sA[row * 136 + dw * 2];
    hb_out[(size_t)(rb + row) * 64 + dw] = v;
  }
}

// -------- aggregation, fallback indirect path --------
__global__ __launch_bounds__(256, 8) void k_agg_ind(const float* __restrict__ h,
                                                    const uint32* __restrict__ hb,
                                                    const float* __restrict__ edge_attr,
                                                    const float* __restrict__ We,
                                                    const float* __restrict__ be,
                                                    const int* __restrict__ row_start,
                                                    const int* __restrict__ src_perm,
                                                    const int* __restrict__ eid_perm,
                                                    float* __restrict__ z) {
  int lane = threadIdx.x & 63;
  int n = (blockIdx.x << 2) + (threadIdx.x >> 6);
  int c = lane << 1;
  float we0[N_ETYPE], we1[N_ETYPE];
#pragma unroll
  for (int k = 0; k < N_ETYPE; ++k) {
    we0[k] = We[k * DH + c];
    we1[k] = We[k * DH + c + 1];
  }
  float be0 = be[c], be1 = be[c + 1];
  float2 hself = *(const float2*)&h[(size_t)n * DH + c];
  float acc0 = hself.x, acc1 = hself.y;
  int beg = row_start[n], end = row_start[n + 1];
  int i = beg;
  for (; i + 1 < end; i += 2) {
    int s0 = src_perm[i], s1 = src_perm[i + 1];
    int e0i = eid_perm[i], e1i = eid_perm[i + 1];
    uint32 g0 = hb[((size_t)s0 << 6) + lane];
    uint32 g1 = hb[((size_t)s1 << 6) + lane];
    const float4* eA = (const float4*)(edge_attr + (size_t)e0i * N_ETYPE);
    const float4* eB = (const float4*)(edge_attr + (size_t)e1i * N_ETYPE);
    float4 a0 = eA[0], a1 = eA[1], a2 = eA[2], a3 = eA[3];
    float p0, p1;
    p0 = be0; p1 = be1; MAC16(a0, a1, a2, a3) RELU_ACC(g0)
    float4 b0 = eB[0], b1v = eB[1], b2v = eB[2], b3 = eB[3];
    p0 = be0; p1 = be1; MAC16(b0, b1v, b2v, b3) RELU_ACC(g1)
  }
  if (i < end) {
    int s0 = src_perm[i];
    int e0i = eid_perm[i];
    uint32 g0 = hb[((size_t)s0 << 6) + lane];
    const float4* eA = (const float4*)(edge_attr + (size_t)e0i * N_ETYPE);
    float4 a0 = eA[0], a1 = eA[1], a2 = eA[2], a3 = eA[3];
    float p0 = be0, p1 = be1;
    MAC16(a0, a1, a2, a3) RELU_ACC(g0)
  }
  *(float2*)&z[(size_t)n * DH + c] = make_float2(acc0, acc1);
}

// ---------------- fallback fp32 MLP ----------------
#define MLPFMA(K, U0, U1)                                            \
  {                                                                  \
    _Pragma("unroll")                                                \
    for (int i_ = 0; i_ < 8; ++i_) {                                 \
      float2 a_ = *(const float2*)&sA[(r0 + i_) * 132 + (K)];        \
      acc[i_][0] = fmaf(a_.x, U0.x, acc[i_][0]);                     \
      acc[i_][1] = fmaf(a_.x, U0.y, acc[i_][1]);                     \
      acc[i_][2] = fmaf(a_.x, U0.z, acc[i_][2]);                     \
      acc[i_][3] = fmaf(a_.x, U0.w, acc[i_][3]);                     \
      acc[i_][0] = fmaf(a_.y, U1.x, acc[i_][0]);                     \
      acc[i_][1] = fmaf(a_.y, U1.y, acc[i_][1]);                     \
      acc[i_][2] = fmaf(a_.y, U1.z, acc[i_][2]);                     \
      acc[i_][3] = fmaf(a_.y, U1.w, acc[i_][3]);                     \
    }                                                                \
  }

__device__ __forceinline__ void gemm_tile_g(const float* sA, const float4* __restrict__ Wv,
                                            float acc[8][4], int r0, int cg) {
  float4 c0 = Wv[cg],       c1 = Wv[32 + cg];
  float4 n0 = Wv[64 + cg],  n1 = Wv[96 + cg];
#pragma unroll 4
  for (int k = 0; k < DH - 4; k += 2) {
    float4 u0 = c0, u1 = c1;
    c0 = n0; c1 = n1;
    n0 = Wv[(k + 4) * 32 + cg];
    n1 = Wv[(k + 5) * 32 + cg];
    MLPFMA(k, u0, u1)
  }
  MLPFMA(DH - 4, c0, c1)
  MLPFMA(DH - 2, n0, n1)
}

__global__ __launch_bounds__(256) void k_mlp(const float* __restrict__ z,
                                             const float* __restrict__ W1,
                                             const float* __restrict__ b1,
                                             const float* __restrict__ W2,
                                             const float* __restrict__ b2,
                                             const int* __restrict__ graph_ids,
                                             float* __restrict__ h_out,
                                             uint32* __restrict__ hb_out,
                                             float* __restrict__ pooled,
                                             int t_slot) {
  __shared__ float sA[64 * 132];
  int tid = threadIdx.x;
  int rb = blockIdx.x * 64;
  for (int idx = tid; idx < 64 * 32; idx += 256) {
    int r = idx >> 5, kq = (idx & 31) << 2;
    *(float4*)&sA[r * 132 + kq] = *(const float4*)&z[(size_t)(rb + r) * DH + kq];
  }
  __syncthreads();

  int cg = tid & 31, rg = tid >> 5;
  int c0 = cg << 2, r0 = rg << 3;
  float acc[8][4];
  {
    float4 bb = *(const float4*)&b1[c0];
#pragma unroll
    for (int i = 0; i < 8; ++i) { acc[i][0] = bb.x; acc[i][1] = bb.y; acc[i][2] = bb.z; acc[i][3] = bb.w; }
  }
  gemm_tile_g(sA, (const float4*)W1, acc, r0, cg);
  __syncthreads();
#pragma unroll
  for (int i = 0; i < 8; ++i) {
    float4 v;
    v.x = fmaxf(acc[i][0], 0.0f); v.y = fmaxf(acc[i][1], 0.0f);
    v.z = fmaxf(acc[i][2], 0.0f); v.w = fmaxf(acc[i][3], 0.0f);
    *(float4*)&sA[(r0 + i) * 132 + c0] = v;
  }
  __syncthreads();
  {
    float4 bb = *(const float4*)&b2[c0];
#pragma unroll
    for (int i = 0; i < 8; ++i) { acc[i][0] = bb.x; acc[i][1] = bb.y; acc[i][2] = bb.z; acc[i][3] = bb.w; }
  }
  gemm_tile_g(sA, (const float4*)W2, acc, r0, cg);

  int node0 = rb + r0;
#pragma unroll
  for (int i = 0; i < 8; ++i) {
    float4 v = make_float4(acc[i][0], acc[i][1], acc[i][2], acc[i][3]);
    *(float4*)&h_out[(size_t)(node0 + i) * DH + c0] = v;
    uint2 hv;
    hv.x = pack_bf2(acc[i][0], acc[i][1]);
    hv.y = pack_bf2(acc[i][2], acc[i][3]);
    *(uint2*)&hb_out[(size_t)(node0 + i) * 64 + (c0 >> 1)] = hv;
  }
  float* pbase = pooled + t_slot * DH;
  int g_first = graph_ids[node0];
  int g_last = graph_ids[node0 + 7];
  if (g_first == g_last) {
    float s0 = 0.f, s1 = 0.f, s2 = 0.f, s3 = 0.f;
#pragma unroll
    for (int i = 0; i < 8; ++i) { s0 += acc[i][0]; s1 += acc[i][1]; s2 += acc[i][2]; s3 += acc[i][3]; }
    atomicAdd(&pbase[g_first * 512 + c0 + 0], s0);
    atomicAdd(&pbase[g_first * 512 + c0 + 1], s1);
    atomicAdd(&pbase[g_first * 512 + c0 + 2], s2);
    atomicAdd(&pbase[g_first * 512 + c0 + 3], s3);
  } else {
#pragma unroll
    for (int i = 0; i < 8; ++i) {
      int g = graph_ids[node0 + i];
      atomicAdd(&pbase[g * 512 + c0 + 0], acc[i][0]);
      atomicAdd(&pbase[g * 512 + c0 + 1], acc[i][1]);
      atomicAdd(&pbase[g * 512 + c0 + 2], acc[i][2]);
      atomicAdd(&pbase[g * 512 + c0 + 3], acc[i][3]);
    }
  }
}

// ---------------- final: out = pooled @ Wl + bl ----------------
__global__ __launch_bounds__(256) void k_final(const float* __restrict__ pooled,
                                               const float* __restrict__ Wl,
                                               const float* __restrict__ bl,
                                               float* __restrict__ out) {
  int g = blockIdx.x, o = threadIdx.x;
  __shared__ float sp[DH * T_ITERS];
  for (int idx = o; idx < DH * T_ITERS; idx += 256) sp[idx] = pooled[g * (DH * T_ITERS) + idx];
  __syncthreads();
  float acc = bl[o];
#pragma unroll 8
  for (int j = 0; j < DH * T_ITERS; ++j)
    acc = fmaf(sp[j], Wl[j * DOUT + o], acc);
  out[g * DOUT + o] = acc;
}

extern "C" void kernel_launch(void* const* d_in, const int* in_sizes, int n_in,
                              void* d_out, int out_size, void* d_ws, size_t ws_size,
                              hipStream_t stream) {
  const float* x         = (const float*)d_in[0];
  const int*   edge_index= (const int*)d_in[1];
  const float* edge_attr = (const float*)d_in[2];
  const int*   graph_ids = (const int*)d_in[3];
  const float* Wn = (const float*)d_in[4];
  const float* bn = (const float*)d_in[5];
  const float* We = (const float*)d_in[6];
  const float* be = (const float*)d_in[7];
  const float* W1 = (const float*)d_in[8];
  const float* b1 = (const float*)d_in[9];
  const float* W2 = (const float*)d_in[10];
  const float* b2 = (const float*)d_in[11];
  const float* Wl = (const float*)d_in[12];
  const float* bl = (const float*)d_in[13];
  float* out = (float*)d_out;

  char* p = (char*)d_ws;
  auto alloc = [&](size_t bytes) { char* r = p; p += (bytes + 255) & ~(size_t)255; return r; };
  float*  h        = (float*)alloc((size_t)N_NODES * DH * 4);   // fallback path only
  float*  z        = (float*)alloc((size_t)N_NODES * DH * 4);   // primary path reuses as zb
  uint32* hb       = (uint32*)alloc((size_t)N_NODES * DH * 2);
  float*  pooled   = (float*)alloc((size_t)N_GRAPHS * DH * T_ITERS * 4);
  int*    counts   = (int*)alloc((size_t)N_NODES * 4);          // reused as w1t/w2t after scan
  int*    row_start= (int*)alloc((size_t)(N_NODES + 1) * 4);
  int*    cursor   = (int*)alloc((size_t)N_NODES * 4);
  int*    src_perm = (int*)alloc((size_t)N_EDGES * 4);
  int*    blk_sums = (int*)alloc(256);
  int*    blk_off  = (int*)alloc(256);

  const int* src = edge_index;
  const int* dst = edge_index + N_EDGES;

  size_t used = (size_t)(p - (char*)d_ws);
  size_t need_e = used + (size_t)N_EDGES * DH + 4096;   // e8_perm 82 MB

  hipMemsetAsync(counts, 0, (size_t)N_NODES * 4, stream);
  hipMemsetAsync(pooled, 0, (size_t)N_GRAPHS * DH * T_ITERS * 4, stream);

  k_embed<<<N_NODES * DH / 256, 256, 0, stream>>>(x, Wn, bn, h, (ushort16*)hb);
  k_hist<<<N_EDGES / 256, 256, 0, stream>>>(dst, counts);
  k_scan1<<<SCAN_BLK, 1024, 0, stream>>>(counts, row_start, blk_sums);
  k_scan2<<<1, 64, 0, stream>>>(blk_sums, blk_off, row_start);
  k_scan3<<<SCAN_BLK, 1024, 0, stream>>>(row_start, blk_off, cursor);

  if (ws_size >= need_e) {
    unsigned short* e8_perm = (unsigned short*)alloc((size_t)N_EDGES * DH);
    uint32* zb = (uint32*)z;                              // overlay (z fp32 unused here)
    ushort16* w1t = (ushort16*)counts;                    // counts dead after scan
    ushort16* w2t = w1t + 128 * 128;
    k_prep_w<<<128, 256, 0, stream>>>(W1, W2, w1t, w2t);
    k_perm_e<<<N_EDGES / 256, 256, 0, stream>>>(src, dst, (const float4*)edge_attr,
                                                We, be, cursor, src_perm, e8_perm);
    for (int t = 0; t < T_ITERS; ++t) {
      k_agg_lite<<<N_NODES / 4, 256, 0, stream>>>(hb, e8_perm, row_start, src_perm, zb);
      k_mlp_mfma<<<N_NODES / 64, 256, 0, stream>>>(zb, w1t, w2t, b1, b2, graph_ids,
                                                   hb, pooled, t);
    }
  } else {
    int* eid_perm = (int*)alloc((size_t)N_EDGES * 4);
    k_permute<<<N_EDGES / 256, 256, 0, stream>>>(src, dst, cursor, src_perm, eid_perm);
    for (int t = 0; t < T_ITERS; ++t) {
      k_agg_ind<<<N_NODES / 4, 256, 0, stream>>>(h, hb, edge_attr, We, be, row_start, src_perm, eid_perm, z);
      k_mlp<<<N_NODES / 64, 256, 0, stream>>>(z, W1, b1, W2, b2, graph_ids, h, (uint32*)hb, pooled, t);
    }
  }
  k_final<<<N_GRAPHS, 256, 0, stream>>>(pooled, Wl, bl, out);
}

// Round 16
// 393.048 us; speedup vs baseline: 1.8922x; 1.0026x over previous
//
#include <hip/hip_runtime.h>

#define N_NODES   40000
#define N_EDGES   640000
#define N_GRAPHS  64
#define DIM_IN    32
#define N_ETYPE   16
#define DH        128
#define DOUT      256
#define T_ITERS   4
#define SCAN_BLK  40          // ceil(40000/1024)

typedef unsigned int uint32;
typedef unsigned short ushort16;
typedef __attribute__((ext_vector_type(8))) short bf16x8;
typedef __attribute__((ext_vector_type(4))) float f32x4;

__device__ __forceinline__ uint32 f2bf1(float f) {
  uint32 u = __float_as_uint(f);
  return (u + 0x7fffu + ((u >> 16) & 1u)) >> 16;
}
__device__ __forceinline__ uint32 pack_bf2(float lo, float hi) {
  return (f2bf1(hi) << 16) | f2bf1(lo);
}
#define UPLO(u) __uint_as_float((u) << 16)
#define UPHI(u) __uint_as_float((u) & 0xffff0000u)

// int8 e quantization: scale 64 (dequant 1/64), clamp +-127
#define EQ_SCALE   64.0f
#define EQ_INV     0.015625f
#define E2F0(E) ((float)((signed char)((E) & 0xff)) * EQ_INV)
#define E2F1(E) ((float)((signed char)((E) >> 8)) * EQ_INV)

// ---------------- node embedding, primary: hb only (h fp32 unused) ----------------
__global__ __launch_bounds__(256) void k_embed_nh(const float* __restrict__ x,
                                                  const float* __restrict__ Wn,
                                                  const float* __restrict__ bn,
                                                  ushort16* __restrict__ hb) {
  int idx = blockIdx.x * 256 + threadIdx.x;     // n*128 + c, exact grid
  int n = idx >> 7, c = idx & 127;
  const float* xr = x + n * DIM_IN;
  float acc = bn[c];
#pragma unroll
  for (int k = 0; k < DIM_IN; ++k)
    acc = fmaf(xr[k], Wn[k * DH + c], acc);
  hb[idx] = (ushort16)f2bf1(acc);
}

// ---------------- node embedding, fallback: fp32 + bf16 mirror ----------------
__global__ __launch_bounds__(256) void k_embed(const float* __restrict__ x,
                                               const float* __restrict__ Wn,
                                               const float* __restrict__ bn,
                                               float* __restrict__ h,
                                               ushort16* __restrict__ hb) {
  int idx = blockIdx.x * 256 + threadIdx.x;
  int n = idx >> 7, c = idx & 127;
  const float* xr = x + n * DIM_IN;
  float acc = bn[c];
#pragma unroll
  for (int k = 0; k < DIM_IN; ++k)
    acc = fmaf(xr[k], Wn[k * DH + c], acc);
  h[idx] = acc;
  hb[idx] = (ushort16)f2bf1(acc);
}

// ---------------- CSR build ----------------
__global__ __launch_bounds__(256) void k_hist(const int* __restrict__ dst,
                                              int* __restrict__ counts) {
  int i = blockIdx.x * 256 + threadIdx.x;
  atomicAdd(&counts[dst[i]], 1);
}

// ---- 3-pass parallel scan ----
__global__ __launch_bounds__(1024) void k_scan1(const int* __restrict__ counts,
                                                int* __restrict__ excl,      // = row_start
                                                int* __restrict__ blk_sums) {
  __shared__ int wsums[16];
  int tid = threadIdx.x, lane = tid & 63, w = tid >> 6;
  int i = blockIdx.x * 1024 + tid;
  int v = (i < N_NODES) ? counts[i] : 0;
  int s = v;
#pragma unroll
  for (int off = 1; off < 64; off <<= 1) {
    int t = __shfl_up(s, off);
    if (lane >= off) s += t;
  }
  if (lane == 63) wsums[w] = s;
  __syncthreads();
  if (tid < 16) {
    int ws_ = wsums[tid];
#pragma unroll
    for (int off = 1; off < 16; off <<= 1) {
      int t = __shfl_up(ws_, off);
      if (tid >= off) ws_ += t;
    }
    wsums[tid] = ws_;
  }
  __syncthreads();
  int e = s - v + (w ? wsums[w - 1] : 0);
  if (i < N_NODES) excl[i] = e;
  if (tid == 0) blk_sums[blockIdx.x] = wsums[15];
}

__global__ __launch_bounds__(64) void k_scan2(const int* __restrict__ blk_sums,
                                              int* __restrict__ blk_off,
                                              int* __restrict__ row_start) {
  int lane = threadIdx.x;
  int v = (lane < SCAN_BLK) ? blk_sums[lane] : 0;
  int s = v;
#pragma unroll
  for (int off = 1; off < 64; off <<= 1) {
    int t = __shfl_up(s, off);
    if (lane >= off) s += t;
  }
  if (lane < SCAN_BLK) blk_off[lane] = s - v;
  if (lane == 63) row_start[N_NODES] = s;
}

__global__ __launch_bounds__(1024) void k_scan3(int* __restrict__ row_start,
                                                const int* __restrict__ blk_off,
                                                int* __restrict__ cursor) {
  int i = blockIdx.x * 1024 + threadIdx.x;
  if (i < N_NODES) {
    int v = row_start[i] + blk_off[blockIdx.x];
    row_start[i] = v;
    cursor[i] = v;
  }
}

__global__ __launch_bounds__(256) void k_permute(const int* __restrict__ src,
                                                 const int* __restrict__ dst,
                                                 int* __restrict__ cursor,
                                                 int* __restrict__ src_perm,
                                                 int* __restrict__ eid_perm) {
  int i = blockIdx.x * 256 + threadIdx.x;
  int d = dst[i];
  int pos = atomicAdd(&cursor[d], 1);
  src_perm[pos] = src[i];
  eid_perm[pos] = i;
}

#define MAC16(A0,A1,A2,A3)                                          \
  p0 = fmaf(A0.x, we0[0], p0);  p1 = fmaf(A0.x, we1[0], p1);        \
  p0 = fmaf(A0.y, we0[1], p0);  p1 = fmaf(A0.y, we1[1], p1);        \
  p0 = fmaf(A0.z, we0[2], p0);  p1 = fmaf(A0.z, we1[2], p1);        \
  p0 = fmaf(A0.w, we0[3], p0);  p1 = fmaf(A0.w, we1[3], p1);        \
  p0 = fmaf(A1.x, we0[4], p0);  p1 = fmaf(A1.x, we1[4], p1);        \
  p0 = fmaf(A1.y, we0[5], p0);  p1 = fmaf(A1.y, we1[5], p1);        \
  p0 = fmaf(A1.z, we0[6], p0);  p1 = fmaf(A1.z, we1[6], p1);        \
  p0 = fmaf(A1.w, we0[7], p0);  p1 = fmaf(A1.w, we1[7], p1);        \
  p0 = fmaf(A2.x, we0[8], p0);  p1 = fmaf(A2.x, we1[8], p1);        \
  p0 = fmaf(A2.y, we0[9], p0);  p1 = fmaf(A2.y, we1[9], p1);        \
  p0 = fmaf(A2.z, we0[10], p0); p1 = fmaf(A2.z, we1[10], p1);       \
  p0 = fmaf(A2.w, we0[11], p0); p1 = fmaf(A2.w, we1[11], p1);       \
  p0 = fmaf(A3.x, we0[12], p0); p1 = fmaf(A3.x, we1[12], p1);       \
  p0 = fmaf(A3.y, we0[13], p0); p1 = fmaf(A3.y, we1[13], p1);       \
  p0 = fmaf(A3.z, we0[14], p0); p1 = fmaf(A3.z, we1[14], p1);       \
  p0 = fmaf(A3.w, we0[15], p0); p1 = fmaf(A3.w, we1[15], p1);

#define RELU_ACC(G)                                                  \
  acc0 += fmaxf(UPLO(G) + p0, 0.0f);                                 \
  acc1 += fmaxf(UPHI(G) + p1, 0.0f);

#define ACC2Q(G,E)                                                   \
  acc0 += fmaxf(UPLO(G) + E2F0(E), 0.0f);                            \
  acc1 += fmaxf(UPHI(G) + E2F1(E), 0.0f);

// ---- one-time merged pass: CSR permute + e8_perm[pos] = int8(edge_attr[i]@We + be) ----
// 128 edges / 128-thread block (2 waves) for higher occupancy on the scatter writes.
__global__ __launch_bounds__(128) void k_perm_e(const int* __restrict__ src,
                                                const int* __restrict__ dst,
                                                const float4* __restrict__ edge_attr,
                                                const float* __restrict__ We,
                                                const float* __restrict__ be,
                                                int* __restrict__ cursor,
                                                int* __restrict__ src_perm,
                                                unsigned short* __restrict__ e8_perm) {
  __shared__ float4 sAttr[512];      // 128 edges x 16 floats = 8 KB
  __shared__ int spos[128];
  int tid = threadIdx.x;
  int i = blockIdx.x * 128 + tid;
  int d = dst[i];
  int pos = atomicAdd(&cursor[d], 1);
  src_perm[pos] = src[i];
  spos[tid] = pos;
  size_t blockBase = (size_t)blockIdx.x * 512;   // float4 units
  for (int idx = tid; idx < 512; idx += 128)
    sAttr[idx] = edge_attr[blockBase + idx];
  __syncthreads();
  int lane = tid & 63, wv = tid >> 6;            // wv in {0,1}
  int c = lane << 1;
  float we0[N_ETYPE], we1[N_ETYPE];
#pragma unroll
  for (int k = 0; k < N_ETYPE; ++k) {
    we0[k] = We[k * DH + c];
    we1[k] = We[k * DH + c + 1];
  }
  float be0 = be[c], be1 = be[c + 1];
  const float4* a = &sAttr[wv << 8];   // 64 edges x 4 float4
  const int* wp = &spos[wv << 6];
#pragma unroll 2
  for (int j = 0; j < 64; ++j) {
    int pos_j = wp[j];
    float4 a0 = a[j * 4 + 0], a1 = a[j * 4 + 1], a2 = a[j * 4 + 2], a3 = a[j * 4 + 3];
    float p0 = be0, p1 = be1;
    MAC16(a0, a1, a2, a3)
    int q0 = (int)rintf(p0 * EQ_SCALE);
    int q1 = (int)rintf(p1 * EQ_SCALE);
    q0 = q0 > 127 ? 127 : (q0 < -127 ? -127 : q0);
    q1 = q1 > 127 ? 127 : (q1 < -127 ? -127 : q1);
    e8_perm[((size_t)pos_j << 6) + lane] =
        (unsigned short)((q0 & 0xff) | ((q1 & 0xff) << 8));
  }
}

// -------- aggregation: zb[n] = bf16(hb[n] + sum relu(hb[src] + dequant(e8))) --------
__global__ __launch_bounds__(256) void k_agg_lite(const uint32* __restrict__ hb,
                                                  const unsigned short* __restrict__ e8_perm,
                                                  const int* __restrict__ row_start,
                                                  const int* __restrict__ src_perm,
                                                  uint32* __restrict__ zb) {
  int lane = threadIdx.x & 63;
  int n = (blockIdx.x << 2) + (threadIdx.x >> 6);
  uint32 hself = hb[(size_t)n * 64 + lane];
  float acc0 = UPLO(hself);
  float acc1 = UPHI(hself);
  int beg = row_start[n], end = row_start[n + 1];
  const unsigned short* ep = e8_perm + ((size_t)beg << 6) + lane;
  const int* sp = src_perm + beg;
  int m = end - beg;
  int i = 0;
  for (; i + 16 <= m; i += 16, ep += 1024, sp += 16) {
    int ss[16];
    uint32 gg[16];
    unsigned short ee[16];
#pragma unroll
    for (int k = 0; k < 16; ++k) ss[k] = sp[k];
#pragma unroll
    for (int k = 0; k < 16; ++k) gg[k] = hb[((size_t)ss[k] << 6) + lane];
#pragma unroll
    for (int k = 0; k < 16; ++k) ee[k] = ep[k * 64];
#pragma unroll
    for (int k = 0; k < 16; ++k) { ACC2Q(gg[k], ee[k]) }
  }
  for (; i + 4 <= m; i += 4, ep += 256, sp += 4) {
    int ss[4];
    uint32 gg[4];
    unsigned short ee[4];
#pragma unroll
    for (int k = 0; k < 4; ++k) ss[k] = sp[k];
#pragma unroll
    for (int k = 0; k < 4; ++k) gg[k] = hb[((size_t)ss[k] << 6) + lane];
#pragma unroll
    for (int k = 0; k < 4; ++k) ee[k] = ep[k * 64];
#pragma unroll
    for (int k = 0; k < 4; ++k) { ACC2Q(gg[k], ee[k]) }
  }
  for (; i < m; ++i, ep += 64, ++sp) {
    int s0 = sp[0];
    uint32 g0 = hb[((size_t)s0 << 6) + lane];
    unsigned short e0 = ep[0];
    ACC2Q(g0, e0)
  }
  zb[(size_t)n * 64 + lane] = pack_bf2(acc0, acc1);
}

// ---- one-time: transpose W1,W2 -> bf16 [out_col][in_k] for MFMA B operands ----
__global__ __launch_bounds__(256) void k_prep_w(const float* __restrict__ W1,
                                                const float* __restrict__ W2,
                                                ushort16* __restrict__ w1t,
                                                ushort16* __restrict__ w2t) {
  int id = blockIdx.x * 256 + threadIdx.x;   // 0..32767
  int which = id >> 14;
  int rem = id & 16383;
  int k = rem >> 7, n = rem & 127;
  const float* W = which ? W2 : W1;
  ushort16* wt = which ? w2t : w1t;
  wt[n * 128 + k] = (ushort16)f2bf1(W[k * 128 + n]);
}

// ------- MFMA MLP (R14-verified): LDS-staged W, bf16-only coalesced epilogue -------
__global__ __launch_bounds__(256) void k_mlp_mfma(const uint32* __restrict__ zb,
                                                  const ushort16* __restrict__ w1t,
                                                  const ushort16* __restrict__ w2t,
                                                  const float* __restrict__ b1,
                                                  const float* __restrict__ b2,
                                                  const int* __restrict__ graph_ids,
                                                  uint32* __restrict__ hb_out,
                                                  float* __restrict__ pooled,
                                                  int t_slot) {
  __shared__ ushort16 sW[128 * 136];   // 34816 B
  __shared__ ushort16 sA[64 * 136];    // 17408 B
  int tid = threadIdx.x;
  int rb = blockIdx.x * 64;

  for (int idx = tid; idx < 1024; idx += 256) {
    int row = idx >> 4, ch = idx & 15;
    *(uint4*)&sA[row * 136 + ch * 8] = *(const uint4*)&zb[(size_t)(rb + row) * 64 + ch * 4];
  }
  for (int idx = tid; idx < 2048; idx += 256) {
    int row = idx >> 4, ch = idx & 15;
    *(uint4*)&sW[row * 136 + ch * 8] = *(const uint4*)&w1t[row * 128 + ch * 8];
  }
  __syncthreads();

  int l = tid & 63, w = tid >> 6;
  int r = l & 15, g = l >> 4;

  f32x4 acc[8];
#pragma unroll
  for (int n = 0; n < 8; ++n) {
    float bv = b1[n * 16 + r];
    acc[n] = (f32x4){bv, bv, bv, bv};
  }
#pragma unroll
  for (int k0 = 0; k0 < 4; ++k0) {
    bf16x8 a = *(const bf16x8*)&sA[(w * 16 + r) * 136 + k0 * 32 + g * 8];
#pragma unroll
    for (int n = 0; n < 8; ++n) {
      bf16x8 b = *(const bf16x8*)&sW[(n * 16 + r) * 136 + k0 * 32 + g * 8];
      acc[n] = __builtin_amdgcn_mfma_f32_16x16x32_bf16(a, b, acc[n], 0, 0, 0);
    }
  }
#pragma unroll
  for (int n = 0; n < 8; ++n) {
#pragma unroll
    for (int q = 0; q < 4; ++q) {
      float v = fmaxf(acc[n][q], 0.0f);
      sA[(w * 16 + g * 4 + q) * 136 + n * 16 + r] = (ushort16)f2bf1(v);
    }
  }
  __syncthreads();
  for (int idx = tid; idx < 2048; idx += 256) {
    int row = idx >> 4, ch = idx & 15;
    *(uint4*)&sW[row * 136 + ch * 8] = *(const uint4*)&w2t[row * 128 + ch * 8];
  }
  __syncthreads();

#pragma unroll
  for (int n = 0; n < 8; ++n) {
    float bv = b2[n * 16 + r];
    acc[n] = (f32x4){bv, bv, bv, bv};
  }
#pragma unroll
  for (int k0 = 0; k0 < 4; ++k0) {
    bf16x8 a = *(const bf16x8*)&sA[(w * 16 + r) * 136 + k0 * 32 + g * 8];
#pragma unroll
    for (int n = 0; n < 8; ++n) {
      bf16x8 b = *(const bf16x8*)&sW[(n * 16 + r) * 136 + k0 * 32 + g * 8];
      acc[n] = __builtin_amdgcn_mfma_f32_16x16x32_bf16(a, b, acc[n], 0, 0, 0);
    }
  }

  // ---- pooled (fp32, from registers) ----
  float* pbase = pooled + t_slot * DH;
  int node0 = rb + w * 16;
  int gid0 = graph_ids[node0];
  if (gid0 == graph_ids[node0 + 15]) {
#pragma unroll
    for (int n = 0; n < 8; ++n) {
      float s = acc[n][0] + acc[n][1] + acc[n][2] + acc[n][3];
      s += __shfl_xor(s, 16);
      s += __shfl_xor(s, 32);
      if (l < 16) atomicAdd(&pbase[gid0 * 512 + n * 16 + r], s);
    }
  } else {
#pragma unroll
    for (int q = 0; q < 4; ++q) {
      int node = node0 + g * 4 + q;
      int gg = graph_ids[node];
#pragma unroll
      for (int n = 0; n < 8; ++n)
        atomicAdd(&pbase[gg * 512 + n * 16 + r], acc[n][q]);
    }
  }

  // ---- epilogue: pack bf16 into own sA rows, coalesced hb store ----
#pragma unroll
  for (int n = 0; n < 8; ++n)
#pragma unroll
    for (int q = 0; q < 4; ++q)
      sA[(w * 16 + g * 4 + q) * 136 + n * 16 + r] = (ushort16)f2bf1(acc[n][q]);
  __syncthreads();
  for (int idx = tid; idx < 4096; idx += 256) {   // 64 rows x 64 dwords
    int row = idx >> 6, dw = idx & 63;
    uint32 v = *(const uint32*)&sA[row * 136 + dw * 2];
    hb_out[(size_t)(rb + row) * 64 + dw] = v;
  }
}

// -------- aggregation, fallback indirect path --------
__global__ __launch_bounds__(256, 8) void k_agg_ind(const float* __restrict__ h,
                                                    const uint32* __restrict__ hb,
                                                    const float* __restrict__ edge_attr,
                                                    const float* __restrict__ We,
                                                    const float* __restrict__ be,
                                                    const int* __restrict__ row_start,
                                                    const int* __restrict__ src_perm,
                                                    const int* __restrict__ eid_perm,
                                                    float* __restrict__ z) {
  int lane = threadIdx.x & 63;
  int n = (blockIdx.x << 2) + (threadIdx.x >> 6);
  int c = lane << 1;
  float we0[N_ETYPE], we1[N_ETYPE];
#pragma unroll
  for (int k = 0; k < N_ETYPE; ++k) {
    we0[k] = We[k * DH + c];
    we1[k] = We[k * DH + c + 1];
  }
  float be0 = be[c], be1 = be[c + 1];
  float2 hself = *(const float2*)&h[(size_t)n * DH + c];
  float acc0 = hself.x, acc1 = hself.y;
  int beg = row_start[n], end = row_start[n + 1];
  int i = beg;
  for (; i + 1 < end; i += 2) {
    int s0 = src_perm[i], s1 = src_perm[i + 1];
    int e0i = eid_perm[i], e1i = eid_perm[i + 1];
    uint32 g0 = hb[((size_t)s0 << 6) + lane];
    uint32 g1 = hb[((size_t)s1 << 6) + lane];
    const float4* eA = (const float4*)(edge_attr + (size_t)e0i * N_ETYPE);
    const float4* eB = (const float4*)(edge_attr + (size_t)e1i * N_ETYPE);
    float4 a0 = eA[0], a1 = eA[1], a2 = eA[2], a3 = eA[3];
    float p0, p1;
    p0 = be0; p1 = be1; MAC16(a0, a1, a2, a3) RELU_ACC(g0)
    float4 b0 = eB[0], b1v = eB[1], b2v = eB[2], b3 = eB[3];
    p0 = be0; p1 = be1; MAC16(b0, b1v, b2v, b3) RELU_ACC(g1)
  }
  if (i < end) {
    int s0 = src_perm[i];
    int e0i = eid_perm[i];
    uint32 g0 = hb[((size_t)s0 << 6) + lane];
    const float4* eA = (const float4*)(edge_attr + (size_t)e0i * N_ETYPE);
    float4 a0 = eA[0], a1 = eA[1], a2 = eA[2], a3 = eA[3];
    float p0 = be0, p1 = be1;
    MAC16(a0, a1, a2, a3) RELU_ACC(g0)
  }
  *(float2*)&z[(size_t)n * DH + c] = make_float2(acc0, acc1);
}

// ---------------- fallback fp32 MLP ----------------
#define MLPFMA(K, U0, U1)                                            \
  {                                                                  \
    _Pragma("unroll")                                                \
    for (int i_ = 0; i_ < 8; ++i_) {                                 \
      float2 a_ = *(const float2*)&sA[(r0 + i_) * 132 + (K)];        \
      acc[i_][0] = fmaf(a_.x, U0.x, acc[i_][0]);                     \
      acc[i_][1] = fmaf(a_.x, U0.y, acc[i_][1]);                     \
      acc[i_][2] = fmaf(a_.x, U0.z, acc[i_][2]);                     \
      acc[i_][3] = fmaf(a_.x, U0.w, acc[i_][3]);                     \
      acc[i_][0] = fmaf(a_.y, U1.x, acc[i_][0]);                     \
      acc[i_][1] = fmaf(a_.y, U1.y, acc[i_][1]);                     \
      acc[i_][2] = fmaf(a_.y, U1.z, acc[i_][2]);                     \
      acc[i_][3] = fmaf(a_.y, U1.w, acc[i_][3]);                     \
    }                                                                \
  }

__device__ __forceinline__ void gemm_tile_g(const float* sA, const float4* __restrict__ Wv,
                                            float acc[8][4], int r0, int cg) {
  float4 c0 = Wv[cg],       c1 = Wv[32 + cg];
  float4 n0 = Wv[64 + cg],  n1 = Wv[96 + cg];
#pragma unroll 4
  for (int k = 0; k < DH - 4; k += 2) {
    float4 u0 = c0, u1 = c1;
    c0 = n0; c1 = n1;
    n0 = Wv[(k + 4) * 32 + cg];
    n1 = Wv[(k + 5) * 32 + cg];
    MLPFMA(k, u0, u1)
  }
  MLPFMA(DH - 4, c0, c1)
  MLPFMA(DH - 2, n0, n1)
}

__global__ __launch_bounds__(256) void k_mlp(const float* __restrict__ z,
                                             const float* __restrict__ W1,
                                             const float* __restrict__ b1,
                                             const float* __restrict__ W2,
                                             const float* __restrict__ b2,
                                             const int* __restrict__ graph_ids,
                                             float* __restrict__ h_out,
                                             uint32* __restrict__ hb_out,
                                             float* __restrict__ pooled,
                                             int t_slot) {
  __shared__ float sA[64 * 132];
  int tid = threadIdx.x;
  int rb = blockIdx.x * 64;
  for (int idx = tid; idx < 64 * 32; idx += 256) {
    int r = idx >> 5, kq = (idx & 31) << 2;
    *(float4*)&sA[r * 132 + kq] = *(const float4*)&z[(size_t)(rb + r) * DH + kq];
  }
  __syncthreads();

  int cg = tid & 31, rg = tid >> 5;
  int c0 = cg << 2, r0 = rg << 3;
  float acc[8][4];
  {
    float4 bb = *(const float4*)&b1[c0];
#pragma unroll
    for (int i = 0; i < 8; ++i) { acc[i][0] = bb.x; acc[i][1] = bb.y; acc[i][2] = bb.z; acc[i][3] = bb.w; }
  }
  gemm_tile_g(sA, (const float4*)W1, acc, r0, cg);
  __syncthreads();
#pragma unroll
  for (int i = 0; i < 8; ++i) {
    float4 v;
    v.x = fmaxf(acc[i][0], 0.0f); v.y = fmaxf(acc[i][1], 0.0f);
    v.z = fmaxf(acc[i][2], 0.0f); v.w = fmaxf(acc[i][3], 0.0f);
    *(float4*)&sA[(r0 + i) * 132 + c0] = v;
  }
  __syncthreads();
  {
    float4 bb = *(const float4*)&b2[c0];
#pragma unroll
    for (int i = 0; i < 8; ++i) { acc[i][0] = bb.x; acc[i][1] = bb.y; acc[i][2] = bb.z; acc[i][3] = bb.w; }
  }
  gemm_tile_g(sA, (const float4*)W2, acc, r0, cg);

  int node0 = rb + r0;
#pragma unroll
  for (int i = 0; i < 8; ++i) {
    float4 v = make_float4(acc[i][0], acc[i][1], acc[i][2], acc[i][3]);
    *(float4*)&h_out[(size_t)(node0 + i) * DH + c0] = v;
    uint2 hv;
    hv.x = pack_bf2(acc[i][0], acc[i][1]);
    hv.y = pack_bf2(acc[i][2], acc[i][3]);
    *(uint2*)&hb_out[(size_t)(node0 + i) * 64 + (c0 >> 1)] = hv;
  }
  float* pbase = pooled + t_slot * DH;
  int g_first = graph_ids[node0];
  int g_last = graph_ids[node0 + 7];
  if (g_first == g_last) {
    float s0 = 0.f, s1 = 0.f, s2 = 0.f, s3 = 0.f;
#pragma unroll
    for (int i = 0; i < 8; ++i) { s0 += acc[i][0]; s1 += acc[i][1]; s2 += acc[i][2]; s3 += acc[i][3]; }
    atomicAdd(&pbase[g_first * 512 + c0 + 0], s0);
    atomicAdd(&pbase[g_first * 512 + c0 + 1], s1);
    atomicAdd(&pbase[g_first * 512 + c0 + 2], s2);
    atomicAdd(&pbase[g_first * 512 + c0 + 3], s3);
  } else {
#pragma unroll
    for (int i = 0; i < 8; ++i) {
      int g = graph_ids[node0 + i];
      atomicAdd(&pbase[g * 512 + c0 + 0], acc[i][0]);
      atomicAdd(&pbase[g * 512 + c0 + 1], acc[i][1]);
      atomicAdd(&pbase[g * 512 + c0 + 2], acc[i][2]);
      atomicAdd(&pbase[g * 512 + c0 + 3], acc[i][3]);
    }
  }
}

// ---------------- final: out = pooled @ Wl + bl ----------------
__global__ __launch_bounds__(256) void k_final(const float* __restrict__ pooled,
                                               const float* __restrict__ Wl,
                                               const float* __restrict__ bl,
                                               float* __restrict__ out) {
  int g = blockIdx.x, o = threadIdx.x;
  __shared__ float sp[DH * T_ITERS];
  for (int idx = o; idx < DH * T_ITERS; idx += 256) sp[idx] = pooled[g * (DH * T_ITERS) + idx];
  __syncthreads();
  float acc = bl[o];
#pragma unroll 8
  for (int j = 0; j < DH * T_ITERS; ++j)
    acc = fmaf(sp[j], Wl[j * DOUT + o], acc);
  out[g * DOUT + o] = acc;
}

extern "C" void kernel_launch(void* const* d_in, const int* in_sizes, int n_in,
                              void* d_out, int out_size, void* d_ws, size_t ws_size,
                              hipStream_t stream) {
  const float* x         = (const float*)d_in[0];
  const int*   edge_index= (const int*)d_in[1];
  const float* edge_attr = (const float*)d_in[2];
  const int*   graph_ids = (const int*)d_in[3];
  const float* Wn = (const float*)d_in[4];
  const float* bn = (const float*)d_in[5];
  const float* We = (const float*)d_in[6];
  const float* be = (const float*)d_in[7];
  const float* W1 = (const float*)d_in[8];
  const float* b1 = (const float*)d_in[9];
  const float* W2 = (const float*)d_in[10];
  const float* b2 = (const float*)d_in[11];
  const float* Wl = (const float*)d_in[12];
  const float* bl = (const float*)d_in[13];
  float* out = (float*)d_out;

  char* p = (char*)d_ws;
  auto alloc = [&](size_t bytes) { char* r = p; p += (bytes + 255) & ~(size_t)255; return r; };
  float*  h        = (float*)alloc((size_t)N_NODES * DH * 4);   // fallback path only
  float*  z        = (float*)alloc((size_t)N_NODES * DH * 4);   // primary path reuses as zb
  uint32* hb       = (uint32*)alloc((size_t)N_NODES * DH * 2);
  float*  pooled   = (float*)alloc((size_t)N_GRAPHS * DH * T_ITERS * 4);
  int*    counts   = (int*)alloc((size_t)N_NODES * 4);          // reused as w1t/w2t after scan
  int*    row_start= (int*)alloc((size_t)(N_NODES + 1) * 4);
  int*    cursor   = (int*)alloc((size_t)N_NODES * 4);
  int*    src_perm = (int*)alloc((size_t)N_EDGES * 4);
  int*    blk_sums = (int*)alloc(256);
  int*    blk_off  = (int*)alloc(256);

  const int* src = edge_index;
  const int* dst = edge_index + N_EDGES;

  size_t used = (size_t)(p - (char*)d_ws);
  size_t need_e = used + (size_t)N_EDGES * DH + 4096;   // e8_perm 82 MB

  hipMemsetAsync(counts, 0, (size_t)N_NODES * 4, stream);
  hipMemsetAsync(pooled, 0, (size_t)N_GRAPHS * DH * T_ITERS * 4, stream);

  bool primary = (ws_size >= need_e);
  if (primary) {
    k_embed_nh<<<N_NODES * DH / 256, 256, 0, stream>>>(x, Wn, bn, (ushort16*)hb);
  } else {
    k_embed<<<N_NODES * DH / 256, 256, 0, stream>>>(x, Wn, bn, h, (ushort16*)hb);
  }
  k_hist<<<N_EDGES / 256, 256, 0, stream>>>(dst, counts);
  k_scan1<<<SCAN_BLK, 1024, 0, stream>>>(counts, row_start, blk_sums);
  k_scan2<<<1, 64, 0, stream>>>(blk_sums, blk_off, row_start);
  k_scan3<<<SCAN_BLK, 1024, 0, stream>>>(row_start, blk_off, cursor);

  if (primary) {
    unsigned short* e8_perm = (unsigned short*)alloc((size_t)N_EDGES * DH);
    uint32* zb = (uint32*)z;                              // overlay (z fp32 unused here)
    ushort16* w1t = (ushort16*)counts;                    // counts dead after scan
    ushort16* w2t = w1t + 128 * 128;
    k_prep_w<<<128, 256, 0, stream>>>(W1, W2, w1t, w2t);
    k_perm_e<<<N_EDGES / 128, 128, 0, stream>>>(src, dst, (const float4*)edge_attr,
                                                We, be, cursor, src_perm, e8_perm);
    for (int t = 0; t < T_ITERS; ++t) {
      k_agg_lite<<<N_NODES / 4, 256, 0, stream>>>(hb, e8_perm, row_start, src_perm, zb);
      k_mlp_mfma<<<N_NODES / 64, 256, 0, stream>>>(zb, w1t, w2t, b1, b2, graph_ids,
                                                   hb, pooled, t);
    }
  } else {
    int* eid_perm = (int*)alloc((size_t)N_EDGES * 4);
    k_permute<<<N_EDGES / 256, 256, 0, stream>>>(src, dst, cursor, src_perm, eid_perm);
    for (int t = 0; t < T_ITERS; ++t) {
      k_agg_ind<<<N_NODES / 4, 256, 0, stream>>>(h, hb, edge_attr, We, be, row_start, src_perm, eid_perm, z);
      k_mlp<<<N_NODES / 64, 256, 0, stream>>>(z, W1, b1, W2, b2, graph_ids, h, (uint32*)hb, pooled, t);
    }
  }
  k_final<<<N_GRAPHS, 256, 0, stream>>>(pooled, Wl, bl, out);
}

// Round 17
// 388.439 us; speedup vs baseline: 1.9146x; 1.0119x over previous
//
#include <hip/hip_runtime.h>

#define N_NODES   40000
#define N_EDGES   640000
#define N_GRAPHS  64
#define DIM_IN    32
#define N_ETYPE   16
#define DH        128
#define DOUT      256
#define T_ITERS   4
#define SCAN_BLK  40          // ceil(40000/1024)

typedef unsigned int uint32;
typedef unsigned short ushort16;
typedef __attribute__((ext_vector_type(8))) short bf16x8;
typedef __attribute__((ext_vector_type(4))) float f32x4;

__device__ __forceinline__ uint32 f2bf1(float f) {
  uint32 u = __float_as_uint(f);
  return (u + 0x7fffu + ((u >> 16) & 1u)) >> 16;
}
__device__ __forceinline__ uint32 pack_bf2(float lo, float hi) {
  return (f2bf1(hi) << 16) | f2bf1(lo);
}
#define UPLO(u) __uint_as_float((u) << 16)
#define UPHI(u) __uint_as_float((u) & 0xffff0000u)

// int8 e quantization: scale 64 (dequant 1/64), clamp +-127
#define EQ_SCALE   64.0f
#define EQ_INV     0.015625f
#define E2F0(E) ((float)((signed char)((E) & 0xff)) * EQ_INV)
#define E2F1(E) ((float)((signed char)((E) >> 8)) * EQ_INV)

// ---------------- node embedding, primary: hb only ----------------
__global__ __launch_bounds__(256) void k_embed_nh(const float* __restrict__ x,
                                                  const float* __restrict__ Wn,
                                                  const float* __restrict__ bn,
                                                  ushort16* __restrict__ hb) {
  int idx = blockIdx.x * 256 + threadIdx.x;     // n*128 + c, exact grid
  int n = idx >> 7, c = idx & 127;
  const float* xr = x + n * DIM_IN;
  float acc = bn[c];
#pragma unroll
  for (int k = 0; k < DIM_IN; ++k)
    acc = fmaf(xr[k], Wn[k * DH + c], acc);
  hb[idx] = (ushort16)f2bf1(acc);
}

// ---------------- node embedding, fallback: fp32 + bf16 mirror ----------------
__global__ __launch_bounds__(256) void k_embed(const float* __restrict__ x,
                                               const float* __restrict__ Wn,
                                               const float* __restrict__ bn,
                                               float* __restrict__ h,
                                               ushort16* __restrict__ hb) {
  int idx = blockIdx.x * 256 + threadIdx.x;
  int n = idx >> 7, c = idx & 127;
  const float* xr = x + n * DIM_IN;
  float acc = bn[c];
#pragma unroll
  for (int k = 0; k < DIM_IN; ++k)
    acc = fmaf(xr[k], Wn[k * DH + c], acc);
  h[idx] = acc;
  hb[idx] = (ushort16)f2bf1(acc);
}

// ---------------- CSR build ----------------
__global__ __launch_bounds__(256) void k_hist(const int* __restrict__ dst,
                                              int* __restrict__ counts) {
  int i = blockIdx.x * 256 + threadIdx.x;
  atomicAdd(&counts[dst[i]], 1);
}

// ---- 2-pass parallel scan (scan2 folded into scan23) ----
__global__ __launch_bounds__(1024) void k_scan1(const int* __restrict__ counts,
                                                int* __restrict__ excl,      // = row_start
                                                int* __restrict__ blk_sums) {
  __shared__ int wsums[16];
  int tid = threadIdx.x, lane = tid & 63, w = tid >> 6;
  int i = blockIdx.x * 1024 + tid;
  int v = (i < N_NODES) ? counts[i] : 0;
  int s = v;
#pragma unroll
  for (int off = 1; off < 64; off <<= 1) {
    int t = __shfl_up(s, off);
    if (lane >= off) s += t;
  }
  if (lane == 63) wsums[w] = s;
  __syncthreads();
  if (tid < 16) {
    int ws_ = wsums[tid];
#pragma unroll
    for (int off = 1; off < 16; off <<= 1) {
      int t = __shfl_up(ws_, off);
      if (tid >= off) ws_ += t;
    }
    wsums[tid] = ws_;
  }
  __syncthreads();
  int e = s - v + (w ? wsums[w - 1] : 0);
  if (i < N_NODES) excl[i] = e;
  if (tid == 0) blk_sums[blockIdx.x] = wsums[15];
}

// each block redundantly scans the 40 block sums in its first wave, then applies
__global__ __launch_bounds__(1024) void k_scan23(int* __restrict__ row_start,
                                                 const int* __restrict__ blk_sums,
                                                 int* __restrict__ cursor) {
  __shared__ int s_off;
  __shared__ int s_tot;
  int tid = threadIdx.x;
  if (tid < 64) {
    int v = (tid < SCAN_BLK) ? blk_sums[tid] : 0;
    int s = v;
#pragma unroll
    for (int off = 1; off < 64; off <<= 1) {
      int t = __shfl_up(s, off);
      if (tid >= off) s += t;
    }
    if (tid == (int)blockIdx.x) s_off = s - v;   // exclusive prefix for this block
    if (tid == 63) s_tot = s;
  }
  __syncthreads();
  int i = blockIdx.x * 1024 + tid;
  if (i < N_NODES) {
    int v = row_start[i] + s_off;
    row_start[i] = v;
    cursor[i] = v;
  }
  if (blockIdx.x == 0 && tid == 0) row_start[N_NODES] = s_tot;
}

__global__ __launch_bounds__(256) void k_permute(const int* __restrict__ src,
                                                 const int* __restrict__ dst,
                                                 int* __restrict__ cursor,
                                                 int* __restrict__ src_perm,
                                                 int* __restrict__ eid_perm) {
  int i = blockIdx.x * 256 + threadIdx.x;
  int d = dst[i];
  int pos = atomicAdd(&cursor[d], 1);
  src_perm[pos] = src[i];
  eid_perm[pos] = i;
}

#define MAC16(A0,A1,A2,A3)                                          \
  p0 = fmaf(A0.x, we0[0], p0);  p1 = fmaf(A0.x, we1[0], p1);        \
  p0 = fmaf(A0.y, we0[1], p0);  p1 = fmaf(A0.y, we1[1], p1);        \
  p0 = fmaf(A0.z, we0[2], p0);  p1 = fmaf(A0.z, we1[2], p1);        \
  p0 = fmaf(A0.w, we0[3], p0);  p1 = fmaf(A0.w, we1[3], p1);        \
  p0 = fmaf(A1.x, we0[4], p0);  p1 = fmaf(A1.x, we1[4], p1);        \
  p0 = fmaf(A1.y, we0[5], p0);  p1 = fmaf(A1.y, we1[5], p1);        \
  p0 = fmaf(A1.z, we0[6], p0);  p1 = fmaf(A1.z, we1[6], p1);        \
  p0 = fmaf(A1.w, we0[7], p0);  p1 = fmaf(A1.w, we1[7], p1);        \
  p0 = fmaf(A2.x, we0[8], p0);  p1 = fmaf(A2.x, we1[8], p1);        \
  p0 = fmaf(A2.y, we0[9], p0);  p1 = fmaf(A2.y, we1[9], p1);        \
  p0 = fmaf(A2.z, we0[10], p0); p1 = fmaf(A2.z, we1[10], p1);       \
  p0 = fmaf(A2.w, we0[11], p0); p1 = fmaf(A2.w, we1[11], p1);       \
  p0 = fmaf(A3.x, we0[12], p0); p1 = fmaf(A3.x, we1[12], p1);       \
  p0 = fmaf(A3.y, we0[13], p0); p1 = fmaf(A3.y, we1[13], p1);       \
  p0 = fmaf(A3.z, we0[14], p0); p1 = fmaf(A3.z, we1[14], p1);       \
  p0 = fmaf(A3.w, we0[15], p0); p1 = fmaf(A3.w, we1[15], p1);

#define RELU_ACC(G)                                                  \
  acc0 += fmaxf(UPLO(G) + p0, 0.0f);                                 \
  acc1 += fmaxf(UPHI(G) + p1, 0.0f);

#define ACC2Q(G,E)                                                   \
  acc0 += fmaxf(UPLO(G) + E2F0(E), 0.0f);                            \
  acc1 += fmaxf(UPHI(G) + E2F1(E), 0.0f);

// ---- one-time merged pass: CSR permute + e8_perm[pos] = int8(edge_attr[i]@We + be) ----
__global__ __launch_bounds__(128) void k_perm_e(const int* __restrict__ src,
                                                const int* __restrict__ dst,
                                                const float4* __restrict__ edge_attr,
                                                const float* __restrict__ We,
                                                const float* __restrict__ be,
                                                int* __restrict__ cursor,
                                                int* __restrict__ src_perm,
                                                unsigned short* __restrict__ e8_perm) {
  __shared__ float4 sAttr[512];      // 128 edges x 16 floats = 8 KB
  __shared__ int spos[128];
  int tid = threadIdx.x;
  int i = blockIdx.x * 128 + tid;
  int d = dst[i];
  int pos = atomicAdd(&cursor[d], 1);
  src_perm[pos] = src[i];
  spos[tid] = pos;
  size_t blockBase = (size_t)blockIdx.x * 512;   // float4 units
  for (int idx = tid; idx < 512; idx += 128)
    sAttr[idx] = edge_attr[blockBase + idx];
  __syncthreads();
  int lane = tid & 63, wv = tid >> 6;            // wv in {0,1}
  int c = lane << 1;
  float we0[N_ETYPE], we1[N_ETYPE];
#pragma unroll
  for (int k = 0; k < N_ETYPE; ++k) {
    we0[k] = We[k * DH + c];
    we1[k] = We[k * DH + c + 1];
  }
  float be0 = be[c], be1 = be[c + 1];
  const float4* a = &sAttr[wv << 8];   // 64 edges x 4 float4
  const int* wp = &spos[wv << 6];
#pragma unroll 2
  for (int j = 0; j < 64; ++j) {
    int pos_j = wp[j];
    float4 a0 = a[j * 4 + 0], a1 = a[j * 4 + 1], a2 = a[j * 4 + 2], a3 = a[j * 4 + 3];
    float p0 = be0, p1 = be1;
    MAC16(a0, a1, a2, a3)
    int q0 = (int)rintf(p0 * EQ_SCALE);
    int q1 = (int)rintf(p1 * EQ_SCALE);
    q0 = q0 > 127 ? 127 : (q0 < -127 ? -127 : q0);
    q1 = q1 > 127 ? 127 : (q1 < -127 ? -127 : q1);
    e8_perm[((size_t)pos_j << 6) + lane] =
        (unsigned short)((q0 & 0xff) | ((q1 & 0xff) << 8));
  }
}

// -------- aggregation: zb[n] = bf16(hb[n] + sum relu(hb[src] + dequant(e8))) --------
__global__ __launch_bounds__(256) void k_agg_lite(const uint32* __restrict__ hb,
                                                  const unsigned short* __restrict__ e8_perm,
                                                  const int* __restrict__ row_start,
                                                  const int* __restrict__ src_perm,
                                                  uint32* __restrict__ zb) {
  int lane = threadIdx.x & 63;
  int n = (blockIdx.x << 2) + (threadIdx.x >> 6);
  uint32 hself = hb[(size_t)n * 64 + lane];
  float acc0 = UPLO(hself);
  float acc1 = UPHI(hself);
  int beg = row_start[n], end = row_start[n + 1];
  const unsigned short* ep = e8_perm + ((size_t)beg << 6) + lane;
  const int* sp = src_perm + beg;
  int m = end - beg;
  int i = 0;
  for (; i + 16 <= m; i += 16, ep += 1024, sp += 16) {
    int ss[16];
    uint32 gg[16];
    unsigned short ee[16];
#pragma unroll
    for (int k = 0; k < 16; ++k) ss[k] = sp[k];
#pragma unroll
    for (int k = 0; k < 16; ++k) gg[k] = hb[((size_t)ss[k] << 6) + lane];
#pragma unroll
    for (int k = 0; k < 16; ++k) ee[k] = ep[k * 64];
#pragma unroll
    for (int k = 0; k < 16; ++k) { ACC2Q(gg[k], ee[k]) }
  }
  for (; i + 4 <= m; i += 4, ep += 256, sp += 4) {
    int ss[4];
    uint32 gg[4];
    unsigned short ee[4];
#pragma unroll
    for (int k = 0; k < 4; ++k) ss[k] = sp[k];
#pragma unroll
    for (int k = 0; k < 4; ++k) gg[k] = hb[((size_t)ss[k] << 6) + lane];
#pragma unroll
    for (int k = 0; k < 4; ++k) ee[k] = ep[k * 64];
#pragma unroll
    for (int k = 0; k < 4; ++k) { ACC2Q(gg[k], ee[k]) }
  }
  for (; i < m; ++i, ep += 64, ++sp) {
    int s0 = sp[0];
    uint32 g0 = hb[((size_t)s0 << 6) + lane];
    unsigned short e0 = ep[0];
    ACC2Q(g0, e0)
  }
  zb[(size_t)n * 64 + lane] = pack_bf2(acc0, acc1);
}

// ---- one-time: transpose W1,W2 -> bf16 [out_col][in_k] for MFMA B operands ----
__global__ __launch_bounds__(256) void k_prep_w(const float* __restrict__ W1,
                                                const float* __restrict__ W2,
                                                ushort16* __restrict__ w1t,
                                                ushort16* __restrict__ w2t) {
  int id = blockIdx.x * 256 + threadIdx.x;   // 0..32767
  int which = id >> 14;
  int rem = id & 16383;
  int k = rem >> 7, n = rem & 127;
  const float* W = which ? W2 : W1;
  ushort16* wt = which ? w2t : w1t;
  wt[n * 128 + k] = (ushort16)f2bf1(W[k * 128 + n]);
}

// ------- MFMA MLP: LDS-staged W, bf16-only coalesced epilogue; hb store skippable -------
__global__ __launch_bounds__(256) void k_mlp_mfma(const uint32* __restrict__ zb,
                                                  const ushort16* __restrict__ w1t,
                                                  const ushort16* __restrict__ w2t,
                                                  const float* __restrict__ b1,
                                                  const float* __restrict__ b2,
                                                  const int* __restrict__ graph_ids,
                                                  uint32* __restrict__ hb_out,
                                                  float* __restrict__ pooled,
                                                  int t_slot, int write_hb) {
  __shared__ ushort16 sW[128 * 136];   // 34816 B
  __shared__ ushort16 sA[64 * 136];    // 17408 B
  int tid = threadIdx.x;
  int rb = blockIdx.x * 64;

  for (int idx = tid; idx < 1024; idx += 256) {
    int row = idx >> 4, ch = idx & 15;
    *(uint4*)&sA[row * 136 + ch * 8] = *(const uint4*)&zb[(size_t)(rb + row) * 64 + ch * 4];
  }
  for (int idx = tid; idx < 2048; idx += 256) {
    int row = idx >> 4, ch = idx & 15;
    *(uint4*)&sW[row * 136 + ch * 8] = *(const uint4*)&w1t[row * 128 + ch * 8];
  }
  __syncthreads();

  int l = tid & 63, w = tid >> 6;
  int r = l & 15, g = l >> 4;

  f32x4 acc[8];
#pragma unroll
  for (int n = 0; n < 8; ++n) {
    float bv = b1[n * 16 + r];
    acc[n] = (f32x4){bv, bv, bv, bv};
  }
#pragma unroll
  for (int k0 = 0; k0 < 4; ++k0) {
    bf16x8 a = *(const bf16x8*)&sA[(w * 16 + r) * 136 + k0 * 32 + g * 8];
#pragma unroll
    for (int n = 0; n < 8; ++n) {
      bf16x8 b = *(const bf16x8*)&sW[(n * 16 + r) * 136 + k0 * 32 + g * 8];
      acc[n] = __builtin_amdgcn_mfma_f32_16x16x32_bf16(a, b, acc[n], 0, 0, 0);
    }
  }
#pragma unroll
  for (int n = 0; n < 8; ++n) {
#pragma unroll
    for (int q = 0; q < 4; ++q) {
      float v = fmaxf(acc[n][q], 0.0f);
      sA[(w * 16 + g * 4 + q) * 136 + n * 16 + r] = (ushort16)f2bf1(v);
    }
  }
  __syncthreads();
  for (int idx = tid; idx < 2048; idx += 256) {
    int row = idx >> 4, ch = idx & 15;
    *(uint4*)&sW[row * 136 + ch * 8] = *(const uint4*)&w2t[row * 128 + ch * 8];
  }
  __syncthreads();

#pragma unroll
  for (int n = 0; n < 8; ++n) {
    float bv = b2[n * 16 + r];
    acc[n] = (f32x4){bv, bv, bv, bv};
  }
#pragma unroll
  for (int k0 = 0; k0 < 4; ++k0) {
    bf16x8 a = *(const bf16x8*)&sA[(w * 16 + r) * 136 + k0 * 32 + g * 8];
#pragma unroll
    for (int n = 0; n < 8; ++n) {
      bf16x8 b = *(const bf16x8*)&sW[(n * 16 + r) * 136 + k0 * 32 + g * 8];
      acc[n] = __builtin_amdgcn_mfma_f32_16x16x32_bf16(a, b, acc[n], 0, 0, 0);
    }
  }

  // ---- pooled (fp32, from registers) ----
  float* pbase = pooled + t_slot * DH;
  int node0 = rb + w * 16;
  int gid0 = graph_ids[node0];
  if (gid0 == graph_ids[node0 + 15]) {
#pragma unroll
    for (int n = 0; n < 8; ++n) {
      float s = acc[n][0] + acc[n][1] + acc[n][2] + acc[n][3];
      s += __shfl_xor(s, 16);
      s += __shfl_xor(s, 32);
      if (l < 16) atomicAdd(&pbase[gid0 * 512 + n * 16 + r], s);
    }
  } else {
#pragma unroll
    for (int q = 0; q < 4; ++q) {
      int node = node0 + g * 4 + q;
      int gg = graph_ids[node];
#pragma unroll
      for (int n = 0; n < 8; ++n)
        atomicAdd(&pbase[gg * 512 + n * 16 + r], acc[n][q]);
    }
  }

  // ---- epilogue (skipped on last iteration: hb dead after final MLP) ----
  if (write_hb) {
#pragma unroll
    for (int n = 0; n < 8; ++n)
#pragma unroll
      for (int q = 0; q < 4; ++q)
        sA[(w * 16 + g * 4 + q) * 136 + n * 16 + r] = (ushort16)f2bf1(acc[n][q]);
    __syncthreads();
    for (int idx = tid; idx < 4096; idx += 256) {   // 64 rows x 64 dwords
      int row = idx >> 6, dw = idx & 63;
      uint32 v = *(const uint32*)&sA[row * 136 + dw * 2];
      hb_out[(size_t)(rb + row) * 64 + dw] = v;
    }
  }
}

// -------- aggregation, fallback indirect path --------
__global__ __launch_bounds__(256, 8) void k_agg_ind(const float* __restrict__ h,
                                                    const uint32* __restrict__ hb,
                                                    const float* __restrict__ edge_attr,
                                                    const float* __restrict__ We,
                                                    const float* __restrict__ be,
                                                    const int* __restrict__ row_start,
                                                    const int* __restrict__ src_perm,
                                                    const int* __restrict__ eid_perm,
                                                    float* __restrict__ z) {
  int lane = threadIdx.x & 63;
  int n = (blockIdx.x << 2) + (threadIdx.x >> 6);
  int c = lane << 1;
  float we0[N_ETYPE], we1[N_ETYPE];
#pragma unroll
  for (int k = 0; k < N_ETYPE; ++k) {
    we0[k] = We[k * DH + c];
    we1[k] = We[k * DH + c + 1];
  }
  float be0 = be[c], be1 = be[c + 1];
  float2 hself = *(const float2*)&h[(size_t)n * DH + c];
  float acc0 = hself.x, acc1 = hself.y;
  int beg = row_start[n], end = row_start[n + 1];
  int i = beg;
  for (; i + 1 < end; i += 2) {
    int s0 = src_perm[i], s1 = src_perm[i + 1];
    int e0i = eid_perm[i], e1i = eid_perm[i + 1];
    uint32 g0 = hb[((size_t)s0 << 6) + lane];
    uint32 g1 = hb[((size_t)s1 << 6) + lane];
    const float4* eA = (const float4*)(edge_attr + (size_t)e0i * N_ETYPE);
    const float4* eB = (const float4*)(edge_attr + (size_t)e1i * N_ETYPE);
    float4 a0 = eA[0], a1 = eA[1], a2 = eA[2], a3 = eA[3];
    float p0, p1;
    p0 = be0; p1 = be1; MAC16(a0, a1, a2, a3) RELU_ACC(g0)
    float4 b0 = eB[0], b1v = eB[1], b2v = eB[2], b3 = eB[3];
    p0 = be0; p1 = be1; MAC16(b0, b1v, b2v, b3) RELU_ACC(g1)
  }
  if (i < end) {
    int s0 = src_perm[i];
    int e0i = eid_perm[i];
    uint32 g0 = hb[((size_t)s0 << 6) + lane];
    const float4* eA = (const float4*)(edge_attr + (size_t)e0i * N_ETYPE);
    float4 a0 = eA[0], a1 = eA[1], a2 = eA[2], a3 = eA[3];
    float p0 = be0, p1 = be1;
    MAC16(a0, a1, a2, a3) RELU_ACC(g0)
  }
  *(float2*)&z[(size_t)n * DH + c] = make_float2(acc0, acc1);
}

// ---------------- fallback fp32 MLP ----------------
#define MLPFMA(K, U0, U1)                                            \
  {                                                                  \
    _Pragma("unroll")                                                \
    for (int i_ = 0; i_ < 8; ++i_) {                                 \
      float2 a_ = *(const float2*)&sA[(r0 + i_) * 132 + (K)];        \
      acc[i_][0] = fmaf(a_.x, U0.x, acc[i_][0]);                     \
      acc[i_][1] = fmaf(a_.x, U0.y, acc[i_][1]);                     \
      acc[i_][2] = fmaf(a_.x, U0.z, acc[i_][2]);                     \
      acc[i_][3] = fmaf(a_.x, U0.w, acc[i_][3]);                     \
      acc[i_][0] = fmaf(a_.y, U1.x, acc[i_][0]);                     \
      acc[i_][1] = fmaf(a_.y, U1.y, acc[i_][1]);                     \
      acc[i_][2] = fmaf(a_.y, U1.z, acc[i_][2]);                     \
      acc[i_][3] = fmaf(a_.y, U1.w, acc[i_][3]);                     \
    }                                                                \
  }

__device__ __forceinline__ void gemm_tile_g(const float* sA, const float4* __restrict__ Wv,
                                            float acc[8][4], int r0, int cg) {
  float4 c0 = Wv[cg],       c1 = Wv[32 + cg];
  float4 n0 = Wv[64 + cg],  n1 = Wv[96 + cg];
#pragma unroll 4
  for (int k = 0; k < DH - 4; k += 2) {
    float4 u0 = c0, u1 = c1;
    c0 = n0; c1 = n1;
    n0 = Wv[(k + 4) * 32 + cg];
    n1 = Wv[(k + 5) * 32 + cg];
    MLPFMA(k, u0, u1)
  }
  MLPFMA(DH - 4, c0, c1)
  MLPFMA(DH - 2, n0, n1)
}

__global__ __launch_bounds__(256) void k_mlp(const float* __restrict__ z,
                                             const float* __restrict__ W1,
                                             const float* __restrict__ b1,
                                             const float* __restrict__ W2,
                                             const float* __restrict__ b2,
                                             const int* __restrict__ graph_ids,
                                             float* __restrict__ h_out,
                                             uint32* __restrict__ hb_out,
                                             float* __restrict__ pooled,
                                             int t_slot) {
  __shared__ float sA[64 * 132];
  int tid = threadIdx.x;
  int rb = blockIdx.x * 64;
  for (int idx = tid; idx < 64 * 32; idx += 256) {
    int r = idx >> 5, kq = (idx & 31) << 2;
    *(float4*)&sA[r * 132 + kq] = *(const float4*)&z[(size_t)(rb + r) * DH + kq];
  }
  __syncthreads();

  int cg = tid & 31, rg = tid >> 5;
  int c0 = cg << 2, r0 = rg << 3;
  float acc[8][4];
  {
    float4 bb = *(const float4*)&b1[c0];
#pragma unroll
    for (int i = 0; i < 8; ++i) { acc[i][0] = bb.x; acc[i][1] = bb.y; acc[i][2] = bb.z; acc[i][3] = bb.w; }
  }
  gemm_tile_g(sA, (const float4*)W1, acc, r0, cg);
  __syncthreads();
#pragma unroll
  for (int i = 0; i < 8; ++i) {
    float4 v;
    v.x = fmaxf(acc[i][0], 0.0f); v.y = fmaxf(acc[i][1], 0.0f);
    v.z = fmaxf(acc[i][2], 0.0f); v.w = fmaxf(acc[i][3], 0.0f);
    *(float4*)&sA[(r0 + i) * 132 + c0] = v;
  }
  __syncthreads();
  {
    float4 bb = *(const float4*)&b2[c0];
#pragma unroll
    for (int i = 0; i < 8; ++i) { acc[i][0] = bb.x; acc[i][1] = bb.y; acc[i][2] = bb.z; acc[i][3] = bb.w; }
  }
  gemm_tile_g(sA, (const float4*)W2, acc, r0, cg);

  int node0 = rb + r0;
#pragma unroll
  for (int i = 0; i < 8; ++i) {
    float4 v = make_float4(acc[i][0], acc[i][1], acc[i][2], acc[i][3]);
    *(float4*)&h_out[(size_t)(node0 + i) * DH + c0] = v;
    uint2 hv;
    hv.x = pack_bf2(acc[i][0], acc[i][1]);
    hv.y = pack_bf2(acc[i][2], acc[i][3]);
    *(uint2*)&hb_out[(size_t)(node0 + i) * 64 + (c0 >> 1)] = hv;
  }
  float* pbase = pooled + t_slot * DH;
  int g_first = graph_ids[node0];
  int g_last = graph_ids[node0 + 7];
  if (g_first == g_last) {
    float s0 = 0.f, s1 = 0.f, s2 = 0.f, s3 = 0.f;
#pragma unroll
    for (int i = 0; i < 8; ++i) { s0 += acc[i][0]; s1 += acc[i][1]; s2 += acc[i][2]; s3 += acc[i][3]; }
    atomicAdd(&pbase[g_first * 512 + c0 + 0], s0);
    atomicAdd(&pbase[g_first * 512 + c0 + 1], s1);
    atomicAdd(&pbase[g_first * 512 + c0 + 2], s2);
    atomicAdd(&pbase[g_first * 512 + c0 + 3], s3);
  } else {
#pragma unroll
    for (int i = 0; i < 8; ++i) {
      int g = graph_ids[node0 + i];
      atomicAdd(&pbase[g * 512 + c0 + 0], acc[i][0]);
      atomicAdd(&pbase[g * 512 + c0 + 1], acc[i][1]);
      atomicAdd(&pbase[g * 512 + c0 + 2], acc[i][2]);
      atomicAdd(&pbase[g * 512 + c0 + 3], acc[i][3]);
    }
  }
}

// ---------------- final: out = pooled @ Wl + bl ----------------
__global__ __launch_bounds__(256) void k_final(const float* __restrict__ pooled,
                                               const float* __restrict__ Wl,
                                               const float* __restrict__ bl,
                                               float* __restrict__ out) {
  int g = blockIdx.x, o = threadIdx.x;
  __shared__ float sp[DH * T_ITERS];
  for (int idx = o; idx < DH * T_ITERS; idx += 256) sp[idx] = pooled[g * (DH * T_ITERS) + idx];
  __syncthreads();
  float acc = bl[o];
#pragma unroll 8
  for (int j = 0; j < DH * T_ITERS; ++j)
    acc = fmaf(sp[j], Wl[j * DOUT + o], acc);
  out[g * DOUT + o] = acc;
}

extern "C" void kernel_launch(void* const* d_in, const int* in_sizes, int n_in,
                              void* d_out, int out_size, void* d_ws, size_t ws_size,
                              hipStream_t stream) {
  const float* x         = (const float*)d_in[0];
  const int*   edge_index= (const int*)d_in[1];
  const float* edge_attr = (const float*)d_in[2];
  const int*   graph_ids = (const int*)d_in[3];
  const float* Wn = (const float*)d_in[4];
  const float* bn = (const float*)d_in[5];
  const float* We = (const float*)d_in[6];
  const float* be = (const float*)d_in[7];
  const float* W1 = (const float*)d_in[8];
  const float* b1 = (const float*)d_in[9];
  const float* W2 = (const float*)d_in[10];
  const float* b2 = (const float*)d_in[11];
  const float* Wl = (const float*)d_in[12];
  const float* bl = (const float*)d_in[13];
  float* out = (float*)d_out;

  char* p = (char*)d_ws;
  auto alloc = [&](size_t bytes) { char* r = p; p += (bytes + 255) & ~(size_t)255; return r; };
  float*  h        = (float*)alloc((size_t)N_NODES * DH * 4);   // fallback path only
  float*  z        = (float*)alloc((size_t)N_NODES * DH * 4);   // primary path reuses as zb
  uint32* hb       = (uint32*)alloc((size_t)N_NODES * DH * 2);
  float*  pooled   = (float*)alloc((size_t)N_GRAPHS * DH * T_ITERS * 4);
  int*    counts   = (int*)alloc((size_t)N_NODES * 4);          // reused as w1t/w2t after scan
  int*    row_start= (int*)alloc((size_t)(N_NODES + 1) * 4);
  int*    cursor   = (int*)alloc((size_t)N_NODES * 4);
  int*    src_perm = (int*)alloc((size_t)N_EDGES * 4);
  int*    blk_sums = (int*)alloc(256);

  const int* src = edge_index;
  const int* dst = edge_index + N_EDGES;

  size_t used = (size_t)(p - (char*)d_ws);
  size_t need_e = used + (size_t)N_EDGES * DH + 4096;   // e8_perm 82 MB

  hipMemsetAsync(counts, 0, (size_t)N_NODES * 4, stream);
  hipMemsetAsync(pooled, 0, (size_t)N_GRAPHS * DH * T_ITERS * 4, stream);

  bool primary = (ws_size >= need_e);
  if (primary) {
    k_embed_nh<<<N_NODES * DH / 256, 256, 0, stream>>>(x, Wn, bn, (ushort16*)hb);
  } else {
    k_embed<<<N_NODES * DH / 256, 256, 0, stream>>>(x, Wn, bn, h, (ushort16*)hb);
  }
  k_hist<<<N_EDGES / 256, 256, 0, stream>>>(dst, counts);
  k_scan1<<<SCAN_BLK, 1024, 0, stream>>>(counts, row_start, blk_sums);
  k_scan23<<<SCAN_BLK, 1024, 0, stream>>>(row_start, blk_sums, cursor);

  if (primary) {
    unsigned short* e8_perm = (unsigned short*)alloc((size_t)N_EDGES * DH);
    uint32* zb = (uint32*)z;                              // overlay (z fp32 unused here)
    ushort16* w1t = (ushort16*)counts;                    // counts dead after scan
    ushort16* w2t = w1t + 128 * 128;
    k_prep_w<<<128, 256, 0, stream>>>(W1, W2, w1t, w2t);
    k_perm_e<<<N_EDGES / 128, 128, 0, stream>>>(src, dst, (const float4*)edge_attr,
                                                We, be, cursor, src_perm, e8_perm);
    for (int t = 0; t < T_ITERS; ++t) {
      k_agg_lite<<<N_NODES / 4, 256, 0, stream>>>(hb, e8_perm, row_start, src_perm, zb);
      k_mlp_mfma<<<N_NODES / 64, 256, 0, stream>>>(zb, w1t, w2t, b1, b2, graph_ids,
                                                   hb, pooled, t, (t < T_ITERS - 1) ? 1 : 0);
    }
  } else {
    int* eid_perm = (int*)alloc((size_t)N_EDGES * 4);
    k_permute<<<N_EDGES / 256, 256, 0, stream>>>(src, dst, cursor, src_perm, eid_perm);
    for (int t = 0; t < T_ITERS; ++t) {
      k_agg_ind<<<N_NODES / 4, 256, 0, stream>>>(h, hb, edge_attr, We, be, row_start, src_perm, eid_perm, z);
      k_mlp<<<N_NODES / 64, 256, 0, stream>>>(z, W1, b1, W2, b2, graph_ids, h, (uint32*)hb, pooled, t);
    }
  }
  k_final<<<N_GRAPHS, 256, 0, stream>>>(pooled, Wl, bl, out);
}